// Round 4
// baseline (1142.309 us; speedup 1.0000x reference)
//
#include <hip/hip_runtime.h>
#include <math.h>

typedef short short8 __attribute__((ext_vector_type(8)));
typedef float floatx4 __attribute__((ext_vector_type(4)));

#define Bb 64
#define Ss 512
#define Hh 512
#define DFF 2048
#define HOPS 6
#define BS (Bb*Ss)          // 32768 positions
#define PS 1048576          // weight plane stride (elems), both w1f and w2f
#define BUFSZ 49152         // 48 KB stage buffer (A 16 KB + B 32 KB)

// ---------------- fp32 -> 2x bf16 split (RNE, exact residual) --------------
// Manual bit-twiddle RNE (R1-proven). m240: hand-written v_cvt_pk inline asm
// is SLOWER than compiler-scheduled plain ops -- do not reintroduce.
__device__ inline unsigned bf16rne(float v) {
  union { float f; unsigned u; } a; a.f = v;
  return (a.u + 0x7fffu + ((a.u >> 16) & 1u)) >> 16;
}
__device__ inline void split2(float v, unsigned &h1, unsigned &h2) {
  h1 = bf16rne(v);
  union { unsigned u; float f; } b1; b1.u = h1 << 16;
  h2 = bf16rne(v - b1.f);
}
__device__ inline void split8_store2(const float* xs, unsigned short* dst,
                                     size_t psa) {
  unsigned q1[4], q2[4];
#pragma unroll
  for (int jj = 0; jj < 4; ++jj) {
    unsigned a1, a2, c1, c2;
    split2(xs[2*jj],   a1, a2);
    split2(xs[2*jj+1], c1, c2);
    q1[jj] = a1 | (c1 << 16);
    q2[jj] = a2 | (c2 << 16);
  }
  *(int4*)(dst)       = make_int4(q1[0], q1[1], q1[2], q1[3]);
  *(int4*)(dst + psa) = make_int4(q2[0], q2[1], q2[2], q2[3]);
}

// ---------------- async global->LDS 16B helper -----------------------------
__device__ __forceinline__ void gload16(const void* g, void* l) {
  __builtin_amdgcn_global_load_lds(
      (const __attribute__((address_space(1))) void*)g,
      (__attribute__((address_space(3))) void*)l, 16, 0, 0);
}

// ---------------- weight pre-split into fragment-linear planes -------------
__global__ __launch_bounds__(256) void prep_kernel(
    const float* __restrict__ w, unsigned short* __restrict__ wf,
    int K32, int NTOT, int N)
{
  int id = blockIdx.x * 256 + threadIdx.x;      // one per (k0,NT,lane)
  if (id >= K32 * NTOT * 64) return;
  int l  = id & 63;
  int NT = (id >> 6) % NTOT;
  int k0 = id / (64 * NTOT);
  int n  = NT * 16 + (l & 15);
  int kb = k0 * 32 + 8 * (l >> 4);
  float xs[8];
#pragma unroll
  for (int j = 0; j < 8; ++j) xs[j] = w[(size_t)(kb + j) * N + n];
  split8_store2(xs, wf + (size_t)id * 8, PS);
}

// ---------------- parallel compaction (order-free, outputs invariant) ------
__global__ __launch_bounds__(1024) void compact_kernel(
    const float* __restrict__ halting, int* __restrict__ idx,
    int* __restrict__ cnt)
{
  __shared__ int wsum[16];
  __shared__ int wbase[16];
  __shared__ int s_base;
  int tid = threadIdx.x;
  int lane = tid & 63, wid = tid >> 6;
  int pos = blockIdx.x * 1024 + tid;
  int flag = (halting[pos] < 1.0f) ? 1 : 0;
  unsigned long long m = __ballot(flag);
  int pre = __popcll(m & ((1ull << lane) - 1ull));
  if (lane == 0) wsum[wid] = __popcll(m);
  __syncthreads();
  if (tid == 0) {
    int a = 0;
#pragma unroll
    for (int i = 0; i < 16; ++i) { wbase[i] = a; a += wsum[i]; }
    s_base = (a > 0) ? atomicAdd(cnt, a) : 0;
  }
  __syncthreads();
  if (flag) idx[s_base + wbase[wid] + pre] = pos;
}

// ---------------- halting / p kernel (pure fp32) ---------------------------
__global__ __launch_bounds__(256) void halt_kernel(
    const float* __restrict__ st, const float* __restrict__ te,
    const float* __restrict__ pe_t, const float* __restrict__ wp,
    const float* __restrict__ bp, float* __restrict__ halting,
    float* __restrict__ remainders, float* __restrict__ n_updates,
    float* __restrict__ uw_c, const int* __restrict__ idxbuf,
    const int* __restrict__ cntp)
{
  int cnt = *cntp;
  int i = blockIdx.x * 4 + (threadIdx.x >> 6);
  if (i >= cnt) return;
  int lane = threadIdx.x & 63;
  int pos = idxbuf[i];
  int s = pos & (Ss - 1);
  const float4* stv = (const float4*)(st + (size_t)pos * Hh);
  const float4* tev = (const float4*)(te + (size_t)s * Hh);
  const float4* pev = (const float4*)pe_t;
  const float4* wpv = (const float4*)wp;
  float sum = 0.f;
#pragma unroll
  for (int j = 0; j < 2; ++j) {
    int idx = lane + j * 64;
    float4 a = stv[idx], b = tev[idx], c = pev[idx], w = wpv[idx];
    sum += (a.x + b.x + c.x) * w.x + (a.y + b.y + c.y) * w.y +
           (a.z + b.z + c.z) * w.z + (a.w + b.w + c.w) * w.w;
  }
#pragma unroll
  for (int off = 32; off > 0; off >>= 1) sum += __shfl_xor(sum, off, 64);
  if (lane == 0) {
    float y = sum + bp[0];
    float p = 1.0f / (1.0f + expf(-y));
    const float THRESH = 1.0f - 0.1f;
    float h0  = halting[pos];
    float rem = remainders[pos];
    float nup = n_updates[pos];
    float still = (h0 < 1.0f) ? 1.f : 0.f;
    float cand  = h0 + p * still;
    float nh  = ((cand >  THRESH) ? 1.f : 0.f) * still;
    float st2 = ((cand <= THRESH) ? 1.f : 0.f) * still;
    h0  += p * st2;
    rem += nh * (1.0f - h0);
    h0  += nh * rem;
    nup += st2 + nh;
    float uwv = p * st2 + nh * rem;
    halting[pos]    = h0;
    remainders[pos] = rem;
    n_updates[pos]  = nup;
    uw_c[i]         = uwv;
  }
}

// ---- stage_x: split x = st+te+pe (gathered) into bf16x2 fragment planes ---
__global__ __launch_bounds__(256) void stagex_kernel(
    const float* __restrict__ st, const float* __restrict__ te,
    const float* __restrict__ pe_t, unsigned short* __restrict__ xf,
    const int* __restrict__ idxbuf, const int* __restrict__ cntp,
    int m_base, int mrows, size_t psa)
{
  const int K32 = Hh / 32;
  int cnt = *cntp;
  int rel = cnt - m_base;
  if (rel <= 0) return;
  if (rel > mrows) rel = mrows;
  int rows_pad = (rel + 127) & ~127;
  if (rows_pad > mrows) rows_pad = mrows;
  int id = blockIdx.x * 256 + threadIdx.x;
  int l = id & 63;
  int f = id >> 6;
  int mtile = f / K32, k0 = f - mtile * K32;
  if (mtile * 16 >= rows_pad) return;
  int m = m_base + mtile * 16 + (l & 15);
  int mc = (m < cnt) ? m : cnt - 1;
  int pos = idxbuf[mc];
  int kb = k0 * 32 + (l >> 4) * 8;
  const float* ap = st + (size_t)pos * Hh + kb;
  const float* tp = te + (size_t)(pos & (Ss - 1)) * Hh + kb;
  const float* pp = pe_t + kb;
  float4 xa = *(const float4*)ap, xb = *(const float4*)(ap + 4);
  float4 ta = *(const float4*)tp, tb = *(const float4*)(tp + 4);
  float4 pa = *(const float4*)pp, pb = *(const float4*)(pp + 4);
  float xs[8];
  xs[0] = xa.x + ta.x + pa.x; xs[1] = xa.y + ta.y + pa.y;
  xs[2] = xa.z + ta.z + pa.z; xs[3] = xa.w + ta.w + pa.w;
  xs[4] = xb.x + tb.x + pb.x; xs[5] = xb.y + tb.y + pb.y;
  xs[6] = xb.z + tb.z + pb.z; xs[7] = xb.w + tb.w + pb.w;
  split8_store2(xs, xf + ((size_t)f * 64 + l) * 8, psa);
}

// ======================= phased GEMM kernels ==============================
// 8 waves (512 thr), block tile 128x256, wave tile 64x64 (2m x 4n waves),
// BK=32, LDS dbuf 2x48 KB -> 1 block/CU (2 waves/SIMD). Per k-step:
//   stage 6 gloads/wave for next buf; s_waitcnt vmcnt(6) (counted, T4);
//   barrier; then 4 sub-phases (T3): {ds_read quadrant; bar; lgkmcnt(0);
//   setprio(1); 12 MFMA; setprio(0); bar}; phase 3 is register-only.
// Reads-before-overwrite protected by phase-2-end barrier (last ds_read is
// phase 2). 3-limb products per frag pair (a1b1 + a1b2 + a2b1).

// ---- GEMM1: h = relu(x @ w1 + b1), repacked to A-frag planes --------------
#define LSTR 66
__global__ __launch_bounds__(512, 1) void gemm1_kernel(
    const unsigned short* __restrict__ xf, const unsigned short* __restrict__ w1f,
    const float* __restrict__ b1, unsigned short* __restrict__ hf,
    const int* __restrict__ cntp, int m_base, size_t psa, size_t psh, int nst)
{
  __shared__ __align__(1024) char stage[2 * BUFSZ];
  const int K32 = Hh / 32, NTOT = DFF / 16;   // K32 = 16
  int lin = blockIdx.x;
  int gsz = gridDim.x;
  int q = gsz >> 3, r = gsz & 7;
  int xcd = lin & 7, idx0 = lin >> 3;
  int swz = (xcd < r) ? (xcd * (q + 1) + idx0)
                      : (r * (q + 1) + (xcd - r) * q + idx0);
  int strip = swz >> 3;          // 8 n-blocks of 256 over DFF
  int nb    = swz & 7;
  int cnt = *cntp;
  int m0 = strip * 128;
  if (m_base + m0 >= cnt) return;
  int tid = threadIdx.x, lane = tid & 63, w = tid >> 6;
  int wm = w >> 2, wn = w & 3;
  int n0 = nb * 256;
  int mtb0 = m0 >> 4, ntb0 = n0 >> 4;
  char* sptr = stage;

  auto stage_step = [&](int bsel, int kk) {
    unsigned so = (unsigned)bsel * (unsigned)BUFSZ;
#pragma unroll
    for (int j = 0; j < 6; ++j) {
      int u = w * 6 + j;                      // 0..15 A units, 16..47 B units
      const unsigned short* g;
      if (u < 16) {
        int mtile = u >> 1, limb = u & 1;
        g = xf + ((size_t)(mtb0 + mtile) * K32 + kk) * 512
               + (size_t)limb * psa + (size_t)lane * 8;
      } else {
        int v = u - 16;
        int ntile = v >> 1, limb = v & 1;
        g = w1f + ((size_t)kk * NTOT + (ntb0 + ntile)) * 512
                + (size_t)limb * PS + (size_t)lane * 8;
      }
      gload16(g, sptr + so + (unsigned)u * 1024u);
    }
  };

  floatx4 acc[4][4];
#pragma unroll
  for (int i = 0; i < 4; ++i)
#pragma unroll
    for (int j = 0; j < 4; ++j) acc[i][j] = (floatx4){0.f, 0.f, 0.f, 0.f};

  stage_step(0, 0);
  for (int k0 = 0; k0 < K32; ++k0) {
    int cur = k0 & 1;
    if (k0 + 1 < K32) {
      stage_step(cur ^ 1, k0 + 1);
      asm volatile("s_waitcnt vmcnt(6)" ::: "memory");   // prev stage landed
    } else {
      asm volatile("s_waitcnt vmcnt(0)" ::: "memory");
    }
    __builtin_amdgcn_s_barrier();                        // cur visible to all
    const char* sb = sptr + cur * BUFSZ + (size_t)lane * 16;
    short8 af[2][4], bf[2][4];
    // ---- phase 0: read af01 + bf01; MFMA mt01 x nt01
#pragma unroll
    for (int mt = 0; mt < 2; ++mt) {
      af[0][mt] = *(const short8*)(sb + ((wm * 4 + mt) * 2 + 0) * 1024);
      af[1][mt] = *(const short8*)(sb + ((wm * 4 + mt) * 2 + 1) * 1024);
    }
#pragma unroll
    for (int nt = 0; nt < 2; ++nt) {
      bf[0][nt] = *(const short8*)(sb + 16384 + ((wn * 4 + nt) * 2 + 0) * 1024);
      bf[1][nt] = *(const short8*)(sb + 16384 + ((wn * 4 + nt) * 2 + 1) * 1024);
    }
    asm volatile("" ::: "memory");
    __builtin_amdgcn_s_barrier();
    asm volatile("s_waitcnt lgkmcnt(0)" ::: "memory");
    __builtin_amdgcn_s_setprio(1);
#pragma unroll
    for (int mt = 0; mt < 2; ++mt)
#pragma unroll
      for (int nt = 0; nt < 2; ++nt) {
        floatx4 c = acc[mt][nt];
        c = __builtin_amdgcn_mfma_f32_16x16x32_bf16(af[1][mt], bf[0][nt], c, 0, 0, 0);
        c = __builtin_amdgcn_mfma_f32_16x16x32_bf16(af[0][mt], bf[1][nt], c, 0, 0, 0);
        c = __builtin_amdgcn_mfma_f32_16x16x32_bf16(af[0][mt], bf[0][nt], c, 0, 0, 0);
        acc[mt][nt] = c;
      }
    __builtin_amdgcn_s_setprio(0);
    asm volatile("" ::: "memory");
    __builtin_amdgcn_s_barrier();
    // ---- phase 1: read bf23; MFMA mt01 x nt23
#pragma unroll
    for (int nt = 2; nt < 4; ++nt) {
      bf[0][nt] = *(const short8*)(sb + 16384 + ((wn * 4 + nt) * 2 + 0) * 1024);
      bf[1][nt] = *(const short8*)(sb + 16384 + ((wn * 4 + nt) * 2 + 1) * 1024);
    }
    asm volatile("" ::: "memory");
    __builtin_amdgcn_s_barrier();
    asm volatile("s_waitcnt lgkmcnt(0)" ::: "memory");
    __builtin_amdgcn_s_setprio(1);
#pragma unroll
    for (int mt = 0; mt < 2; ++mt)
#pragma unroll
      for (int nt = 2; nt < 4; ++nt) {
        floatx4 c = acc[mt][nt];
        c = __builtin_amdgcn_mfma_f32_16x16x32_bf16(af[1][mt], bf[0][nt], c, 0, 0, 0);
        c = __builtin_amdgcn_mfma_f32_16x16x32_bf16(af[0][mt], bf[1][nt], c, 0, 0, 0);
        c = __builtin_amdgcn_mfma_f32_16x16x32_bf16(af[0][mt], bf[0][nt], c, 0, 0, 0);
        acc[mt][nt] = c;
      }
    __builtin_amdgcn_s_setprio(0);
    asm volatile("" ::: "memory");
    __builtin_amdgcn_s_barrier();
    // ---- phase 2: read af23; MFMA mt23 x nt01  (last ds_reads of cur)
#pragma unroll
    for (int mt = 2; mt < 4; ++mt) {
      af[0][mt] = *(const short8*)(sb + ((wm * 4 + mt) * 2 + 0) * 1024);
      af[1][mt] = *(const short8*)(sb + ((wm * 4 + mt) * 2 + 1) * 1024);
    }
    asm volatile("" ::: "memory");
    __builtin_amdgcn_s_barrier();
    asm volatile("s_waitcnt lgkmcnt(0)" ::: "memory");
    __builtin_amdgcn_s_setprio(1);
#pragma unroll
    for (int mt = 2; mt < 4; ++mt)
#pragma unroll
      for (int nt = 0; nt < 2; ++nt) {
        floatx4 c = acc[mt][nt];
        c = __builtin_amdgcn_mfma_f32_16x16x32_bf16(af[1][mt], bf[0][nt], c, 0, 0, 0);
        c = __builtin_amdgcn_mfma_f32_16x16x32_bf16(af[0][mt], bf[1][nt], c, 0, 0, 0);
        c = __builtin_amdgcn_mfma_f32_16x16x32_bf16(af[0][mt], bf[0][nt], c, 0, 0, 0);
        acc[mt][nt] = c;
      }
    __builtin_amdgcn_s_setprio(0);
    asm volatile("" ::: "memory");
    __builtin_amdgcn_s_barrier();   // all reads of cur done -> safe to restage
    // ---- phase 3: MFMA mt23 x nt23 (register-only, overlaps next stage)
    __builtin_amdgcn_s_setprio(1);
#pragma unroll
    for (int mt = 2; mt < 4; ++mt)
#pragma unroll
      for (int nt = 2; nt < 4; ++nt) {
        floatx4 c = acc[mt][nt];
        c = __builtin_amdgcn_mfma_f32_16x16x32_bf16(af[1][mt], bf[0][nt], c, 0, 0, 0);
        c = __builtin_amdgcn_mfma_f32_16x16x32_bf16(af[0][mt], bf[1][nt], c, 0, 0, 0);
        c = __builtin_amdgcn_mfma_f32_16x16x32_bf16(af[0][mt], bf[0][nt], c, 0, 0, 0);
        acc[mt][nt] = c;
      }
    __builtin_amdgcn_s_setprio(0);
  }
  // epilogue: relu + bias; repack C-frag -> A-frag in 16-row slices.
  // Per-wave private LDS slice in buffer 0 (cur==1 at loop end since K32
  // even -> buffer 0 region dead), no barriers needed.
  {
    int r0 = (lane >> 4) * 4;
    int c0l = lane & 15;
    int mtb = mtb0 + wm * 4;
    int k2b = (n0 >> 5) + wn * 2;
    float* L = (float*)(void*)sptr + (size_t)w * (16 * LSTR);
    float bias[4];
#pragma unroll
    for (int nt = 0; nt < 4; ++nt) bias[nt] = b1[n0 + wn * 64 + nt * 16 + c0l];
#pragma unroll
    for (int mt = 0; mt < 4; ++mt) {
#pragma unroll
      for (int nt = 0; nt < 4; ++nt)
#pragma unroll
        for (int reg = 0; reg < 4; ++reg)
          L[(r0 + reg) * LSTR + nt * 16 + c0l] =
              fmaxf(acc[mt][nt][reg] + bias[nt], 0.f);
#pragma unroll
      for (int k2 = 0; k2 < 2; ++k2) {
        const float* rp = L + (lane & 15) * LSTR + k2 * 32 + (lane >> 4) * 8;
        float xs[8];
        float4 xa = *(const float4*)rp, xb = *(const float4*)(rp + 4);
        xs[0]=xa.x; xs[1]=xa.y; xs[2]=xa.z; xs[3]=xa.w;
        xs[4]=xb.x; xs[5]=xb.y; xs[6]=xb.z; xs[7]=xb.w;
        size_t f2 = (size_t)(mtb + mt) * 64 + (k2b + k2);
        split8_store2(xs, hf + (f2 * 64 + lane) * 8, psh);
      }
    }
  }
}

// ---- GEMM2f (FULL-K, fused bias + uw-blend scatter epilogue) --------------
__global__ __launch_bounds__(512, 1) void gemm2f_kernel(
    const unsigned short* __restrict__ hf, const unsigned short* __restrict__ w2f,
    const float* __restrict__ b2, const float* __restrict__ uw_c,
    float* __restrict__ st_out, float* __restrict__ prev,
    const int* __restrict__ idxbuf, const int* __restrict__ cntp,
    int m_base, size_t psh, int nst)
{
  __shared__ __align__(1024) char stage[2 * BUFSZ];
  const int K32 = DFF / 32, NTOT = Hh / 16;   // K32 = 64
  int lin = blockIdx.x;
  int gsz = gridDim.x;
  int q = gsz >> 3, r = gsz & 7;
  int xcd = lin & 7, idx0 = lin >> 3;
  int swz = (xcd < r) ? (xcd * (q + 1) + idx0)
                      : (r * (q + 1) + (xcd - r) * q + idx0);
  int strip = swz >> 1, nb = swz & 1;         // 2 n-blocks of 256 over Hh
  int cnt = *cntp;
  int m0 = strip * 128;
  if (m_base + m0 >= cnt) return;
  int n0 = nb * 256;
  int tid = threadIdx.x, lane = tid & 63, w = tid >> 6;
  int wm = w >> 2, wn = w & 3;
  int mtb0 = m0 >> 4, ntb0 = n0 >> 4;
  char* sptr = stage;

  auto stage_step = [&](int bsel, int kk) {
    unsigned so = (unsigned)bsel * (unsigned)BUFSZ;
#pragma unroll
    for (int j = 0; j < 6; ++j) {
      int u = w * 6 + j;
      const unsigned short* g;
      if (u < 16) {
        int mtile = u >> 1, limb = u & 1;
        g = hf + ((size_t)(mtb0 + mtile) * K32 + kk) * 512
               + (size_t)limb * psh + (size_t)lane * 8;
      } else {
        int v = u - 16;
        int ntile = v >> 1, limb = v & 1;
        g = w2f + ((size_t)kk * NTOT + (ntb0 + ntile)) * 512
                + (size_t)limb * PS + (size_t)lane * 8;
      }
      gload16(g, sptr + so + (unsigned)u * 1024u);
    }
  };

  floatx4 acc[4][4];
#pragma unroll
  for (int i = 0; i < 4; ++i)
#pragma unroll
    for (int j = 0; j < 4; ++j) acc[i][j] = (floatx4){0.f, 0.f, 0.f, 0.f};

  stage_step(0, 0);
  for (int k0 = 0; k0 < K32; ++k0) {
    int cur = k0 & 1;
    if (k0 + 1 < K32) {
      stage_step(cur ^ 1, k0 + 1);
      asm volatile("s_waitcnt vmcnt(6)" ::: "memory");
    } else {
      asm volatile("s_waitcnt vmcnt(0)" ::: "memory");
    }
    __builtin_amdgcn_s_barrier();
    const char* sb = sptr + cur * BUFSZ + (size_t)lane * 16;
    short8 af[2][4], bf[2][4];
    // ---- phase 0
#pragma unroll
    for (int mt = 0; mt < 2; ++mt) {
      af[0][mt] = *(const short8*)(sb + ((wm * 4 + mt) * 2 + 0) * 1024);
      af[1][mt] = *(const short8*)(sb + ((wm * 4 + mt) * 2 + 1) * 1024);
    }
#pragma unroll
    for (int nt = 0; nt < 2; ++nt) {
      bf[0][nt] = *(const short8*)(sb + 16384 + ((wn * 4 + nt) * 2 + 0) * 1024);
      bf[1][nt] = *(const short8*)(sb + 16384 + ((wn * 4 + nt) * 2 + 1) * 1024);
    }
    asm volatile("" ::: "memory");
    __builtin_amdgcn_s_barrier();
    asm volatile("s_waitcnt lgkmcnt(0)" ::: "memory");
    __builtin_amdgcn_s_setprio(1);
#pragma unroll
    for (int mt = 0; mt < 2; ++mt)
#pragma unroll
      for (int nt = 0; nt < 2; ++nt) {
        floatx4 c = acc[mt][nt];
        c = __builtin_amdgcn_mfma_f32_16x16x32_bf16(af[1][mt], bf[0][nt], c, 0, 0, 0);
        c = __builtin_amdgcn_mfma_f32_16x16x32_bf16(af[0][mt], bf[1][nt], c, 0, 0, 0);
        c = __builtin_amdgcn_mfma_f32_16x16x32_bf16(af[0][mt], bf[0][nt], c, 0, 0, 0);
        acc[mt][nt] = c;
      }
    __builtin_amdgcn_s_setprio(0);
    asm volatile("" ::: "memory");
    __builtin_amdgcn_s_barrier();
    // ---- phase 1
#pragma unroll
    for (int nt = 2; nt < 4; ++nt) {
      bf[0][nt] = *(const short8*)(sb + 16384 + ((wn * 4 + nt) * 2 + 0) * 1024);
      bf[1][nt] = *(const short8*)(sb + 16384 + ((wn * 4 + nt) * 2 + 1) * 1024);
    }
    asm volatile("" ::: "memory");
    __builtin_amdgcn_s_barrier();
    asm volatile("s_waitcnt lgkmcnt(0)" ::: "memory");
    __builtin_amdgcn_s_setprio(1);
#pragma unroll
    for (int mt = 0; mt < 2; ++mt)
#pragma unroll
      for (int nt = 2; nt < 4; ++nt) {
        floatx4 c = acc[mt][nt];
        c = __builtin_amdgcn_mfma_f32_16x16x32_bf16(af[1][mt], bf[0][nt], c, 0, 0, 0);
        c = __builtin_amdgcn_mfma_f32_16x16x32_bf16(af[0][mt], bf[1][nt], c, 0, 0, 0);
        c = __builtin_amdgcn_mfma_f32_16x16x32_bf16(af[0][mt], bf[0][nt], c, 0, 0, 0);
        acc[mt][nt] = c;
      }
    __builtin_amdgcn_s_setprio(0);
    asm volatile("" ::: "memory");
    __builtin_amdgcn_s_barrier();
    // ---- phase 2
#pragma unroll
    for (int mt = 2; mt < 4; ++mt) {
      af[0][mt] = *(const short8*)(sb + ((wm * 4 + mt) * 2 + 0) * 1024);
      af[1][mt] = *(const short8*)(sb + ((wm * 4 + mt) * 2 + 1) * 1024);
    }
    asm volatile("" ::: "memory");
    __builtin_amdgcn_s_barrier();
    asm volatile("s_waitcnt lgkmcnt(0)" ::: "memory");
    __builtin_amdgcn_s_setprio(1);
#pragma unroll
    for (int mt = 2; mt < 4; ++mt)
#pragma unroll
      for (int nt = 0; nt < 2; ++nt) {
        floatx4 c = acc[mt][nt];
        c = __builtin_amdgcn_mfma_f32_16x16x32_bf16(af[1][mt], bf[0][nt], c, 0, 0, 0);
        c = __builtin_amdgcn_mfma_f32_16x16x32_bf16(af[0][mt], bf[1][nt], c, 0, 0, 0);
        c = __builtin_amdgcn_mfma_f32_16x16x32_bf16(af[0][mt], bf[0][nt], c, 0, 0, 0);
        acc[mt][nt] = c;
      }
    __builtin_amdgcn_s_setprio(0);
    asm volatile("" ::: "memory");
    __builtin_amdgcn_s_barrier();   // all reads of cur done -> safe to restage
    // ---- phase 3 (register-only)
    __builtin_amdgcn_s_setprio(1);
#pragma unroll
    for (int mt = 2; mt < 4; ++mt)
#pragma unroll
      for (int nt = 2; nt < 4; ++nt) {
        floatx4 c = acc[mt][nt];
        c = __builtin_amdgcn_mfma_f32_16x16x32_bf16(af[1][mt], bf[0][nt], c, 0, 0, 0);
        c = __builtin_amdgcn_mfma_f32_16x16x32_bf16(af[0][mt], bf[1][nt], c, 0, 0, 0);
        c = __builtin_amdgcn_mfma_f32_16x16x32_bf16(af[0][mt], bf[0][nt], c, 0, 0, 0);
        acc[mt][nt] = c;
      }
    __builtin_amdgcn_s_setprio(0);
  }
  // fused epilogue: sv = acc + b2; st_out = sv; prev = sv*uw + prev*(1-uw)
  {
    int r0 = (lane >> 4) * 4;
    int c0l = lane & 15;
    int mtb = mtb0 + wm * 4;
    int njb = ntb0 + wn * 4;
    float bias[4];
#pragma unroll
    for (int nt = 0; nt < 4; ++nt) bias[nt] = b2[(njb + nt) * 16 + c0l];
#pragma unroll
    for (int mt = 0; mt < 4; ++mt) {
      int pos4[4]; float uw4[4]; bool ok4[4];
#pragma unroll
      for (int reg = 0; reg < 4; ++reg) {
        int m = m_base + (mtb + mt) * 16 + r0 + reg;
        ok4[reg] = (m < cnt);
        int mc = ok4[reg] ? m : 0;
        pos4[reg] = idxbuf[mc];
        uw4[reg]  = uw_c[mc];
      }
#pragma unroll
      for (int nt = 0; nt < 4; ++nt) {
        int col = (njb + nt) * 16 + c0l;
#pragma unroll
        for (int reg = 0; reg < 4; ++reg) {
          if (ok4[reg]) {
            float sv = acc[mt][nt][reg] + bias[nt];
            size_t off = (size_t)pos4[reg] * Hh + col;
            float pv = prev[off];
            st_out[off] = sv;
            prev[off] = sv * uw4[reg] + pv * (1.f - uw4[reg]);
          }
        }
      }
    }
  }
}

extern "C" void kernel_launch(void* const* d_in, const int* in_sizes, int n_in,
                              void* d_out, int out_size, void* d_ws, size_t ws_size,
                              hipStream_t stream) {
  const float* state  = (const float*)d_in[0];
  const float* te     = (const float*)d_in[2];
  const float* pe     = (const float*)d_in[3];
  const float* wp     = (const float*)d_in[4];
  const float* bp     = (const float*)d_in[5];
  const float* w1     = (const float*)d_in[6];
  const float* b1     = (const float*)d_in[7];
  const float* w2     = (const float*)d_in[8];
  const float* b2     = (const float*)d_in[9];

  float* out        = (float*)d_out;
  float* prev       = out;                          // BS*H
  float* remainders = out + (size_t)BS * Hh;        // BS
  float* n_updates  = remainders + BS;              // BS

  float*          st      = (float*)d_ws;           // BS*H (67 MB)
  float*          halting = st + (size_t)BS * Hh;   // BS
  float*          uw_c    = halting + BS;           // BS
  int*            idxbuf  = (int*)(uw_c + BS);      // BS
  int*            cntp    = idxbuf + BS;            // 64 (one counter per hop)
  unsigned short* w1f     = (unsigned short*)(cntp + 64);   // 2*PS (4 MB)
  unsigned short* w2f     = w1f + 2 * (size_t)PS;           // 2*PS (4 MB)
  unsigned short* hf      = w2f + 2 * (size_t)PS;

  size_t fixed = (size_t)((char*)hf - (char*)d_ws);
  size_t avail = (ws_size > fixed) ? (ws_size - fixed) : 0;
  // per row: hf = 2*2048*2 = 8192 B ; xf = 2048 B
  int hrows = (int)((avail / 10240) & ~(size_t)127);
  if (hrows > 16384) hrows = 16384;  // keep hf chunk L3-resident
  if (hrows < 128) hrows = 128;
  unsigned short* xf = (unsigned short*)((char*)hf + (size_t)hrows * DFF * 2 * 2);
  size_t psa = (size_t)hrows * Hh;    // xf plane stride (ushort elems)
  size_t psh = (size_t)hrows * DFF;   // hf plane stride (ushort elems)
  int nst = hrows / 128;

  hipMemsetAsync(d_out, 0, (size_t)out_size * sizeof(float), stream);
  hipMemsetAsync(halting, 0, (size_t)BS * sizeof(float), stream);
  hipMemsetAsync(cntp, 0, 64 * sizeof(int), stream);
  hipMemcpyAsync(st, state, (size_t)BS * Hh * sizeof(float),
                 hipMemcpyDeviceToDevice, stream);

  prep_kernel<<<512, 256, 0, stream>>>(w1, w1f, Hh / 32, DFF / 16, DFF);
  prep_kernel<<<512, 256, 0, stream>>>(w2, w2f, DFF / 32, Hh / 16, Hh);

  for (int t = 0; t < HOPS; ++t) {
    const float* pe_t = pe + (size_t)t * Hh;
    int* cnt_t = cntp + t;
    compact_kernel<<<BS / 1024, 1024, 0, stream>>>(halting, idxbuf, cnt_t);
    halt_kernel<<<BS / 4, 256, 0, stream>>>(st, te, pe_t, wp, bp, halting,
                                            remainders, n_updates, uw_c,
                                            idxbuf, cnt_t);
    for (int mb = 0; mb < BS; mb += hrows) {
      stagex_kernel<<<hrows / 4, 256, 0, stream>>>(st, te, pe_t, xf, idxbuf,
                                                   cnt_t, mb, hrows, psa);
      gemm1_kernel<<<nst * 8, 512, 0, stream>>>(xf, w1f, b1, hf, cnt_t, mb,
                                                psa, psh, nst);
      gemm2f_kernel<<<nst * 2, 512, 0, stream>>>(hf, w2f, b2, uw_c, st, prev,
                                                 idxbuf, cnt_t, mb, psh, nst);
    }
  }
}

// Round 5
// 1082.058 us; speedup vs baseline: 1.0557x; 1.0557x over previous
//
#include <hip/hip_runtime.h>
#include <math.h>

typedef short short8 __attribute__((ext_vector_type(8)));
typedef float floatx4 __attribute__((ext_vector_type(4)));

#define Bb 64
#define Ss 512
#define Hh 512
#define DFF 2048
#define HOPS 6
#define BS (Bb*Ss)          // 32768 positions
#define PS 1048576          // weight plane stride (elems), both w1f and w2f
#define BUFSZ 24576         // per k-step buffer: A 8KB + B 16KB (BM=64,BN=128)

// ---------------- fp32 -> 2x bf16 split (RNE, exact residual) --------------
// Manual bit-twiddle RNE (R1-proven). m240: hand-written v_cvt_pk inline asm
// is SLOWER than compiler-scheduled plain ops -- do not reintroduce.
__device__ inline unsigned bf16rne(float v) {
  union { float f; unsigned u; } a; a.f = v;
  return (a.u + 0x7fffu + ((a.u >> 16) & 1u)) >> 16;
}
__device__ inline void split2(float v, unsigned &h1, unsigned &h2) {
  h1 = bf16rne(v);
  union { unsigned u; float f; } b1; b1.u = h1 << 16;
  h2 = bf16rne(v - b1.f);
}
__device__ inline void split8_store2(const float* xs, unsigned short* dst,
                                     size_t psa) {
  unsigned q1[4], q2[4];
#pragma unroll
  for (int jj = 0; jj < 4; ++jj) {
    unsigned a1, a2, c1, c2;
    split2(xs[2*jj],   a1, a2);
    split2(xs[2*jj+1], c1, c2);
    q1[jj] = a1 | (c1 << 16);
    q2[jj] = a2 | (c2 << 16);
  }
  *(int4*)(dst)       = make_int4(q1[0], q1[1], q1[2], q1[3]);
  *(int4*)(dst + psa) = make_int4(q2[0], q2[1], q2[2], q2[3]);
}

// ---------------- async global->LDS 16B helper -----------------------------
__device__ __forceinline__ void gload16(const void* g, void* l) {
  __builtin_amdgcn_global_load_lds(
      (const __attribute__((address_space(1))) void*)g,
      (__attribute__((address_space(3))) void*)l, 16, 0, 0);
}

// ---------------- weight pre-split into fragment-linear planes -------------
__global__ __launch_bounds__(256) void prep_kernel(
    const float* __restrict__ w, unsigned short* __restrict__ wf,
    int K32, int NTOT, int N)
{
  int id = blockIdx.x * 256 + threadIdx.x;      // one per (k0,NT,lane)
  if (id >= K32 * NTOT * 64) return;
  int l  = id & 63;
  int NT = (id >> 6) % NTOT;
  int k0 = id / (64 * NTOT);
  int n  = NT * 16 + (l & 15);
  int kb = k0 * 32 + 8 * (l >> 4);
  float xs[8];
#pragma unroll
  for (int j = 0; j < 8; ++j) xs[j] = w[(size_t)(kb + j) * N + n];
  split8_store2(xs, wf + (size_t)id * 8, PS);
}

// ---------------- parallel compaction (order-free, outputs invariant) ------
// tzero: hop 0 has all positions active and halting[] uninitialized -> skip
// the read entirely (no memset needed).
__global__ __launch_bounds__(1024) void compact_kernel(
    const float* __restrict__ halting, int* __restrict__ idx,
    int* __restrict__ cnt, int tzero)
{
  __shared__ int wsum[16];
  __shared__ int wbase[16];
  __shared__ int s_base;
  int tid = threadIdx.x;
  int lane = tid & 63, wid = tid >> 6;
  int pos = blockIdx.x * 1024 + tid;
  int flag = tzero ? 1 : ((halting[pos] < 1.0f) ? 1 : 0);
  unsigned long long m = __ballot(flag);
  int pre = __popcll(m & ((1ull << lane) - 1ull));
  if (lane == 0) wsum[wid] = __popcll(m);
  __syncthreads();
  if (tid == 0) {
    int a = 0;
#pragma unroll
    for (int i = 0; i < 16; ++i) { wbase[i] = a; a += wsum[i]; }
    s_base = (a > 0) ? atomicAdd(cnt, a) : 0;
  }
  __syncthreads();
  if (flag) idx[s_base + wbase[wid] + pre] = pos;
}

// ---------------- halting / p kernel (pure fp32) ---------------------------
// tzero: hop 0 state (halting=rem=nup=0) is known -> skip loads of
// uninitialized buffers; all rows get written, initializing them.
__global__ __launch_bounds__(256) void halt_kernel(
    const float* __restrict__ st, const float* __restrict__ te,
    const float* __restrict__ pe_t, const float* __restrict__ wp,
    const float* __restrict__ bp, float* __restrict__ halting,
    float* __restrict__ remainders, float* __restrict__ n_updates,
    float* __restrict__ uw_c, const int* __restrict__ idxbuf,
    const int* __restrict__ cntp, int tzero)
{
  int cnt = *cntp;
  int i = blockIdx.x * 4 + (threadIdx.x >> 6);
  if (i >= cnt) return;
  int lane = threadIdx.x & 63;
  int pos = idxbuf[i];
  int s = pos & (Ss - 1);
  const float4* stv = (const float4*)(st + (size_t)pos * Hh);
  const float4* tev = (const float4*)(te + (size_t)s * Hh);
  const float4* pev = (const float4*)pe_t;
  const float4* wpv = (const float4*)wp;
  float sum = 0.f;
#pragma unroll
  for (int j = 0; j < 2; ++j) {
    int idx = lane + j * 64;
    float4 a = stv[idx], b = tev[idx], c = pev[idx], w = wpv[idx];
    sum += (a.x + b.x + c.x) * w.x + (a.y + b.y + c.y) * w.y +
           (a.z + b.z + c.z) * w.z + (a.w + b.w + c.w) * w.w;
  }
#pragma unroll
  for (int off = 32; off > 0; off >>= 1) sum += __shfl_xor(sum, off, 64);
  if (lane == 0) {
    float y = sum + bp[0];
    float p = 1.0f / (1.0f + expf(-y));
    const float THRESH = 1.0f - 0.1f;
    float h0  = tzero ? 0.f : halting[pos];
    float rem = tzero ? 0.f : remainders[pos];
    float nup = tzero ? 0.f : n_updates[pos];
    float still = (h0 < 1.0f) ? 1.f : 0.f;
    float cand  = h0 + p * still;
    float nh  = ((cand >  THRESH) ? 1.f : 0.f) * still;
    float st2 = ((cand <= THRESH) ? 1.f : 0.f) * still;
    h0  += p * st2;
    rem += nh * (1.0f - h0);
    h0  += nh * rem;
    nup += st2 + nh;
    float uwv = p * st2 + nh * rem;
    halting[pos]    = h0;
    remainders[pos] = rem;
    n_updates[pos]  = nup;
    uw_c[i]         = uwv;
  }
}

// ---- stage_x: split x = st+te+pe (gathered) into bf16x2 fragment planes ---
__global__ __launch_bounds__(256) void stagex_kernel(
    const float* __restrict__ st, const float* __restrict__ te,
    const float* __restrict__ pe_t, unsigned short* __restrict__ xf,
    const int* __restrict__ idxbuf, const int* __restrict__ cntp,
    int m_base, int mrows, size_t psa)
{
  const int K32 = Hh / 32;
  int cnt = *cntp;
  int rel = cnt - m_base;
  if (rel <= 0) return;
  if (rel > mrows) rel = mrows;
  int rows_pad = (rel + 127) & ~127;
  if (rows_pad > mrows) rows_pad = mrows;
  int id = blockIdx.x * 256 + threadIdx.x;
  int l = id & 63;
  int f = id >> 6;
  int mtile = f / K32, k0 = f - mtile * K32;
  if (mtile * 16 >= rows_pad) return;
  int m = m_base + mtile * 16 + (l & 15);
  int mc = (m < cnt) ? m : cnt - 1;
  int pos = idxbuf[mc];
  int kb = k0 * 32 + (l >> 4) * 8;
  const float* ap = st + (size_t)pos * Hh + kb;
  const float* tp = te + (size_t)(pos & (Ss - 1)) * Hh + kb;
  const float* pp = pe_t + kb;
  float4 xa = *(const float4*)ap, xb = *(const float4*)(ap + 4);
  float4 ta = *(const float4*)tp, tb = *(const float4*)(tp + 4);
  float4 pa = *(const float4*)pp, pb = *(const float4*)(pp + 4);
  float xs[8];
  xs[0] = xa.x + ta.x + pa.x; xs[1] = xa.y + ta.y + pa.y;
  xs[2] = xa.z + ta.z + pa.z; xs[3] = xa.w + ta.w + pa.w;
  xs[4] = xb.x + tb.x + pb.x; xs[5] = xb.y + tb.y + pb.y;
  xs[6] = xb.z + tb.z + pb.z; xs[7] = xb.w + tb.w + pb.w;
  split8_store2(xs, xf + ((size_t)f * 64 + l) * 8, psa);
}

// ======================= GEMM kernels (R3 sync structure) ==================
// BM=64, BN=128, 4 waves (2m x 2n), wave 64x... wave tile 32x64: 2mt x 4nt
// frags of 16x16x32, 3-limb products. LDS dbuf 2 x 24 KB = 48 KB ->
// 3 blocks/CU (12 waves/CU): more independent barrier groups per CU to
// cover each other's stage/barrier drains (R3 had 2). Per k-step: stage
// next buf (6 gloads/wave), s_waitcnt vmcnt(6) waits only the PREVIOUS
// stage, barrier, ds_read 12 x b128, MFMA 24, barrier.  (T3-min + T4)

// ---- GEMM1: h = relu(x @ w1 + b1), repacked to A-frag planes --------------
#define LSTR 66
__global__ __launch_bounds__(256, 3) void gemm1_kernel(
    const unsigned short* __restrict__ xf, const unsigned short* __restrict__ w1f,
    const float* __restrict__ b1, unsigned short* __restrict__ hf,
    const int* __restrict__ cntp, int m_base, size_t psa, size_t psh)
{
  __shared__ __align__(1024) char stage[2 * BUFSZ];
  const int K32 = Hh / 32, NTOT = DFF / 16;   // K32 = 16
  int lin = blockIdx.x;
  int gsz = gridDim.x;
  int q = gsz >> 3, r = gsz & 7;
  int xcd = lin & 7, idx0 = lin >> 3;
  int swz = (xcd < r) ? (xcd * (q + 1) + idx0)
                      : (r * (q + 1) + (xcd - r) * q + idx0);
  int strip = swz >> 4;          // 16 n-blocks of 128 over DFF
  int nb    = swz & 15;
  int cnt = *cntp;
  int m0 = strip * 64;
  if (m_base + m0 >= cnt) return;
  int tid = threadIdx.x, lane = tid & 63, w = tid >> 6;
  int wm = w >> 1, wn = w & 1;
  int n0 = nb * 128;
  int mtb0 = m0 >> 4, ntb0 = n0 >> 4;
  char* sptr = stage;

  // stage one 32-k slab: A (4 mtiles x 2 limbs, 8 KB) + B (8 ntiles x 2, 16 KB)
  auto stage_step = [&](int bsel, int kk) {
    unsigned so = (unsigned)bsel * (unsigned)BUFSZ;
#pragma unroll
    for (int j = 0; j < 6; ++j) {
      int u = w * 6 + j;                      // 0..7 A units, 8..23 B units
      if (u < 8) {
        int mtile = u >> 1, limb = u & 1;
        const unsigned short* g =
            xf + ((size_t)(mtb0 + mtile) * K32 + kk) * 512
               + (size_t)limb * psa + (size_t)lane * 8;
        gload16(g, sptr + so + (unsigned)u * 1024u);
      } else {
        int v = u - 8;
        int ntile = v >> 1, limb = v & 1;
        const unsigned short* g =
            w1f + ((size_t)kk * NTOT + (ntb0 + ntile)) * 512
                + (size_t)limb * PS + (size_t)lane * 8;
        gload16(g, sptr + so + 8192u + (unsigned)v * 1024u);
      }
    }
  };

  floatx4 acc[2][4];
#pragma unroll
  for (int i = 0; i < 2; ++i)
#pragma unroll
    for (int j = 0; j < 4; ++j) acc[i][j] = (floatx4){0.f, 0.f, 0.f, 0.f};

  stage_step(0, 0);
  for (int k0 = 0; k0 < K32; ++k0) {
    int cur = k0 & 1;
    if (k0 + 1 < K32) {
      stage_step(cur ^ 1, k0 + 1);
      asm volatile("s_waitcnt vmcnt(6)" ::: "memory");   // prev stage landed
    } else {
      asm volatile("s_waitcnt vmcnt(0)" ::: "memory");
    }
    __builtin_amdgcn_s_barrier();                        // all waves staged
    asm volatile("" ::: "memory");
    const char* sb = sptr + cur * BUFSZ + (size_t)lane * 16;
    short8 af[2][2], bf[2][4];
#pragma unroll
    for (int mt = 0; mt < 2; ++mt) {
      af[0][mt] = *(const short8*)(sb + ((wm * 2 + mt) * 2 + 0) * 1024);
      af[1][mt] = *(const short8*)(sb + ((wm * 2 + mt) * 2 + 1) * 1024);
    }
#pragma unroll
    for (int nt = 0; nt < 4; ++nt) {
      bf[0][nt] = *(const short8*)(sb + 8192 + ((wn * 4 + nt) * 2 + 0) * 1024);
      bf[1][nt] = *(const short8*)(sb + 8192 + ((wn * 4 + nt) * 2 + 1) * 1024);
    }
    __builtin_amdgcn_s_setprio(1);
#pragma unroll
    for (int mt = 0; mt < 2; ++mt)
#pragma unroll
      for (int nt = 0; nt < 4; ++nt) {
        floatx4 c = acc[mt][nt];
        c = __builtin_amdgcn_mfma_f32_16x16x32_bf16(af[1][mt], bf[0][nt], c, 0, 0, 0);
        c = __builtin_amdgcn_mfma_f32_16x16x32_bf16(af[0][mt], bf[1][nt], c, 0, 0, 0);
        c = __builtin_amdgcn_mfma_f32_16x16x32_bf16(af[0][mt], bf[0][nt], c, 0, 0, 0);
        acc[mt][nt] = c;
      }
    __builtin_amdgcn_s_setprio(0);
    asm volatile("" ::: "memory");
    __builtin_amdgcn_s_barrier();  // all reads done before next overwrite
  }
  // epilogue: relu + bias; repack C-frag -> A-frag in 16-row slices.
  // Per-wave private LDS slice in buffer 0 (dead: K32 even, last cur==1),
  // no barriers needed.
  {
    int r0 = (lane >> 4) * 4;
    int c0l = lane & 15;
    int mtb = mtb0 + wm * 2;
    int k2b = (n0 >> 5) + wn * 2;
    float* L = (float*)(void*)sptr + (size_t)w * (16 * LSTR);
    float bias[4];
#pragma unroll
    for (int nt = 0; nt < 4; ++nt) bias[nt] = b1[n0 + wn * 64 + nt * 16 + c0l];
#pragma unroll
    for (int mt = 0; mt < 2; ++mt) {
#pragma unroll
      for (int nt = 0; nt < 4; ++nt)
#pragma unroll
        for (int reg = 0; reg < 4; ++reg)
          L[(r0 + reg) * LSTR + nt * 16 + c0l] =
              fmaxf(acc[mt][nt][reg] + bias[nt], 0.f);
#pragma unroll
      for (int k2 = 0; k2 < 2; ++k2) {
        const float* rp = L + (lane & 15) * LSTR + k2 * 32 + (lane >> 4) * 8;
        float xs[8];
        float4 xa = *(const float4*)rp, xb = *(const float4*)(rp + 4);
        xs[0]=xa.x; xs[1]=xa.y; xs[2]=xa.z; xs[3]=xa.w;
        xs[4]=xb.x; xs[5]=xb.y; xs[6]=xb.z; xs[7]=xb.w;
        size_t f2 = (size_t)(mtb + mt) * 64 + (k2b + k2);
        split8_store2(xs, hf + (f2 * 64 + lane) * 8, psh);
      }
    }
  }
}

// ---- GEMM2f (FULL-K, fused bias + uw-blend scatter epilogue) --------------
// tzero: hop 0 -> prev is uninitialized and logically zero; skip the read.
__global__ __launch_bounds__(256, 3) void gemm2f_kernel(
    const unsigned short* __restrict__ hf, const unsigned short* __restrict__ w2f,
    const float* __restrict__ b2, const float* __restrict__ uw_c,
    float* __restrict__ st_out, float* __restrict__ prev,
    const int* __restrict__ idxbuf, const int* __restrict__ cntp,
    int m_base, size_t psh, int tzero)
{
  __shared__ __align__(1024) char stage[2 * BUFSZ];
  const int K32 = DFF / 32, NTOT = Hh / 16;   // K32 = 64
  int lin = blockIdx.x;
  int gsz = gridDim.x;
  int q = gsz >> 3, r = gsz & 7;
  int xcd = lin & 7, idx0 = lin >> 3;
  int swz = (xcd < r) ? (xcd * (q + 1) + idx0)
                      : (r * (q + 1) + (xcd - r) * q + idx0);
  int strip = swz >> 2, nb = swz & 3;         // 4 n-blocks of 128 over Hh
  int cnt = *cntp;
  int m0 = strip * 64;
  if (m_base + m0 >= cnt) return;
  int n0 = nb * 128;
  int tid = threadIdx.x, lane = tid & 63, w = tid >> 6;
  int wm = w >> 1, wn = w & 1;
  int mtb0 = m0 >> 4, ntb0 = n0 >> 4;
  char* sptr = stage;

  auto stage_step = [&](int bsel, int kk) {
    unsigned so = (unsigned)bsel * (unsigned)BUFSZ;
#pragma unroll
    for (int j = 0; j < 6; ++j) {
      int u = w * 6 + j;
      if (u < 8) {
        int mtile = u >> 1, limb = u & 1;
        const unsigned short* g =
            hf + ((size_t)(mtb0 + mtile) * K32 + kk) * 512
               + (size_t)limb * psh + (size_t)lane * 8;
        gload16(g, sptr + so + (unsigned)u * 1024u);
      } else {
        int v = u - 8;
        int ntile = v >> 1, limb = v & 1;
        const unsigned short* g =
            w2f + ((size_t)kk * NTOT + (ntb0 + ntile)) * 512
                + (size_t)limb * PS + (size_t)lane * 8;
        gload16(g, sptr + so + 8192u + (unsigned)v * 1024u);
      }
    }
  };

  floatx4 acc[2][4];
#pragma unroll
  for (int i = 0; i < 2; ++i)
#pragma unroll
    for (int j = 0; j < 4; ++j) acc[i][j] = (floatx4){0.f, 0.f, 0.f, 0.f};

  stage_step(0, 0);
  for (int k0 = 0; k0 < K32; ++k0) {
    int cur = k0 & 1;
    if (k0 + 1 < K32) {
      stage_step(cur ^ 1, k0 + 1);
      asm volatile("s_waitcnt vmcnt(6)" ::: "memory");
    } else {
      asm volatile("s_waitcnt vmcnt(0)" ::: "memory");
    }
    __builtin_amdgcn_s_barrier();
    asm volatile("" ::: "memory");
    const char* sb = sptr + cur * BUFSZ + (size_t)lane * 16;
    short8 af[2][2], bf[2][4];
#pragma unroll
    for (int mt = 0; mt < 2; ++mt) {
      af[0][mt] = *(const short8*)(sb + ((wm * 2 + mt) * 2 + 0) * 1024);
      af[1][mt] = *(const short8*)(sb + ((wm * 2 + mt) * 2 + 1) * 1024);
    }
#pragma unroll
    for (int nt = 0; nt < 4; ++nt) {
      bf[0][nt] = *(const short8*)(sb + 8192 + ((wn * 4 + nt) * 2 + 0) * 1024);
      bf[1][nt] = *(const short8*)(sb + 8192 + ((wn * 4 + nt) * 2 + 1) * 1024);
    }
#pragma unroll
    for (int mt = 0; mt < 2; ++mt)
#pragma unroll
      for (int nt = 0; nt < 4; ++nt) {
        floatx4 c = acc[mt][nt];
        c = __builtin_amdgcn_mfma_f32_16x16x32_bf16(af[1][mt], bf[0][nt], c, 0, 0, 0);
        c = __builtin_amdgcn_mfma_f32_16x16x32_bf16(af[0][mt], bf[1][nt], c, 0, 0, 0);
        c = __builtin_amdgcn_mfma_f32_16x16x32_bf16(af[0][mt], bf[0][nt], c, 0, 0, 0);
        acc[mt][nt] = c;
      }
    asm volatile("" ::: "memory");
    __builtin_amdgcn_s_barrier();
  }
  // fused epilogue: sv = acc + b2; st_out = sv; prev = sv*uw + prev*(1-uw)
  {
    int r0 = (lane >> 4) * 4;
    int c0l = lane & 15;
    int mtb = mtb0 + wm * 2;
    int njb = ntb0 + wn * 4;
    float bias[4];
#pragma unroll
    for (int nt = 0; nt < 4; ++nt) bias[nt] = b2[(njb + nt) * 16 + c0l];
#pragma unroll
    for (int mt = 0; mt < 2; ++mt) {
      int pos4[4]; float uw4[4]; bool ok4[4];
#pragma unroll
      for (int reg = 0; reg < 4; ++reg) {
        int m = m_base + (mtb + mt) * 16 + r0 + reg;
        ok4[reg] = (m < cnt);
        int mc = ok4[reg] ? m : 0;
        pos4[reg] = idxbuf[mc];
        uw4[reg]  = uw_c[mc];
      }
#pragma unroll
      for (int nt = 0; nt < 4; ++nt) {
        int col = (njb + nt) * 16 + c0l;
#pragma unroll
        for (int reg = 0; reg < 4; ++reg) {
          if (ok4[reg]) {
            float sv = acc[mt][nt][reg] + bias[nt];
            size_t off = (size_t)pos4[reg] * Hh + col;
            float pv = tzero ? 0.f : prev[off];
            st_out[off] = sv;
            prev[off] = sv * uw4[reg] + pv * (1.f - uw4[reg]);
          }
        }
      }
    }
  }
}

extern "C" void kernel_launch(void* const* d_in, const int* in_sizes, int n_in,
                              void* d_out, int out_size, void* d_ws, size_t ws_size,
                              hipStream_t stream) {
  const float* state  = (const float*)d_in[0];
  const float* te     = (const float*)d_in[2];
  const float* pe     = (const float*)d_in[3];
  const float* wp     = (const float*)d_in[4];
  const float* bp     = (const float*)d_in[5];
  const float* w1     = (const float*)d_in[6];
  const float* b1     = (const float*)d_in[7];
  const float* w2     = (const float*)d_in[8];
  const float* b2     = (const float*)d_in[9];

  float* out        = (float*)d_out;
  float* prev       = out;                          // BS*H (fully written @t0)
  float* remainders = out + (size_t)BS * Hh;        // BS   (fully written @t0)
  float* n_updates  = remainders + BS;              // BS   (fully written @t0)

  float*          st      = (float*)d_ws;           // BS*H (fully written @t0)
  float*          halting = st + (size_t)BS * Hh;   // BS   (fully written @t0)
  float*          uw_c    = halting + BS;           // BS
  int*            idxbuf  = (int*)(uw_c + BS);      // BS
  int*            cntp    = idxbuf + BS;            // 64 (one counter per hop)
  unsigned short* w1f     = (unsigned short*)(cntp + 64);   // 2*PS (4 MB)
  unsigned short* w2f     = w1f + 2 * (size_t)PS;           // 2*PS (4 MB)
  unsigned short* hf      = w2f + 2 * (size_t)PS;

  size_t fixed = (size_t)((char*)hf - (char*)d_ws);
  size_t avail = (ws_size > fixed) ? (ws_size - fixed) : 0;
  // per row: hf = 2*2048*2 = 8192 B ; xf = 2048 B
  int hrows = (int)((avail / 10240) & ~(size_t)127);
  if (hrows > 16384) hrows = 16384;  // keep hf chunk mostly L3-resident
  if (hrows < 128) hrows = 128;
  unsigned short* xf = (unsigned short*)((char*)hf + (size_t)hrows * DFF * 2 * 2);
  size_t psa = (size_t)hrows * Hh;    // xf plane stride (ushort elems)
  size_t psh = (size_t)hrows * DFF;   // hf plane stride (ushort elems)
  int nst64 = hrows / 64;

  // Only the hop counters need zeroing: all other state buffers are fully
  // written at hop 0 via the tzero paths (no 67 MB memcpy/memset passes).
  hipMemsetAsync(cntp, 0, 64 * sizeof(int), stream);

  prep_kernel<<<512, 256, 0, stream>>>(w1, w1f, Hh / 32, DFF / 16, DFF);
  prep_kernel<<<512, 256, 0, stream>>>(w2, w2f, DFF / 32, Hh / 16, Hh);

  for (int t = 0; t < HOPS; ++t) {
    const float* pe_t = pe + (size_t)t * Hh;
    int* cnt_t = cntp + t;
    int tz = (t == 0) ? 1 : 0;
    const float* st_src = tz ? state : st;   // hop 0 reads the input directly
    compact_kernel<<<BS / 1024, 1024, 0, stream>>>(halting, idxbuf, cnt_t, tz);
    halt_kernel<<<BS / 4, 256, 0, stream>>>(st_src, te, pe_t, wp, bp, halting,
                                            remainders, n_updates, uw_c,
                                            idxbuf, cnt_t, tz);
    for (int mb = 0; mb < BS; mb += hrows) {
      stagex_kernel<<<hrows / 4, 256, 0, stream>>>(st_src, te, pe_t, xf, idxbuf,
                                                   cnt_t, mb, hrows, psa);
      gemm1_kernel<<<nst64 * 16, 256, 0, stream>>>(xf, w1f, b1, hf, cnt_t, mb,
                                                   psa, psh);
      gemm2f_kernel<<<nst64 * 4, 256, 0, stream>>>(hf, w2f, b2, uw_c, st, prev,
                                                   idxbuf, cnt_t, mb, psh, tz);
    }
  }
}

// Round 6
// 961.472 us; speedup vs baseline: 1.1881x; 1.1254x over previous
//
#include <hip/hip_runtime.h>
#include <math.h>

typedef short short8 __attribute__((ext_vector_type(8)));
typedef float floatx4 __attribute__((ext_vector_type(4)));

#define Bb 64
#define Ss 512
#define Hh 512
#define DFF 2048
#define HOPS 6
#define BS (Bb*Ss)          // 32768 positions
#define PS 1048576          // weight plane stride (elems), both w1f and w2f

// ---------------- fp32 -> 2x bf16 split (RNE, exact residual) --------------
// Manual bit-twiddle RNE (R1-proven). m240: hand-written v_cvt_pk inline asm
// is SLOWER than compiler-scheduled plain ops -- do not reintroduce.
__device__ inline unsigned bf16rne(float v) {
  union { float f; unsigned u; } a; a.f = v;
  return (a.u + 0x7fffu + ((a.u >> 16) & 1u)) >> 16;
}
__device__ inline void split2(float v, unsigned &h1, unsigned &h2) {
  h1 = bf16rne(v);
  union { unsigned u; float f; } b1; b1.u = h1 << 16;
  h2 = bf16rne(v - b1.f);
}
__device__ inline void split8_store2(const float* xs, unsigned short* dst,
                                     size_t psa) {
  unsigned q1[4], q2[4];
#pragma unroll
  for (int jj = 0; jj < 4; ++jj) {
    unsigned a1, a2, c1, c2;
    split2(xs[2*jj],   a1, a2);
    split2(xs[2*jj+1], c1, c2);
    q1[jj] = a1 | (c1 << 16);
    q2[jj] = a2 | (c2 << 16);
  }
  *(int4*)(dst)       = make_int4(q1[0], q1[1], q1[2], q1[3]);
  *(int4*)(dst + psa) = make_int4(q2[0], q2[1], q2[2], q2[3]);
}

// ---------------- async global->LDS 16B helper -----------------------------
__device__ __forceinline__ void gload16(const void* g, void* l) {
  __builtin_amdgcn_global_load_lds(
      (const __attribute__((address_space(1))) void*)g,
      (__attribute__((address_space(3))) void*)l, 16, 0, 0);
}

// ---------------- weight pre-split into fragment-linear planes -------------
__global__ __launch_bounds__(256) void prep_kernel(
    const float* __restrict__ w, unsigned short* __restrict__ wf,
    int K32, int NTOT, int N)
{
  int id = blockIdx.x * 256 + threadIdx.x;      // one per (k0,NT,lane)
  if (id >= K32 * NTOT * 64) return;
  int l  = id & 63;
  int NT = (id >> 6) % NTOT;
  int k0 = id / (64 * NTOT);
  int n  = NT * 16 + (l & 15);
  int kb = k0 * 32 + 8 * (l >> 4);
  float xs[8];
#pragma unroll
  for (int j = 0; j < 8; ++j) xs[j] = w[(size_t)(kb + j) * N + n];
  split8_store2(xs, wf + (size_t)id * 8, PS);
}

// ---------------- parallel compaction (order-free, outputs invariant) ------
// tzero: hop 0 has all positions active and halting[] uninitialized -> skip
// the read entirely (no memset needed).
__global__ __launch_bounds__(1024) void compact_kernel(
    const float* __restrict__ halting, int* __restrict__ idx,
    int* __restrict__ cnt, int tzero)
{
  __shared__ int wsum[16];
  __shared__ int wbase[16];
  __shared__ int s_base;
  int tid = threadIdx.x;
  int lane = tid & 63, wid = tid >> 6;
  int pos = blockIdx.x * 1024 + tid;
  int flag = tzero ? 1 : ((halting[pos] < 1.0f) ? 1 : 0);
  unsigned long long m = __ballot(flag);
  int pre = __popcll(m & ((1ull << lane) - 1ull));
  if (lane == 0) wsum[wid] = __popcll(m);
  __syncthreads();
  if (tid == 0) {
    int a = 0;
#pragma unroll
    for (int i = 0; i < 16; ++i) { wbase[i] = a; a += wsum[i]; }
    s_base = (a > 0) ? atomicAdd(cnt, a) : 0;
  }
  __syncthreads();
  if (flag) idx[s_base + wbase[wid] + pre] = pos;
}

// ---------------- halting / p kernel (pure fp32) ---------------------------
// tzero: hop 0 state (halting=rem=nup=0) is known -> skip loads of
// uninitialized buffers; all rows get written, initializing them.
__global__ __launch_bounds__(256) void halt_kernel(
    const float* __restrict__ st, const float* __restrict__ te,
    const float* __restrict__ pe_t, const float* __restrict__ wp,
    const float* __restrict__ bp, float* __restrict__ halting,
    float* __restrict__ remainders, float* __restrict__ n_updates,
    float* __restrict__ uw_c, const int* __restrict__ idxbuf,
    const int* __restrict__ cntp, int tzero)
{
  int cnt = *cntp;
  int i = blockIdx.x * 4 + (threadIdx.x >> 6);
  if (i >= cnt) return;
  int lane = threadIdx.x & 63;
  int pos = idxbuf[i];
  int s = pos & (Ss - 1);
  const float4* stv = (const float4*)(st + (size_t)pos * Hh);
  const float4* tev = (const float4*)(te + (size_t)s * Hh);
  const float4* pev = (const float4*)pe_t;
  const float4* wpv = (const float4*)wp;
  float sum = 0.f;
#pragma unroll
  for (int j = 0; j < 2; ++j) {
    int idx = lane + j * 64;
    float4 a = stv[idx], b = tev[idx], c = pev[idx], w = wpv[idx];
    sum += (a.x + b.x + c.x) * w.x + (a.y + b.y + c.y) * w.y +
           (a.z + b.z + c.z) * w.z + (a.w + b.w + c.w) * w.w;
  }
#pragma unroll
  for (int off = 32; off > 0; off >>= 1) sum += __shfl_xor(sum, off, 64);
  if (lane == 0) {
    float y = sum + bp[0];
    float p = 1.0f / (1.0f + expf(-y));
    const float THRESH = 1.0f - 0.1f;
    float h0  = tzero ? 0.f : halting[pos];
    float rem = tzero ? 0.f : remainders[pos];
    float nup = tzero ? 0.f : n_updates[pos];
    float still = (h0 < 1.0f) ? 1.f : 0.f;
    float cand  = h0 + p * still;
    float nh  = ((cand >  THRESH) ? 1.f : 0.f) * still;
    float st2 = ((cand <= THRESH) ? 1.f : 0.f) * still;
    h0  += p * st2;
    rem += nh * (1.0f - h0);
    h0  += nh * rem;
    nup += st2 + nh;
    float uwv = p * st2 + nh * rem;
    halting[pos]    = h0;
    remainders[pos] = rem;
    n_updates[pos]  = nup;
    uw_c[i]         = uwv;
  }
}

// ---- stage_x: split x = st+te+pe (gathered) into bf16x2 fragment planes ---
__global__ __launch_bounds__(256) void stagex_kernel(
    const float* __restrict__ st, const float* __restrict__ te,
    const float* __restrict__ pe_t, unsigned short* __restrict__ xf,
    const int* __restrict__ idxbuf, const int* __restrict__ cntp,
    int m_base, int mrows, size_t psa)
{
  const int K32 = Hh / 32;
  int cnt = *cntp;
  int rel = cnt - m_base;
  if (rel <= 0) return;
  if (rel > mrows) rel = mrows;
  int rows_pad = (rel + 127) & ~127;
  if (rows_pad > mrows) rows_pad = mrows;
  int id = blockIdx.x * 256 + threadIdx.x;
  int l = id & 63;
  int f = id >> 6;
  int mtile = f / K32, k0 = f - mtile * K32;
  if (mtile * 16 >= rows_pad) return;
  int m = m_base + mtile * 16 + (l & 15);
  int mc = (m < cnt) ? m : cnt - 1;
  int pos = idxbuf[mc];
  int kb = k0 * 32 + (l >> 4) * 8;
  const float* ap = st + (size_t)pos * Hh + kb;
  const float* tp = te + (size_t)(pos & (Ss - 1)) * Hh + kb;
  const float* pp = pe_t + kb;
  float4 xa = *(const float4*)ap, xb = *(const float4*)(ap + 4);
  float4 ta = *(const float4*)tp, tb = *(const float4*)(tp + 4);
  float4 pa = *(const float4*)pp, pb = *(const float4*)(pp + 4);
  float xs[8];
  xs[0] = xa.x + ta.x + pa.x; xs[1] = xa.y + ta.y + pa.y;
  xs[2] = xa.z + ta.z + pa.z; xs[3] = xa.w + ta.w + pa.w;
  xs[4] = xb.x + tb.x + pb.x; xs[5] = xb.y + tb.y + pb.y;
  xs[6] = xb.z + tb.z + pb.z; xs[7] = xb.w + tb.w + pb.w;
  split8_store2(xs, xf + ((size_t)f * 64 + l) * 8, psa);
}

// ======================= GEMM kernels (R3-proven geometry) =================
// block 128x128, 4 waves (2m x 2n), wave 64x64 = 4x4 frags of 16x16x32,
// 3-limb products. LDS dbuf 2 x 32 KB = 64 KB -> 2 blocks/CU. Per k-step:
// stage next buf (8 gloads on waves 0-1 for A, 8 on waves 2-3 for B),
// s_waitcnt vmcnt(8) waits only the PREVIOUS stage (T3-min + T4), barrier,
// ds_read 16 x b128, 48 MFMA, barrier. Measured best of {this, 4-phase
// 128x256 (R4: -10%), BM=64 (R5: -8%)} -- do not deviate without A/B.

// ---- GEMM1: h = relu(x @ w1 + b1), repacked to A-frag planes --------------
#define LSTR 66
__global__ __launch_bounds__(256, 2) void gemm1_kernel(
    const unsigned short* __restrict__ xf, const unsigned short* __restrict__ w1f,
    const float* __restrict__ b1, unsigned short* __restrict__ hf,
    const int* __restrict__ cntp, int m_base, size_t psa, size_t psh)
{
  __shared__ __align__(1024) char stage[65536];
  const int K32 = Hh / 32, NTOT = DFF / 16;
  int lin = blockIdx.x;
  int gsz = gridDim.x;
  int q = gsz >> 3, r = gsz & 7;
  int xcd = lin & 7, idx0 = lin >> 3;
  int swz = (xcd < r) ? (xcd * (q + 1) + idx0)
                      : (r * (q + 1) + (xcd - r) * q + idx0);
  int strip = swz >> 4;
  int nb    = swz & 15;
  int cnt = *cntp;
  int m0 = strip * 128;
  if (m_base + m0 >= cnt) return;
  int tid = threadIdx.x, lane = tid & 63, w = tid >> 6;
  int wm = w >> 1, wn = w & 1;
  int n0 = nb * 128;
  int mtb0 = m0 >> 4, ntb0 = n0 >> 4;
  char* sptr = stage;

  auto stage_step = [&](int bsel, int kk) {
    unsigned so = (unsigned)bsel * 32768u;
    int t0 = (w & 1) * 4;
    if (w < 2) {
#pragma unroll
      for (int j = 0; j < 4; ++j) {
        int mtile = t0 + j;
        const unsigned short* g0 =
            xf + ((size_t)(mtb0 + mtile) * K32 + kk) * 512 + (size_t)lane * 8;
        gload16(g0,       sptr + so + (unsigned)(mtile * 2 + 0) * 1024u);
        gload16(g0 + psa, sptr + so + (unsigned)(mtile * 2 + 1) * 1024u);
      }
    } else {
#pragma unroll
      for (int j = 0; j < 4; ++j) {
        int ntile = t0 + j;
        const unsigned short* g0 =
            w1f + ((size_t)kk * NTOT + (ntb0 + ntile)) * 512 + (size_t)lane * 8;
        gload16(g0,      sptr + so + 16384u + (unsigned)(ntile * 2 + 0) * 1024u);
        gload16(g0 + PS, sptr + so + 16384u + (unsigned)(ntile * 2 + 1) * 1024u);
      }
    }
  };

  floatx4 acc[4][4];
#pragma unroll
  for (int i = 0; i < 4; ++i)
#pragma unroll
    for (int j = 0; j < 4; ++j) acc[i][j] = (floatx4){0.f, 0.f, 0.f, 0.f};

  stage_step(0, 0);
  for (int k0 = 0; k0 < K32; ++k0) {
    int cur = k0 & 1;
    if (k0 + 1 < K32) {
      stage_step(cur ^ 1, k0 + 1);
      asm volatile("s_waitcnt vmcnt(8)" ::: "memory");   // prev stage landed
    } else {
      asm volatile("s_waitcnt vmcnt(0)" ::: "memory");
    }
    __builtin_amdgcn_s_barrier();                        // all waves staged
    asm volatile("" ::: "memory");
    const char* sb = sptr + cur * 32768 + (size_t)lane * 16;
    short8 af[2][4], bf[2][4];
#pragma unroll
    for (int mt = 0; mt < 4; ++mt) {
      af[0][mt] = *(const short8*)(sb + ((wm * 4 + mt) * 2 + 0) * 1024);
      af[1][mt] = *(const short8*)(sb + ((wm * 4 + mt) * 2 + 1) * 1024);
    }
#pragma unroll
    for (int nt = 0; nt < 4; ++nt) {
      bf[0][nt] = *(const short8*)(sb + 16384 + ((wn * 4 + nt) * 2 + 0) * 1024);
      bf[1][nt] = *(const short8*)(sb + 16384 + ((wn * 4 + nt) * 2 + 1) * 1024);
    }
    __builtin_amdgcn_s_setprio(1);
#pragma unroll
    for (int mt = 0; mt < 4; ++mt)
#pragma unroll
      for (int nt = 0; nt < 4; ++nt) {
        floatx4 c = acc[mt][nt];
        c = __builtin_amdgcn_mfma_f32_16x16x32_bf16(af[1][mt], bf[0][nt], c, 0, 0, 0);
        c = __builtin_amdgcn_mfma_f32_16x16x32_bf16(af[0][mt], bf[1][nt], c, 0, 0, 0);
        c = __builtin_amdgcn_mfma_f32_16x16x32_bf16(af[0][mt], bf[0][nt], c, 0, 0, 0);
        acc[mt][nt] = c;
      }
    __builtin_amdgcn_s_setprio(0);
    asm volatile("" ::: "memory");
    __builtin_amdgcn_s_barrier();  // all reads done before next overwrite
  }
  // epilogue: relu + bias; repack C-frag -> A-frag in 16-row slices.
  // Per-wave private LDS slice in buffer 0 (dead: K32 even, last cur==1),
  // no barriers needed.
  {
    int r0 = (lane >> 4) * 4;
    int c0l = lane & 15;
    int mtb = mtb0 + wm * 4;
    int k2b = (n0 >> 5) + wn * 2;
    float* L = (float*)(void*)sptr + (size_t)w * (16 * LSTR);
    float bias[4];
#pragma unroll
    for (int nt = 0; nt < 4; ++nt) bias[nt] = b1[n0 + wn * 64 + nt * 16 + c0l];
#pragma unroll
    for (int mt = 0; mt < 4; ++mt) {
#pragma unroll
      for (int nt = 0; nt < 4; ++nt)
#pragma unroll
        for (int reg = 0; reg < 4; ++reg)
          L[(r0 + reg) * LSTR + nt * 16 + c0l] =
              fmaxf(acc[mt][nt][reg] + bias[nt], 0.f);
#pragma unroll
      for (int k2 = 0; k2 < 2; ++k2) {
        const float* rp = L + (lane & 15) * LSTR + k2 * 32 + (lane >> 4) * 8;
        float xs[8];
        float4 xa = *(const float4*)rp, xb = *(const float4*)(rp + 4);
        xs[0]=xa.x; xs[1]=xa.y; xs[2]=xa.z; xs[3]=xa.w;
        xs[4]=xb.x; xs[5]=xb.y; xs[6]=xb.z; xs[7]=xb.w;
        size_t f2 = (size_t)(mtb + mt) * 64 + (k2b + k2);
        split8_store2(xs, hf + (f2 * 64 + lane) * 8, psh);
      }
    }
  }
}

// ---- GEMM2f (FULL-K, fused bias + uw-blend scatter epilogue) --------------
// tzero: hop 0 -> prev is uninitialized and logically zero; skip the read.
// No setprio (m190 / R2-measured: hurts this lockstep GEMM).
__global__ __launch_bounds__(256, 2) void gemm2f_kernel(
    const unsigned short* __restrict__ hf, const unsigned short* __restrict__ w2f,
    const float* __restrict__ b2, const float* __restrict__ uw_c,
    float* __restrict__ st_out, float* __restrict__ prev,
    const int* __restrict__ idxbuf, const int* __restrict__ cntp,
    int m_base, size_t psh, int tzero)
{
  __shared__ __align__(1024) char stage[65536];
  const int K32 = DFF / 32, NTOT = Hh / 16;
  int lin = blockIdx.x;
  int gsz = gridDim.x;
  int q = gsz >> 3, r = gsz & 7;
  int xcd = lin & 7, idx0 = lin >> 3;
  int swz = (xcd < r) ? (xcd * (q + 1) + idx0)
                      : (r * (q + 1) + (xcd - r) * q + idx0);
  int strip = swz >> 2, nb = swz & 3;
  int cnt = *cntp;
  int m0 = strip * 128;
  if (m_base + m0 >= cnt) return;
  int n0 = nb * 128;
  int tid = threadIdx.x, lane = tid & 63, w = tid >> 6;
  int wm = w >> 1, wn = w & 1;
  int mtb0 = m0 >> 4, ntb0 = n0 >> 4;
  char* sptr = stage;

  auto stage_step = [&](int bsel, int kk) {
    unsigned so = (unsigned)bsel * 32768u;
    int t0 = (w & 1) * 4;
    if (w < 2) {
#pragma unroll
      for (int j = 0; j < 4; ++j) {
        int mtile = t0 + j;
        const unsigned short* g0 =
            hf + ((size_t)(mtb0 + mtile) * K32 + kk) * 512 + (size_t)lane * 8;
        gload16(g0,       sptr + so + (unsigned)(mtile * 2 + 0) * 1024u);
        gload16(g0 + psh, sptr + so + (unsigned)(mtile * 2 + 1) * 1024u);
      }
    } else {
#pragma unroll
      for (int j = 0; j < 4; ++j) {
        int ntile = t0 + j;
        const unsigned short* g0 =
            w2f + ((size_t)kk * NTOT + (ntb0 + ntile)) * 512 + (size_t)lane * 8;
        gload16(g0,      sptr + so + 16384u + (unsigned)(ntile * 2 + 0) * 1024u);
        gload16(g0 + PS, sptr + so + 16384u + (unsigned)(ntile * 2 + 1) * 1024u);
      }
    }
  };

  floatx4 acc[4][4];
#pragma unroll
  for (int i = 0; i < 4; ++i)
#pragma unroll
    for (int j = 0; j < 4; ++j) acc[i][j] = (floatx4){0.f, 0.f, 0.f, 0.f};

  stage_step(0, 0);
  for (int k0 = 0; k0 < K32; ++k0) {
    int cur = k0 & 1;
    if (k0 + 1 < K32) {
      stage_step(cur ^ 1, k0 + 1);
      asm volatile("s_waitcnt vmcnt(8)" ::: "memory");
    } else {
      asm volatile("s_waitcnt vmcnt(0)" ::: "memory");
    }
    __builtin_amdgcn_s_barrier();
    asm volatile("" ::: "memory");
    const char* sb = sptr + cur * 32768 + (size_t)lane * 16;
    short8 af[2][4], bf[2][4];
#pragma unroll
    for (int mt = 0; mt < 4; ++mt) {
      af[0][mt] = *(const short8*)(sb + ((wm * 4 + mt) * 2 + 0) * 1024);
      af[1][mt] = *(const short8*)(sb + ((wm * 4 + mt) * 2 + 1) * 1024);
    }
#pragma unroll
    for (int nt = 0; nt < 4; ++nt) {
      bf[0][nt] = *(const short8*)(sb + 16384 + ((wn * 4 + nt) * 2 + 0) * 1024);
      bf[1][nt] = *(const short8*)(sb + 16384 + ((wn * 4 + nt) * 2 + 1) * 1024);
    }
#pragma unroll
    for (int mt = 0; mt < 4; ++mt)
#pragma unroll
      for (int nt = 0; nt < 4; ++nt) {
        floatx4 c = acc[mt][nt];
        c = __builtin_amdgcn_mfma_f32_16x16x32_bf16(af[1][mt], bf[0][nt], c, 0, 0, 0);
        c = __builtin_amdgcn_mfma_f32_16x16x32_bf16(af[0][mt], bf[1][nt], c, 0, 0, 0);
        c = __builtin_amdgcn_mfma_f32_16x16x32_bf16(af[0][mt], bf[0][nt], c, 0, 0, 0);
        acc[mt][nt] = c;
      }
    asm volatile("" ::: "memory");
    __builtin_amdgcn_s_barrier();
  }
  // fused epilogue: sv = acc + b2; st_out = sv; prev = sv*uw + prev*(1-uw)
  {
    int r0 = (lane >> 4) * 4;
    int c0l = lane & 15;
    int mtb = mtb0 + wm * 4;
    int njb = ntb0 + wn * 4;
    float bias[4];
#pragma unroll
    for (int nt = 0; nt < 4; ++nt) bias[nt] = b2[(njb + nt) * 16 + c0l];
#pragma unroll
    for (int mt = 0; mt < 4; ++mt) {
      int pos4[4]; float uw4[4]; bool ok4[4];
#pragma unroll
      for (int reg = 0; reg < 4; ++reg) {
        int m = m_base + (mtb + mt) * 16 + r0 + reg;
        ok4[reg] = (m < cnt);
        int mc = ok4[reg] ? m : 0;
        pos4[reg] = idxbuf[mc];
        uw4[reg]  = uw_c[mc];
      }
#pragma unroll
      for (int nt = 0; nt < 4; ++nt) {
        int col = (njb + nt) * 16 + c0l;
#pragma unroll
        for (int reg = 0; reg < 4; ++reg) {
          if (ok4[reg]) {
            float sv = acc[mt][nt][reg] + bias[nt];
            size_t off = (size_t)pos4[reg] * Hh + col;
            float pv = tzero ? 0.f : prev[off];
            st_out[off] = sv;
            prev[off] = sv * uw4[reg] + pv * (1.f - uw4[reg]);
          }
        }
      }
    }
  }
}

extern "C" void kernel_launch(void* const* d_in, const int* in_sizes, int n_in,
                              void* d_out, int out_size, void* d_ws, size_t ws_size,
                              hipStream_t stream) {
  const float* state  = (const float*)d_in[0];
  const float* te     = (const float*)d_in[2];
  const float* pe     = (const float*)d_in[3];
  const float* wp     = (const float*)d_in[4];
  const float* bp     = (const float*)d_in[5];
  const float* w1     = (const float*)d_in[6];
  const float* b1     = (const float*)d_in[7];
  const float* w2     = (const float*)d_in[8];
  const float* b2     = (const float*)d_in[9];

  float* out        = (float*)d_out;
  float* prev       = out;                          // BS*H (fully written @t0)
  float* remainders = out + (size_t)BS * Hh;        // BS   (fully written @t0)
  float* n_updates  = remainders + BS;              // BS   (fully written @t0)

  float*          st      = (float*)d_ws;           // BS*H (fully written @t0)
  float*          halting = st + (size_t)BS * Hh;   // BS   (fully written @t0)
  float*          uw_c    = halting + BS;           // BS
  int*            idxbuf  = (int*)(uw_c + BS);      // BS
  int*            cntp    = idxbuf + BS;            // 64 (one counter per hop)
  unsigned short* w1f     = (unsigned short*)(cntp + 64);   // 2*PS (4 MB)
  unsigned short* w2f     = w1f + 2 * (size_t)PS;           // 2*PS (4 MB)
  unsigned short* hf      = w2f + 2 * (size_t)PS;

  size_t fixed = (size_t)((char*)hf - (char*)d_ws);
  size_t avail = (ws_size > fixed) ? (ws_size - fixed) : 0;
  // per row: hf = 2*2048*2 = 8192 B ; xf = 2048 B
  int hrows = (int)((avail / 10240) & ~(size_t)127);
  if (hrows > 16384) hrows = 16384;  // keep hf chunk mostly L3-resident
  if (hrows < 128) hrows = 128;
  unsigned short* xf = (unsigned short*)((char*)hf + (size_t)hrows * DFF * 2 * 2);
  size_t psa = (size_t)hrows * Hh;    // xf plane stride (ushort elems)
  size_t psh = (size_t)hrows * DFF;   // hf plane stride (ushort elems)
  int nst = hrows / 128;

  // Only the hop counters need zeroing: all other state buffers are fully
  // written at hop 0 via the tzero paths (no 67 MB memcpy/memset passes).
  hipMemsetAsync(cntp, 0, 64 * sizeof(int), stream);

  prep_kernel<<<512, 256, 0, stream>>>(w1, w1f, Hh / 32, DFF / 16, DFF);
  prep_kernel<<<512, 256, 0, stream>>>(w2, w2f, DFF / 32, Hh / 16, Hh);

  for (int t = 0; t < HOPS; ++t) {
    const float* pe_t = pe + (size_t)t * Hh;
    int* cnt_t = cntp + t;
    int tz = (t == 0) ? 1 : 0;
    const float* st_src = tz ? state : st;   // hop 0 reads the input directly
    compact_kernel<<<BS / 1024, 1024, 0, stream>>>(halting, idxbuf, cnt_t, tz);
    halt_kernel<<<BS / 4, 256, 0, stream>>>(st_src, te, pe_t, wp, bp, halting,
                                            remainders, n_updates, uw_c,
                                            idxbuf, cnt_t, tz);
    for (int mb = 0; mb < BS; mb += hrows) {
      stagex_kernel<<<hrows / 4, 256, 0, stream>>>(st_src, te, pe_t, xf, idxbuf,
                                                   cnt_t, mb, hrows, psa);
      gemm1_kernel<<<nst * 16, 256, 0, stream>>>(xf, w1f, b1, hf, cnt_t, mb,
                                                 psa, psh);
      gemm2f_kernel<<<nst * 4, 256, 0, stream>>>(hf, w2f, b2, uw_c, st, prev,
                                                 idxbuf, cnt_t, mb, psh, tz);
    }
  }
}

// Round 7
// 777.402 us; speedup vs baseline: 1.4694x; 1.2368x over previous
//
#include <hip/hip_runtime.h>
#include <math.h>

typedef short short8 __attribute__((ext_vector_type(8)));
typedef _Float16 half8 __attribute__((ext_vector_type(8)));
typedef float floatx4 __attribute__((ext_vector_type(4)));

#define Bb 64
#define Ss 512
#define Hh 512
#define DFF 2048
#define HOPS 6
#define BS (Bb*Ss)          // 32768 positions
#define PS 1048576          // weight plane stride (elems), both w1f and w2f
#define BUFSZ 24576         // stage buffer: A 8KB (1 limb) + B 16KB (2 limbs)
#define RSCALE 2048.0f      // weight limb-2 scale (2^11 = fp16 ulp^-1)
#define RINV   (1.0f/2048.0f)

// ---------------- fp16 pack helpers ---------------------------------------
// A-side (x, h): SINGLE fp16 plane. Dominant scheme error = 2^-11 |a|,
// ~3e-4 at output -- under the 0.0039 absmax floor observed across all
// rounds (floor is not GEMM-limb-driven; halting decisions have 0.25 margin
// so no flip risk). B-side (weights): 2 fp16 limbs, limb2 scaled by 2048
// into fp16 normal range (avoids subnormal flush), second accumulator,
// epilogue combines main + lo/2048.
__device__ inline unsigned short f16u(float v) {
  _Float16 h = (_Float16)v;
  union { _Float16 h; unsigned short u; } c; c.h = h; return c.u;
}
__device__ inline void split8_store1(const float* xs, unsigned short* dst) {
  unsigned q[4];
#pragma unroll
  for (int j = 0; j < 4; ++j)
    q[j] = (unsigned)f16u(xs[2*j]) | ((unsigned)f16u(xs[2*j+1]) << 16);
  *(int4*)dst = make_int4(q[0], q[1], q[2], q[3]);
}
__device__ inline void split8_store2w(const float* xs, unsigned short* dst,
                                      size_t ps) {
  unsigned q1[4], q2[4];
#pragma unroll
  for (int j = 0; j < 4; ++j) {
    float lo = xs[2*j], hi = xs[2*j+1];
    _Float16 l1 = (_Float16)lo, h1 = (_Float16)hi;
    union { _Float16 h; unsigned short u; } cl, ch;
    cl.h = l1; ch.h = h1;
    q1[j] = (unsigned)cl.u | ((unsigned)ch.u << 16);
    float rl = (lo - (float)l1) * RSCALE, rh = (hi - (float)h1) * RSCALE;
    q2[j] = (unsigned)f16u(rl) | ((unsigned)f16u(rh) << 16);
  }
  *(int4*)(dst)      = make_int4(q1[0], q1[1], q1[2], q1[3]);
  *(int4*)(dst + ps) = make_int4(q2[0], q2[1], q2[2], q2[3]);
}

// ---------------- async global->LDS 16B helper -----------------------------
__device__ __forceinline__ void gload16(const void* g, void* l) {
  __builtin_amdgcn_global_load_lds(
      (const __attribute__((address_space(1))) void*)g,
      (__attribute__((address_space(3))) void*)l, 16, 0, 0);
}

// ---------------- weight pre-split into fragment-linear fp16 planes -------
__global__ __launch_bounds__(256) void prep_kernel(
    const float* __restrict__ w, unsigned short* __restrict__ wf,
    int K32, int NTOT, int N)
{
  int id = blockIdx.x * 256 + threadIdx.x;      // one per (k0,NT,lane)
  if (id >= K32 * NTOT * 64) return;
  int l  = id & 63;
  int NT = (id >> 6) % NTOT;
  int k0 = id / (64 * NTOT);
  int n  = NT * 16 + (l & 15);
  int kb = k0 * 32 + 8 * (l >> 4);
  float xs[8];
#pragma unroll
  for (int j = 0; j < 8; ++j) xs[j] = w[(size_t)(kb + j) * N + n];
  split8_store2w(xs, wf + (size_t)id * 8, PS);
}

// ---------------- parallel compaction (order-free, outputs invariant) ------
__global__ __launch_bounds__(1024) void compact_kernel(
    const float* __restrict__ halting, int* __restrict__ idx,
    int* __restrict__ cnt, int tzero)
{
  __shared__ int wsum[16];
  __shared__ int wbase[16];
  __shared__ int s_base;
  int tid = threadIdx.x;
  int lane = tid & 63, wid = tid >> 6;
  int pos = blockIdx.x * 1024 + tid;
  int flag = tzero ? 1 : ((halting[pos] < 1.0f) ? 1 : 0);
  unsigned long long m = __ballot(flag);
  int pre = __popcll(m & ((1ull << lane) - 1ull));
  if (lane == 0) wsum[wid] = __popcll(m);
  __syncthreads();
  if (tid == 0) {
    int a = 0;
#pragma unroll
    for (int i = 0; i < 16; ++i) { wbase[i] = a; a += wsum[i]; }
    s_base = (a > 0) ? atomicAdd(cnt, a) : 0;
  }
  __syncthreads();
  if (flag) idx[s_base + wbase[wid] + pre] = pos;
}

// ---------------- halting / p kernel (pure fp32) ---------------------------
__global__ __launch_bounds__(256) void halt_kernel(
    const float* __restrict__ st, const float* __restrict__ te,
    const float* __restrict__ pe_t, const float* __restrict__ wp,
    const float* __restrict__ bp, float* __restrict__ halting,
    float* __restrict__ remainders, float* __restrict__ n_updates,
    float* __restrict__ uw_c, const int* __restrict__ idxbuf,
    const int* __restrict__ cntp, int tzero)
{
  int cnt = *cntp;
  int i = blockIdx.x * 4 + (threadIdx.x >> 6);
  if (i >= cnt) return;
  int lane = threadIdx.x & 63;
  int pos = idxbuf[i];
  int s = pos & (Ss - 1);
  const float4* stv = (const float4*)(st + (size_t)pos * Hh);
  const float4* tev = (const float4*)(te + (size_t)s * Hh);
  const float4* pev = (const float4*)pe_t;
  const float4* wpv = (const float4*)wp;
  float sum = 0.f;
#pragma unroll
  for (int j = 0; j < 2; ++j) {
    int idx = lane + j * 64;
    float4 a = stv[idx], b = tev[idx], c = pev[idx], w = wpv[idx];
    sum += (a.x + b.x + c.x) * w.x + (a.y + b.y + c.y) * w.y +
           (a.z + b.z + c.z) * w.z + (a.w + b.w + c.w) * w.w;
  }
#pragma unroll
  for (int off = 32; off > 0; off >>= 1) sum += __shfl_xor(sum, off, 64);
  if (lane == 0) {
    float y = sum + bp[0];
    float p = 1.0f / (1.0f + expf(-y));
    const float THRESH = 1.0f - 0.1f;
    float h0  = tzero ? 0.f : halting[pos];
    float rem = tzero ? 0.f : remainders[pos];
    float nup = tzero ? 0.f : n_updates[pos];
    float still = (h0 < 1.0f) ? 1.f : 0.f;
    float cand  = h0 + p * still;
    float nh  = ((cand >  THRESH) ? 1.f : 0.f) * still;
    float st2 = ((cand <= THRESH) ? 1.f : 0.f) * still;
    h0  += p * st2;
    rem += nh * (1.0f - h0);
    h0  += nh * rem;
    nup += st2 + nh;
    float uwv = p * st2 + nh * rem;
    halting[pos]    = h0;
    remainders[pos] = rem;
    n_updates[pos]  = nup;
    uw_c[i]         = uwv;
  }
}

// ---- stage_x: x = st+te+pe (gathered) into single fp16 fragment plane -----
__global__ __launch_bounds__(256) void stagex_kernel(
    const float* __restrict__ st, const float* __restrict__ te,
    const float* __restrict__ pe_t, unsigned short* __restrict__ xf,
    const int* __restrict__ idxbuf, const int* __restrict__ cntp,
    int m_base, int mrows)
{
  const int K32 = Hh / 32;
  int cnt = *cntp;
  int rel = cnt - m_base;
  if (rel <= 0) return;
  if (rel > mrows) rel = mrows;
  int rows_pad = (rel + 127) & ~127;
  if (rows_pad > mrows) rows_pad = mrows;
  int id = blockIdx.x * 256 + threadIdx.x;
  int l = id & 63;
  int f = id >> 6;
  int mtile = f / K32, k0 = f - mtile * K32;
  if (mtile * 16 >= rows_pad) return;
  int m = m_base + mtile * 16 + (l & 15);
  int mc = (m < cnt) ? m : cnt - 1;
  int pos = idxbuf[mc];
  int kb = k0 * 32 + (l >> 4) * 8;
  const float* ap = st + (size_t)pos * Hh + kb;
  const float* tp = te + (size_t)(pos & (Ss - 1)) * Hh + kb;
  const float* pp = pe_t + kb;
  float4 xa = *(const float4*)ap, xb = *(const float4*)(ap + 4);
  float4 ta = *(const float4*)tp, tb = *(const float4*)(tp + 4);
  float4 pa = *(const float4*)pp, pb = *(const float4*)(pp + 4);
  float xs[8];
  xs[0] = xa.x + ta.x + pa.x; xs[1] = xa.y + ta.y + pa.y;
  xs[2] = xa.z + ta.z + pa.z; xs[3] = xa.w + ta.w + pa.w;
  xs[4] = xb.x + tb.x + pb.x; xs[5] = xb.y + tb.y + pb.y;
  xs[6] = xb.z + tb.z + pb.z; xs[7] = xb.w + tb.w + pb.w;
  split8_store1(xs, xf + ((size_t)f * 64 + l) * 8);
}

// ======================= GEMM kernels (R6 sync structure) ==================
// block 128x128, 4 waves (2m x 2n), wave 64x64 = 4x4 frags of 16x16x32 fp16,
// A single-limb + B 2-limb (limb2 scaled): 2 MFMA per frag pair into dual
// accumulators; epilogue combines main + lo/2048. LDS dbuf 2 x 24 KB.
// Per k-step: stage next buf (6 gloads/wave over 24 units), s_waitcnt
// vmcnt(6) waits only the PREVIOUS stage, barrier, 12 ds_read_b128,
// 32 MFMA, barrier. Sync pattern identical to R6 (measured best).

// ---- GEMM1: h = relu(x @ w1 + b1), stored as single fp16 A-frag plane -----
#define LSTR 66
__global__ __launch_bounds__(256, 2) void gemm1_kernel(
    const unsigned short* __restrict__ xf, const unsigned short* __restrict__ w1f,
    const float* __restrict__ b1, unsigned short* __restrict__ hf,
    const int* __restrict__ cntp, int m_base)
{
  __shared__ __align__(1024) char stage[2 * BUFSZ];
  const int K32 = Hh / 32, NTOT = DFF / 16;   // 16, 128
  int lin = blockIdx.x;
  int gsz = gridDim.x;
  int q = gsz >> 3, r = gsz & 7;
  int xcd = lin & 7, idx0 = lin >> 3;
  int swz = (xcd < r) ? (xcd * (q + 1) + idx0)
                      : (r * (q + 1) + (xcd - r) * q + idx0);
  int strip = swz >> 4;
  int nb    = swz & 15;
  int cnt = *cntp;
  int m0 = strip * 128;
  if (m_base + m0 >= cnt) return;
  int tid = threadIdx.x, lane = tid & 63, w = tid >> 6;
  int wm = w >> 1, wn = w & 1;
  int n0 = nb * 128;
  int mtb0 = m0 >> 4, ntb0 = n0 >> 4;
  char* sptr = stage;

  // 24 units: 0..7 = A mtile (1 limb), 8..23 = B (ntile, limb)
  auto stage_step = [&](int bsel, int kk) {
    unsigned so = (unsigned)bsel * (unsigned)BUFSZ;
#pragma unroll
    for (int j = 0; j < 6; ++j) {
      int u = w * 6 + j;
      if (u < 8) {
        const unsigned short* g =
            xf + ((size_t)(mtb0 + u) * K32 + kk) * 512 + (size_t)lane * 8;
        gload16(g, sptr + so + (unsigned)u * 1024u);
      } else {
        int v = u - 8;
        int ntile = v >> 1, limb = v & 1;
        const unsigned short* g =
            w1f + ((size_t)kk * NTOT + (ntb0 + ntile)) * 512
                + (size_t)limb * PS + (size_t)lane * 8;
        gload16(g, sptr + so + 8192u + (unsigned)v * 1024u);
      }
    }
  };

  floatx4 am[4][4], al[4][4];
#pragma unroll
  for (int i = 0; i < 4; ++i)
#pragma unroll
    for (int j = 0; j < 4; ++j) {
      am[i][j] = (floatx4){0.f, 0.f, 0.f, 0.f};
      al[i][j] = (floatx4){0.f, 0.f, 0.f, 0.f};
    }

  stage_step(0, 0);
  for (int k0 = 0; k0 < K32; ++k0) {
    int cur = k0 & 1;
    if (k0 + 1 < K32) {
      stage_step(cur ^ 1, k0 + 1);
      asm volatile("s_waitcnt vmcnt(6)" ::: "memory");   // prev stage landed
    } else {
      asm volatile("s_waitcnt vmcnt(0)" ::: "memory");
    }
    __builtin_amdgcn_s_barrier();                        // all waves staged
    asm volatile("" ::: "memory");
    const char* sb = sptr + cur * BUFSZ + (size_t)lane * 16;
    half8 af[4], bf[2][4];
#pragma unroll
    for (int mt = 0; mt < 4; ++mt)
      af[mt] = *(const half8*)(sb + (wm * 4 + mt) * 1024);
#pragma unroll
    for (int nt = 0; nt < 4; ++nt) {
      bf[0][nt] = *(const half8*)(sb + 8192 + ((wn * 4 + nt) * 2 + 0) * 1024);
      bf[1][nt] = *(const half8*)(sb + 8192 + ((wn * 4 + nt) * 2 + 1) * 1024);
    }
    __builtin_amdgcn_s_setprio(1);
#pragma unroll
    for (int mt = 0; mt < 4; ++mt)
#pragma unroll
      for (int nt = 0; nt < 4; ++nt) {
        am[mt][nt] = __builtin_amdgcn_mfma_f32_16x16x32_f16(af[mt], bf[0][nt],
                                                            am[mt][nt], 0, 0, 0);
        al[mt][nt] = __builtin_amdgcn_mfma_f32_16x16x32_f16(af[mt], bf[1][nt],
                                                            al[mt][nt], 0, 0, 0);
      }
    __builtin_amdgcn_s_setprio(0);
    asm volatile("" ::: "memory");
    __builtin_amdgcn_s_barrier();  // all reads done before next overwrite
  }
  // epilogue: relu + bias + limb combine; repack C-frag -> A-frag in 16-row
  // slices. Per-wave private LDS slice in buffer 0 (dead: last cur==1).
  {
    int r0 = (lane >> 4) * 4;
    int c0l = lane & 15;
    int mtb = mtb0 + wm * 4;
    int k2b = (n0 >> 5) + wn * 2;
    float* L = (float*)(void*)sptr + (size_t)w * (16 * LSTR);
    float bias[4];
#pragma unroll
    for (int nt = 0; nt < 4; ++nt) bias[nt] = b1[n0 + wn * 64 + nt * 16 + c0l];
#pragma unroll
    for (int mt = 0; mt < 4; ++mt) {
#pragma unroll
      for (int nt = 0; nt < 4; ++nt)
#pragma unroll
        for (int reg = 0; reg < 4; ++reg)
          L[(r0 + reg) * LSTR + nt * 16 + c0l] =
              fmaxf(am[mt][nt][reg] + al[mt][nt][reg] * RINV + bias[nt], 0.f);
#pragma unroll
      for (int k2 = 0; k2 < 2; ++k2) {
        const float* rp = L + (lane & 15) * LSTR + k2 * 32 + (lane >> 4) * 8;
        float xs[8];
        float4 xa = *(const float4*)rp, xb = *(const float4*)(rp + 4);
        xs[0]=xa.x; xs[1]=xa.y; xs[2]=xa.z; xs[3]=xa.w;
        xs[4]=xb.x; xs[5]=xb.y; xs[6]=xb.z; xs[7]=xb.w;
        size_t f2 = (size_t)(mtb + mt) * 64 + (k2b + k2);
        split8_store1(xs, hf + (f2 * 64 + lane) * 8);
      }
    }
  }
}

// ---- GEMM2f (FULL-K, fused bias + uw-blend scatter epilogue) --------------
__global__ __launch_bounds__(256, 2) void gemm2f_kernel(
    const unsigned short* __restrict__ hf, const unsigned short* __restrict__ w2f,
    const float* __restrict__ b2, const float* __restrict__ uw_c,
    float* __restrict__ st_out, float* __restrict__ prev,
    const int* __restrict__ idxbuf, const int* __restrict__ cntp,
    int m_base, int tzero)
{
  __shared__ __align__(1024) char stage[2 * BUFSZ];
  const int K32 = DFF / 32, NTOT = Hh / 16;   // 64, 32
  int lin = blockIdx.x;
  int gsz = gridDim.x;
  int q = gsz >> 3, r = gsz & 7;
  int xcd = lin & 7, idx0 = lin >> 3;
  int swz = (xcd < r) ? (xcd * (q + 1) + idx0)
                      : (r * (q + 1) + (xcd - r) * q + idx0);
  int strip = swz >> 2, nb = swz & 3;
  int cnt = *cntp;
  int m0 = strip * 128;
  if (m_base + m0 >= cnt) return;
  int n0 = nb * 128;
  int tid = threadIdx.x, lane = tid & 63, w = tid >> 6;
  int wm = w >> 1, wn = w & 1;
  int mtb0 = m0 >> 4, ntb0 = n0 >> 4;
  char* sptr = stage;

  auto stage_step = [&](int bsel, int kk) {
    unsigned so = (unsigned)bsel * (unsigned)BUFSZ;
#pragma unroll
    for (int j = 0; j < 6; ++j) {
      int u = w * 6 + j;
      if (u < 8) {
        const unsigned short* g =
            hf + ((size_t)(mtb0 + u) * K32 + kk) * 512 + (size_t)lane * 8;
        gload16(g, sptr + so + (unsigned)u * 1024u);
      } else {
        int v = u - 8;
        int ntile = v >> 1, limb = v & 1;
        const unsigned short* g =
            w2f + ((size_t)kk * NTOT + (ntb0 + ntile)) * 512
                + (size_t)limb * PS + (size_t)lane * 8;
        gload16(g, sptr + so + 8192u + (unsigned)v * 1024u);
      }
    }
  };

  floatx4 am[4][4], al[4][4];
#pragma unroll
  for (int i = 0; i < 4; ++i)
#pragma unroll
    for (int j = 0; j < 4; ++j) {
      am[i][j] = (floatx4){0.f, 0.f, 0.f, 0.f};
      al[i][j] = (floatx4){0.f, 0.f, 0.f, 0.f};
    }

  stage_step(0, 0);
  for (int k0 = 0; k0 < K32; ++k0) {
    int cur = k0 & 1;
    if (k0 + 1 < K32) {
      stage_step(cur ^ 1, k0 + 1);
      asm volatile("s_waitcnt vmcnt(6)" ::: "memory");
    } else {
      asm volatile("s_waitcnt vmcnt(0)" ::: "memory");
    }
    __builtin_amdgcn_s_barrier();
    asm volatile("" ::: "memory");
    const char* sb = sptr + cur * BUFSZ + (size_t)lane * 16;
    half8 af[4], bf[2][4];
#pragma unroll
    for (int mt = 0; mt < 4; ++mt)
      af[mt] = *(const half8*)(sb + (wm * 4 + mt) * 1024);
#pragma unroll
    for (int nt = 0; nt < 4; ++nt) {
      bf[0][nt] = *(const half8*)(sb + 8192 + ((wn * 4 + nt) * 2 + 0) * 1024);
      bf[1][nt] = *(const half8*)(sb + 8192 + ((wn * 4 + nt) * 2 + 1) * 1024);
    }
#pragma unroll
    for (int mt = 0; mt < 4; ++mt)
#pragma unroll
      for (int nt = 0; nt < 4; ++nt) {
        am[mt][nt] = __builtin_amdgcn_mfma_f32_16x16x32_f16(af[mt], bf[0][nt],
                                                            am[mt][nt], 0, 0, 0);
        al[mt][nt] = __builtin_amdgcn_mfma_f32_16x16x32_f16(af[mt], bf[1][nt],
                                                            al[mt][nt], 0, 0, 0);
      }
    asm volatile("" ::: "memory");
    __builtin_amdgcn_s_barrier();
  }
  // fused epilogue: sv = main + lo/2048 + b2; st_out = sv;
  // prev = sv*uw + prev*(1-uw)
  {
    int r0 = (lane >> 4) * 4;
    int c0l = lane & 15;
    int mtb = mtb0 + wm * 4;
    int njb = ntb0 + wn * 4;
    float bias[4];
#pragma unroll
    for (int nt = 0; nt < 4; ++nt) bias[nt] = b2[(njb + nt) * 16 + c0l];
#pragma unroll
    for (int mt = 0; mt < 4; ++mt) {
      int pos4[4]; float uw4[4]; bool ok4[4];
#pragma unroll
      for (int reg = 0; reg < 4; ++reg) {
        int m = m_base + (mtb + mt) * 16 + r0 + reg;
        ok4[reg] = (m < cnt);
        int mc = ok4[reg] ? m : 0;
        pos4[reg] = idxbuf[mc];
        uw4[reg]  = uw_c[mc];
      }
#pragma unroll
      for (int nt = 0; nt < 4; ++nt) {
        int col = (njb + nt) * 16 + c0l;
#pragma unroll
        for (int reg = 0; reg < 4; ++reg) {
          if (ok4[reg]) {
            float sv = am[mt][nt][reg] + al[mt][nt][reg] * RINV + bias[nt];
            size_t off = (size_t)pos4[reg] * Hh + col;
            float pv = tzero ? 0.f : prev[off];
            st_out[off] = sv;
            prev[off] = sv * uw4[reg] + pv * (1.f - uw4[reg]);
          }
        }
      }
    }
  }
}

extern "C" void kernel_launch(void* const* d_in, const int* in_sizes, int n_in,
                              void* d_out, int out_size, void* d_ws, size_t ws_size,
                              hipStream_t stream) {
  const float* state  = (const float*)d_in[0];
  const float* te     = (const float*)d_in[2];
  const float* pe     = (const float*)d_in[3];
  const float* wp     = (const float*)d_in[4];
  const float* bp     = (const float*)d_in[5];
  const float* w1     = (const float*)d_in[6];
  const float* b1     = (const float*)d_in[7];
  const float* w2     = (const float*)d_in[8];
  const float* b2     = (const float*)d_in[9];

  float* out        = (float*)d_out;
  float* prev       = out;                          // BS*H (fully written @t0)
  float* remainders = out + (size_t)BS * Hh;        // BS   (fully written @t0)
  float* n_updates  = remainders + BS;              // BS   (fully written @t0)

  float*          st      = (float*)d_ws;           // BS*H (fully written @t0)
  float*          halting = st + (size_t)BS * Hh;   // BS   (fully written @t0)
  float*          uw_c    = halting + BS;           // BS
  int*            idxbuf  = (int*)(uw_c + BS);      // BS
  int*            cntp    = idxbuf + BS;            // 64 (one counter per hop)
  unsigned short* w1f     = (unsigned short*)(cntp + 64);   // 2*PS (4 MB)
  unsigned short* w2f     = w1f + 2 * (size_t)PS;           // 2*PS (4 MB)
  unsigned short* hf      = w2f + 2 * (size_t)PS;

  size_t fixed = (size_t)((char*)hf - (char*)d_ws);
  size_t avail = (ws_size > fixed) ? (ws_size - fixed) : 0;
  // per row: hf = 2048*2 = 4096 B ; xf = 512*2 = 1024 B (single fp16 planes)
  int hrows = (int)((avail / 5120) & ~(size_t)127);
  if (hrows > 16384) hrows = 16384;
  if (hrows < 128) hrows = 128;
  unsigned short* xf = hf + (size_t)hrows * DFF;    // hf = hrows*DFF ushorts
  int nst = hrows / 128;

  // Only the hop counters need zeroing: all other state buffers are fully
  // written at hop 0 via the tzero paths.
  hipMemsetAsync(cntp, 0, 64 * sizeof(int), stream);

  prep_kernel<<<512, 256, 0, stream>>>(w1, w1f, Hh / 32, DFF / 16, DFF);
  prep_kernel<<<512, 256, 0, stream>>>(w2, w2f, DFF / 32, Hh / 16, Hh);

  for (int t = 0; t < HOPS; ++t) {
    const float* pe_t = pe + (size_t)t * Hh;
    int* cnt_t = cntp + t;
    int tz = (t == 0) ? 1 : 0;
    const float* st_src = tz ? state : st;   // hop 0 reads the input directly
    compact_kernel<<<BS / 1024, 1024, 0, stream>>>(halting, idxbuf, cnt_t, tz);
    halt_kernel<<<BS / 4, 256, 0, stream>>>(st_src, te, pe_t, wp, bp, halting,
                                            remainders, n_updates, uw_c,
                                            idxbuf, cnt_t, tz);
    for (int mb = 0; mb < BS; mb += hrows) {
      stagex_kernel<<<hrows / 4, 256, 0, stream>>>(st_src, te, pe_t, xf, idxbuf,
                                                   cnt_t, mb, hrows);
      gemm1_kernel<<<nst * 16, 256, 0, stream>>>(xf, w1f, b1, hf, cnt_t, mb);
      gemm2f_kernel<<<nst * 4, 256, 0, stream>>>(hf, w2f, b2, uw_c, st, prev,
                                                 idxbuf, cnt_t, mb, tz);
    }
  }
}

// Round 8
// 763.285 us; speedup vs baseline: 1.4966x; 1.0185x over previous
//
#include <hip/hip_runtime.h>
#include <math.h>

typedef short short8 __attribute__((ext_vector_type(8)));
typedef _Float16 half8 __attribute__((ext_vector_type(8)));
typedef float floatx4 __attribute__((ext_vector_type(4)));

#define Bb 64
#define Ss 512
#define Hh 512
#define DFF 2048
#define HOPS 6
#define BS (Bb*Ss)          // 32768 positions
#define PS 1048576          // weight plane stride (elems), both w1f and w2f
#define BUFSZ 24576         // stage buffer: A 8KB (1 limb) + B 16KB (2 limbs)
#define RSCALE 2048.0f      // weight limb-2 scale (2^11 = fp16 ulp^-1)
#define RINV   (1.0f/2048.0f)

// ---------------- fp16 pack helpers ---------------------------------------
// A-side (x, h): SINGLE fp16 plane (error 2^-11|a|, under the absmax floor;
// halting decisions have ~0.25 margin so no flip risk -- R7-verified).
// B-side (weights): 2 fp16 limbs, limb2 scaled by 2048 into normal range,
// dual accumulators, epilogue combines main + lo/2048.
__device__ inline unsigned short f16u(float v) {
  _Float16 h = (_Float16)v;
  union { _Float16 h; unsigned short u; } c; c.h = h; return c.u;
}
__device__ inline void split8_store1(const float* xs, unsigned short* dst) {
  unsigned q[4];
#pragma unroll
  for (int j = 0; j < 4; ++j)
    q[j] = (unsigned)f16u(xs[2*j]) | ((unsigned)f16u(xs[2*j+1]) << 16);
  *(int4*)dst = make_int4(q[0], q[1], q[2], q[3]);
}
__device__ inline void split8_store2w(const float* xs, unsigned short* dst,
                                      size_t ps) {
  unsigned q1[4], q2[4];
#pragma unroll
  for (int j = 0; j < 4; ++j) {
    float lo = xs[2*j], hi = xs[2*j+1];
    _Float16 l1 = (_Float16)lo, h1 = (_Float16)hi;
    union { _Float16 h; unsigned short u; } cl, ch;
    cl.h = l1; ch.h = h1;
    q1[j] = (unsigned)cl.u | ((unsigned)ch.u << 16);
    float rl = (lo - (float)l1) * RSCALE, rh = (hi - (float)h1) * RSCALE;
    q2[j] = (unsigned)f16u(rl) | ((unsigned)f16u(rh) << 16);
  }
  *(int4*)(dst)      = make_int4(q1[0], q1[1], q1[2], q1[3]);
  *(int4*)(dst + ps) = make_int4(q2[0], q2[1], q2[2], q2[3]);
}

// ---------------- async global->LDS 16B helper -----------------------------
__device__ __forceinline__ void gload16(const void* g, void* l) {
  __builtin_amdgcn_global_load_lds(
      (const __attribute__((address_space(1))) void*)g,
      (__attribute__((address_space(3))) void*)l, 16, 0, 0);
}

// ---------------- weight pre-split into fragment-linear fp16 planes -------
__global__ __launch_bounds__(256) void prep_kernel(
    const float* __restrict__ w, unsigned short* __restrict__ wf,
    int K32, int NTOT, int N)
{
  int id = blockIdx.x * 256 + threadIdx.x;      // one per (k0,NT,lane)
  if (id >= K32 * NTOT * 64) return;
  int l  = id & 63;
  int NT = (id >> 6) % NTOT;
  int k0 = id / (64 * NTOT);
  int n  = NT * 16 + (l & 15);
  int kb = k0 * 32 + 8 * (l >> 4);
  float xs[8];
#pragma unroll
  for (int j = 0; j < 8; ++j) xs[j] = w[(size_t)(kb + j) * N + n];
  split8_store2w(xs, wf + (size_t)id * 8, PS);
}

// ---------------- parallel compaction (order-free, outputs invariant) ------
__global__ __launch_bounds__(1024) void compact_kernel(
    const float* __restrict__ halting, int* __restrict__ idx,
    int* __restrict__ cnt, int tzero)
{
  __shared__ int wsum[16];
  __shared__ int wbase[16];
  __shared__ int s_base;
  int tid = threadIdx.x;
  int lane = tid & 63, wid = tid >> 6;
  int pos = blockIdx.x * 1024 + tid;
  int flag = tzero ? 1 : ((halting[pos] < 1.0f) ? 1 : 0);
  unsigned long long m = __ballot(flag);
  int pre = __popcll(m & ((1ull << lane) - 1ull));
  if (lane == 0) wsum[wid] = __popcll(m);
  __syncthreads();
  if (tid == 0) {
    int a = 0;
#pragma unroll
    for (int i = 0; i < 16; ++i) { wbase[i] = a; a += wsum[i]; }
    s_base = (a > 0) ? atomicAdd(cnt, a) : 0;
  }
  __syncthreads();
  if (flag) idx[s_base + wbase[wid] + pre] = pos;
}

// ---------------- halting / p kernel (pure fp32) ---------------------------
__global__ __launch_bounds__(256) void halt_kernel(
    const float* __restrict__ st, const float* __restrict__ te,
    const float* __restrict__ pe_t, const float* __restrict__ wp,
    const float* __restrict__ bp, float* __restrict__ halting,
    float* __restrict__ remainders, float* __restrict__ n_updates,
    float* __restrict__ uw_c, const int* __restrict__ idxbuf,
    const int* __restrict__ cntp, int tzero)
{
  int cnt = *cntp;
  int i = blockIdx.x * 4 + (threadIdx.x >> 6);
  if (i >= cnt) return;
  int lane = threadIdx.x & 63;
  int pos = idxbuf[i];
  int s = pos & (Ss - 1);
  const float4* stv = (const float4*)(st + (size_t)pos * Hh);
  const float4* tev = (const float4*)(te + (size_t)s * Hh);
  const float4* pev = (const float4*)pe_t;
  const float4* wpv = (const float4*)wp;
  float sum = 0.f;
#pragma unroll
  for (int j = 0; j < 2; ++j) {
    int idx = lane + j * 64;
    float4 a = stv[idx], b = tev[idx], c = pev[idx], w = wpv[idx];
    sum += (a.x + b.x + c.x) * w.x + (a.y + b.y + c.y) * w.y +
           (a.z + b.z + c.z) * w.z + (a.w + b.w + c.w) * w.w;
  }
#pragma unroll
  for (int off = 32; off > 0; off >>= 1) sum += __shfl_xor(sum, off, 64);
  if (lane == 0) {
    float y = sum + bp[0];
    float p = 1.0f / (1.0f + expf(-y));
    const float THRESH = 1.0f - 0.1f;
    float h0  = tzero ? 0.f : halting[pos];
    float rem = tzero ? 0.f : remainders[pos];
    float nup = tzero ? 0.f : n_updates[pos];
    float still = (h0 < 1.0f) ? 1.f : 0.f;
    float cand  = h0 + p * still;
    float nh  = ((cand >  THRESH) ? 1.f : 0.f) * still;
    float st2 = ((cand <= THRESH) ? 1.f : 0.f) * still;
    h0  += p * st2;
    rem += nh * (1.0f - h0);
    h0  += nh * rem;
    nup += st2 + nh;
    float uwv = p * st2 + nh * rem;
    halting[pos]    = h0;
    remainders[pos] = rem;
    n_updates[pos]  = nup;
    uw_c[i]         = uwv;
  }
}

// ---- stage_x: x = st+te+pe (gathered) into single fp16 fragment plane -----
__global__ __launch_bounds__(256) void stagex_kernel(
    const float* __restrict__ st, const float* __restrict__ te,
    const float* __restrict__ pe_t, unsigned short* __restrict__ xf,
    const int* __restrict__ idxbuf, const int* __restrict__ cntp,
    int m_base, int mrows)
{
  const int K32 = Hh / 32;
  int cnt = *cntp;
  int rel = cnt - m_base;
  if (rel <= 0) return;
  if (rel > mrows) rel = mrows;
  int rows_pad = (rel + 127) & ~127;
  if (rows_pad > mrows) rows_pad = mrows;
  int id = blockIdx.x * 256 + threadIdx.x;
  int l = id & 63;
  int f = id >> 6;
  int mtile = f / K32, k0 = f - mtile * K32;
  if (mtile * 16 >= rows_pad) return;
  int m = m_base + mtile * 16 + (l & 15);
  int mc = (m < cnt) ? m : cnt - 1;
  int pos = idxbuf[mc];
  int kb = k0 * 32 + (l >> 4) * 8;
  const float* ap = st + (size_t)pos * Hh + kb;
  const float* tp = te + (size_t)(pos & (Ss - 1)) * Hh + kb;
  const float* pp = pe_t + kb;
  float4 xa = *(const float4*)ap, xb = *(const float4*)(ap + 4);
  float4 ta = *(const float4*)tp, tb = *(const float4*)(tp + 4);
  float4 pa = *(const float4*)pp, pb = *(const float4*)(pp + 4);
  float xs[8];
  xs[0] = xa.x + ta.x + pa.x; xs[1] = xa.y + ta.y + pa.y;
  xs[2] = xa.z + ta.z + pa.z; xs[3] = xa.w + ta.w + pa.w;
  xs[4] = xb.x + tb.x + pb.x; xs[5] = xb.y + tb.y + pb.y;
  xs[6] = xb.z + tb.z + pb.z; xs[7] = xb.w + tb.w + pb.w;
  split8_store1(xs, xf + ((size_t)f * 64 + l) * 8);
}

// ======================= GEMM kernels (R6 sync structure) ==================
// block 128x128, 4 waves (2m x 2n), wave 64x64 = 4x4 frags of 16x16x32 fp16,
// A single-limb + B 2-limb: 2 MFMA per frag pair, dual accumulators.
// LDS dbuf 2 x 24 KB = 48 KB -> up to 3 blocks/CU when the grid provides
// them (single-chunk hrows=BS gives 1024+ blocks; R7's 2-chunk grid was
// exactly 2/CU = grid-limited). Per k-step: stage next buf (6 gloads/wave),
// s_waitcnt vmcnt(6) waits only the PREVIOUS stage, barrier, 12 ds_read,
// 32 MFMA, barrier. Sync pattern measured-best (R4/R5 deviations lost).

// ---- GEMM1: h = relu(x @ w1 + b1), stored as single fp16 A-frag plane -----
#define LSTR 66
__global__ __launch_bounds__(256, 2) void gemm1_kernel(
    const unsigned short* __restrict__ xf, const unsigned short* __restrict__ w1f,
    const float* __restrict__ b1, unsigned short* __restrict__ hf,
    const int* __restrict__ cntp, int m_base)
{
  __shared__ __align__(1024) char stage[2 * BUFSZ];
  const int K32 = Hh / 32, NTOT = DFF / 16;   // 16, 128
  int lin = blockIdx.x;
  int gsz = gridDim.x;
  int q = gsz >> 3, r = gsz & 7;
  int xcd = lin & 7, idx0 = lin >> 3;
  int swz = (xcd < r) ? (xcd * (q + 1) + idx0)
                      : (r * (q + 1) + (xcd - r) * q + idx0);
  int strip = swz >> 4;
  int nb    = swz & 15;
  int cnt = *cntp;
  int m0 = strip * 128;
  if (m_base + m0 >= cnt) return;
  int tid = threadIdx.x, lane = tid & 63, w = tid >> 6;
  int wm = w >> 1, wn = w & 1;
  int n0 = nb * 128;
  int mtb0 = m0 >> 4, ntb0 = n0 >> 4;
  char* sptr = stage;

  // 24 units: 0..7 = A mtile (1 limb), 8..23 = B (ntile, limb)
  auto stage_step = [&](int bsel, int kk) {
    unsigned so = (unsigned)bsel * (unsigned)BUFSZ;
#pragma unroll
    for (int j = 0; j < 6; ++j) {
      int u = w * 6 + j;
      if (u < 8) {
        const unsigned short* g =
            xf + ((size_t)(mtb0 + u) * K32 + kk) * 512 + (size_t)lane * 8;
        gload16(g, sptr + so + (unsigned)u * 1024u);
      } else {
        int v = u - 8;
        int ntile = v >> 1, limb = v & 1;
        const unsigned short* g =
            w1f + ((size_t)kk * NTOT + (ntb0 + ntile)) * 512
                + (size_t)limb * PS + (size_t)lane * 8;
        gload16(g, sptr + so + 8192u + (unsigned)v * 1024u);
      }
    }
  };

  floatx4 am[4][4], al[4][4];
#pragma unroll
  for (int i = 0; i < 4; ++i)
#pragma unroll
    for (int j = 0; j < 4; ++j) {
      am[i][j] = (floatx4){0.f, 0.f, 0.f, 0.f};
      al[i][j] = (floatx4){0.f, 0.f, 0.f, 0.f};
    }

  stage_step(0, 0);
  for (int k0 = 0; k0 < K32; ++k0) {
    int cur = k0 & 1;
    if (k0 + 1 < K32) {
      stage_step(cur ^ 1, k0 + 1);
      asm volatile("s_waitcnt vmcnt(6)" ::: "memory");   // prev stage landed
    } else {
      asm volatile("s_waitcnt vmcnt(0)" ::: "memory");
    }
    __builtin_amdgcn_s_barrier();                        // all waves staged
    asm volatile("" ::: "memory");
    const char* sb = sptr + cur * BUFSZ + (size_t)lane * 16;
    half8 af[4], bf[2][4];
#pragma unroll
    for (int mt = 0; mt < 4; ++mt)
      af[mt] = *(const half8*)(sb + (wm * 4 + mt) * 1024);
#pragma unroll
    for (int nt = 0; nt < 4; ++nt) {
      bf[0][nt] = *(const half8*)(sb + 8192 + ((wn * 4 + nt) * 2 + 0) * 1024);
      bf[1][nt] = *(const half8*)(sb + 8192 + ((wn * 4 + nt) * 2 + 1) * 1024);
    }
    __builtin_amdgcn_s_setprio(1);
#pragma unroll
    for (int mt = 0; mt < 4; ++mt)
#pragma unroll
      for (int nt = 0; nt < 4; ++nt) {
        am[mt][nt] = __builtin_amdgcn_mfma_f32_16x16x32_f16(af[mt], bf[0][nt],
                                                            am[mt][nt], 0, 0, 0);
        al[mt][nt] = __builtin_amdgcn_mfma_f32_16x16x32_f16(af[mt], bf[1][nt],
                                                            al[mt][nt], 0, 0, 0);
      }
    __builtin_amdgcn_s_setprio(0);
    asm volatile("" ::: "memory");
    __builtin_amdgcn_s_barrier();  // all reads done before next overwrite
  }
  // epilogue: relu + bias + limb combine; repack C-frag -> A-frag in 16-row
  // slices. Per-wave private LDS slice in buffer 0 (dead: last cur==1).
  {
    int r0 = (lane >> 4) * 4;
    int c0l = lane & 15;
    int mtb = mtb0 + wm * 4;
    int k2b = (n0 >> 5) + wn * 2;
    float* L = (float*)(void*)sptr + (size_t)w * (16 * LSTR);
    float bias[4];
#pragma unroll
    for (int nt = 0; nt < 4; ++nt) bias[nt] = b1[n0 + wn * 64 + nt * 16 + c0l];
#pragma unroll
    for (int mt = 0; mt < 4; ++mt) {
#pragma unroll
      for (int nt = 0; nt < 4; ++nt)
#pragma unroll
        for (int reg = 0; reg < 4; ++reg)
          L[(r0 + reg) * LSTR + nt * 16 + c0l] =
              fmaxf(am[mt][nt][reg] + al[mt][nt][reg] * RINV + bias[nt], 0.f);
#pragma unroll
      for (int k2 = 0; k2 < 2; ++k2) {
        const float* rp = L + (lane & 15) * LSTR + k2 * 32 + (lane >> 4) * 8;
        float xs[8];
        float4 xa = *(const float4*)rp, xb = *(const float4*)(rp + 4);
        xs[0]=xa.x; xs[1]=xa.y; xs[2]=xa.z; xs[3]=xa.w;
        xs[4]=xb.x; xs[5]=xb.y; xs[6]=xb.z; xs[7]=xb.w;
        size_t f2 = (size_t)(mtb + mt) * 64 + (k2b + k2);
        split8_store1(xs, hf + (f2 * 64 + lane) * 8);
      }
    }
  }
}

// ---- GEMM2f (FULL-K, fused bias + uw-blend scatter epilogue) --------------
__global__ __launch_bounds__(256, 2) void gemm2f_kernel(
    const unsigned short* __restrict__ hf, const unsigned short* __restrict__ w2f,
    const float* __restrict__ b2, const float* __restrict__ uw_c,
    float* __restrict__ st_out, float* __restrict__ prev,
    const int* __restrict__ idxbuf, const int* __restrict__ cntp,
    int m_base, int tzero)
{
  __shared__ __align__(1024) char stage[2 * BUFSZ];
  const int K32 = DFF / 32, NTOT = Hh / 16;   // 64, 32
  int lin = blockIdx.x;
  int gsz = gridDim.x;
  int q = gsz >> 3, r = gsz & 7;
  int xcd = lin & 7, idx0 = lin >> 3;
  int swz = (xcd < r) ? (xcd * (q + 1) + idx0)
                      : (r * (q + 1) + (xcd - r) * q + idx0);
  int strip = swz >> 2, nb = swz & 3;
  int cnt = *cntp;
  int m0 = strip * 128;
  if (m_base + m0 >= cnt) return;
  int n0 = nb * 128;
  int tid = threadIdx.x, lane = tid & 63, w = tid >> 6;
  int wm = w >> 1, wn = w & 1;
  int mtb0 = m0 >> 4, ntb0 = n0 >> 4;
  char* sptr = stage;

  auto stage_step = [&](int bsel, int kk) {
    unsigned so = (unsigned)bsel * (unsigned)BUFSZ;
#pragma unroll
    for (int j = 0; j < 6; ++j) {
      int u = w * 6 + j;
      if (u < 8) {
        const unsigned short* g =
            hf + ((size_t)(mtb0 + u) * K32 + kk) * 512 + (size_t)lane * 8;
        gload16(g, sptr + so + (unsigned)u * 1024u);
      } else {
        int v = u - 8;
        int ntile = v >> 1, limb = v & 1;
        const unsigned short* g =
            w2f + ((size_t)kk * NTOT + (ntb0 + ntile)) * 512
                + (size_t)limb * PS + (size_t)lane * 8;
        gload16(g, sptr + so + 8192u + (unsigned)v * 1024u);
      }
    }
  };

  floatx4 am[4][4], al[4][4];
#pragma unroll
  for (int i = 0; i < 4; ++i)
#pragma unroll
    for (int j = 0; j < 4; ++j) {
      am[i][j] = (floatx4){0.f, 0.f, 0.f, 0.f};
      al[i][j] = (floatx4){0.f, 0.f, 0.f, 0.f};
    }

  stage_step(0, 0);
  for (int k0 = 0; k0 < K32; ++k0) {
    int cur = k0 & 1;
    if (k0 + 1 < K32) {
      stage_step(cur ^ 1, k0 + 1);
      asm volatile("s_waitcnt vmcnt(6)" ::: "memory");
    } else {
      asm volatile("s_waitcnt vmcnt(0)" ::: "memory");
    }
    __builtin_amdgcn_s_barrier();
    asm volatile("" ::: "memory");
    const char* sb = sptr + cur * BUFSZ + (size_t)lane * 16;
    half8 af[4], bf[2][4];
#pragma unroll
    for (int mt = 0; mt < 4; ++mt)
      af[mt] = *(const half8*)(sb + (wm * 4 + mt) * 1024);
#pragma unroll
    for (int nt = 0; nt < 4; ++nt) {
      bf[0][nt] = *(const half8*)(sb + 8192 + ((wn * 4 + nt) * 2 + 0) * 1024);
      bf[1][nt] = *(const half8*)(sb + 8192 + ((wn * 4 + nt) * 2 + 1) * 1024);
    }
#pragma unroll
    for (int mt = 0; mt < 4; ++mt)
#pragma unroll
      for (int nt = 0; nt < 4; ++nt) {
        am[mt][nt] = __builtin_amdgcn_mfma_f32_16x16x32_f16(af[mt], bf[0][nt],
                                                            am[mt][nt], 0, 0, 0);
        al[mt][nt] = __builtin_amdgcn_mfma_f32_16x16x32_f16(af[mt], bf[1][nt],
                                                            al[mt][nt], 0, 0, 0);
      }
    asm volatile("" ::: "memory");
    __builtin_amdgcn_s_barrier();
  }
  // fused epilogue: sv = main + lo/2048 + b2; st_out = sv;
  // prev = sv*uw + prev*(1-uw)
  {
    int r0 = (lane >> 4) * 4;
    int c0l = lane & 15;
    int mtb = mtb0 + wm * 4;
    int njb = ntb0 + wn * 4;
    float bias[4];
#pragma unroll
    for (int nt = 0; nt < 4; ++nt) bias[nt] = b2[(njb + nt) * 16 + c0l];
#pragma unroll
    for (int mt = 0; mt < 4; ++mt) {
      int pos4[4]; float uw4[4]; bool ok4[4];
#pragma unroll
      for (int reg = 0; reg < 4; ++reg) {
        int m = m_base + (mtb + mt) * 16 + r0 + reg;
        ok4[reg] = (m < cnt);
        int mc = ok4[reg] ? m : 0;
        pos4[reg] = idxbuf[mc];
        uw4[reg]  = uw_c[mc];
      }
#pragma unroll
      for (int nt = 0; nt < 4; ++nt) {
        int col = (njb + nt) * 16 + c0l;
#pragma unroll
        for (int reg = 0; reg < 4; ++reg) {
          if (ok4[reg]) {
            float sv = am[mt][nt][reg] + al[mt][nt][reg] * RINV + bias[nt];
            size_t off = (size_t)pos4[reg] * Hh + col;
            float pv = tzero ? 0.f : prev[off];
            st_out[off] = sv;
            prev[off] = sv * uw4[reg] + pv * (1.f - uw4[reg]);
          }
        }
      }
    }
  }
}

extern "C" void kernel_launch(void* const* d_in, const int* in_sizes, int n_in,
                              void* d_out, int out_size, void* d_ws, size_t ws_size,
                              hipStream_t stream) {
  const float* state  = (const float*)d_in[0];
  const float* te     = (const float*)d_in[2];
  const float* pe     = (const float*)d_in[3];
  const float* wp     = (const float*)d_in[4];
  const float* bp     = (const float*)d_in[5];
  const float* w1     = (const float*)d_in[6];
  const float* b1     = (const float*)d_in[7];
  const float* w2     = (const float*)d_in[8];
  const float* b2     = (const float*)d_in[9];

  float* out        = (float*)d_out;
  float* prev       = out;                          // BS*H (fully written @t0)
  float* remainders = out + (size_t)BS * Hh;        // BS   (fully written @t0)
  float* n_updates  = remainders + BS;              // BS   (fully written @t0)

  float*          st      = (float*)d_ws;           // BS*H (fully written @t0)
  float*          halting = st + (size_t)BS * Hh;   // BS   (fully written @t0)
  float*          uw_c    = halting + BS;           // BS
  int*            idxbuf  = (int*)(uw_c + BS);      // BS
  int*            cntp    = idxbuf + BS;            // 64 (one counter per hop)
  unsigned short* w1f     = (unsigned short*)(cntp + 64);   // 2*PS (4 MB)
  unsigned short* w2f     = w1f + 2 * (size_t)PS;           // 2*PS (4 MB)
  unsigned short* hf      = w2f + 2 * (size_t)PS;

  size_t fixed = (size_t)((char*)hf - (char*)d_ws);
  size_t avail = (ws_size > fixed) ? (ws_size - fixed) : 0;
  // per row: hf = 2048*2 = 4096 B ; xf = 512*2 = 1024 B (single fp16 planes).
  // Single chunk (hrows=BS) when workspace allows: R7 FETCH evidence showed
  // hf is HBM-served regardless of chunk size, so the old L3-residency cap
  // only cost extra dispatch boundaries and kept the gemm2f grid at exactly
  // 2 blocks/CU (grid-limited; 48KB LDS allows 3/CU).
  int hrows = (int)((avail / 5120) & ~(size_t)127);
  if (hrows > BS) hrows = BS;
  if (hrows < 128) hrows = 128;
  unsigned short* xf = hf + (size_t)hrows * DFF;    // hf = hrows*DFF ushorts
  int nst = hrows / 128;

  // Only the hop counters need zeroing: all other state buffers are fully
  // written at hop 0 via the tzero paths.
  hipMemsetAsync(cntp, 0, 64 * sizeof(int), stream);

  prep_kernel<<<512, 256, 0, stream>>>(w1, w1f, Hh / 32, DFF / 16, DFF);
  prep_kernel<<<512, 256, 0, stream>>>(w2, w2f, DFF / 32, Hh / 16, Hh);

  for (int t = 0; t < HOPS; ++t) {
    const float* pe_t = pe + (size_t)t * Hh;
    int* cnt_t = cntp + t;
    int tz = (t == 0) ? 1 : 0;
    const float* st_src = tz ? state : st;   // hop 0 reads the input directly
    compact_kernel<<<BS / 1024, 1024, 0, stream>>>(halting, idxbuf, cnt_t, tz);
    halt_kernel<<<BS / 4, 256, 0, stream>>>(st_src, te, pe_t, wp, bp, halting,
                                            remainders, n_updates, uw_c,
                                            idxbuf, cnt_t, tz);
    for (int mb = 0; mb < BS; mb += hrows) {
      stagex_kernel<<<hrows / 4, 256, 0, stream>>>(st_src, te, pe_t, xf, idxbuf,
                                                   cnt_t, mb, hrows);
      gemm1_kernel<<<nst * 16, 256, 0, stream>>>(xf, w1f, b1, hf, cnt_t, mb);
      gemm2f_kernel<<<nst * 4, 256, 0, stream>>>(hf, w2f, b2, uw_c, st, prev,
                                                 idxbuf, cnt_t, mb, tz);
    }
  }
}

// Round 9
// 761.904 us; speedup vs baseline: 1.4993x; 1.0018x over previous
//
#include <hip/hip_runtime.h>
#include <math.h>

typedef short short8 __attribute__((ext_vector_type(8)));
typedef _Float16 half8 __attribute__((ext_vector_type(8)));
typedef float floatx4 __attribute__((ext_vector_type(4)));

#define Bb 64
#define Ss 512
#define Hh 512
#define DFF 2048
#define HOPS 6
#define BS (Bb*Ss)          // 32768 positions
#define PS 1048576          // weight plane stride (elems), both w1f and w2f
#define BUFSZ 24576         // stage buffer: A 8KB (1 limb) + B 16KB (2 limbs)
#define RSCALE 2048.0f      // weight limb-2 scale (2^11 = fp16 ulp^-1)
#define RINV   (1.0f/2048.0f)

// ---------------- fp16 pack helpers ---------------------------------------
// A-side (x, h): SINGLE fp16 plane (error 2^-11|a|, under the absmax floor;
// halting decisions have ~0.25 margin so no flip risk -- R7-verified).
// B-side (weights): 2 fp16 limbs, limb2 scaled by 2048 into normal range,
// dual accumulators, epilogue combines main + lo/2048.
__device__ inline unsigned short f16u(float v) {
  _Float16 h = (_Float16)v;
  union { _Float16 h; unsigned short u; } c; c.h = h; return c.u;
}
__device__ inline void split8_store1(const float* xs, unsigned short* dst) {
  unsigned q[4];
#pragma unroll
  for (int j = 0; j < 4; ++j)
    q[j] = (unsigned)f16u(xs[2*j]) | ((unsigned)f16u(xs[2*j+1]) << 16);
  *(int4*)dst = make_int4(q[0], q[1], q[2], q[3]);
}
__device__ inline void split8_store2w(const float* xs, unsigned short* dst,
                                      size_t ps) {
  unsigned q1[4], q2[4];
#pragma unroll
  for (int j = 0; j < 4; ++j) {
    float lo = xs[2*j], hi = xs[2*j+1];
    _Float16 l1 = (_Float16)lo, h1 = (_Float16)hi;
    union { _Float16 h; unsigned short u; } cl, ch;
    cl.h = l1; ch.h = h1;
    q1[j] = (unsigned)cl.u | ((unsigned)ch.u << 16);
    float rl = (lo - (float)l1) * RSCALE, rh = (hi - (float)h1) * RSCALE;
    q2[j] = (unsigned)f16u(rl) | ((unsigned)f16u(rh) << 16);
  }
  *(int4*)(dst)      = make_int4(q1[0], q1[1], q1[2], q1[3]);
  *(int4*)(dst + ps) = make_int4(q2[0], q2[1], q2[2], q2[3]);
}

// ---------------- async global->LDS 16B helper -----------------------------
__device__ __forceinline__ void gload16(const void* g, void* l) {
  __builtin_amdgcn_global_load_lds(
      (const __attribute__((address_space(1))) void*)g,
      (__attribute__((address_space(3))) void*)l, 16, 0, 0);
}

// ---------------- weight pre-split into fragment-linear fp16 planes -------
__global__ __launch_bounds__(256) void prep_kernel(
    const float* __restrict__ w, unsigned short* __restrict__ wf,
    int K32, int NTOT, int N)
{
  int id = blockIdx.x * 256 + threadIdx.x;      // one per (k0,NT,lane)
  if (id >= K32 * NTOT * 64) return;
  int l  = id & 63;
  int NT = (id >> 6) % NTOT;
  int k0 = id / (64 * NTOT);
  int n  = NT * 16 + (l & 15);
  int kb = k0 * 32 + 8 * (l >> 4);
  float xs[8];
#pragma unroll
  for (int j = 0; j < 8; ++j) xs[j] = w[(size_t)(kb + j) * N + n];
  split8_store2w(xs, wf + (size_t)id * 8, PS);
}

// ---------------- parallel compaction (order-free, outputs invariant) ------
__global__ __launch_bounds__(1024) void compact_kernel(
    const float* __restrict__ halting, int* __restrict__ idx,
    int* __restrict__ cnt, int tzero)
{
  __shared__ int wsum[16];
  __shared__ int wbase[16];
  __shared__ int s_base;
  int tid = threadIdx.x;
  int lane = tid & 63, wid = tid >> 6;
  int pos = blockIdx.x * 1024 + tid;
  int flag = tzero ? 1 : ((halting[pos] < 1.0f) ? 1 : 0);
  unsigned long long m = __ballot(flag);
  int pre = __popcll(m & ((1ull << lane) - 1ull));
  if (lane == 0) wsum[wid] = __popcll(m);
  __syncthreads();
  if (tid == 0) {
    int a = 0;
#pragma unroll
    for (int i = 0; i < 16; ++i) { wbase[i] = a; a += wsum[i]; }
    s_base = (a > 0) ? atomicAdd(cnt, a) : 0;
  }
  __syncthreads();
  if (flag) idx[s_base + wbase[wid] + pre] = pos;
}

// ---------------- halting / p kernel (pure fp32) ---------------------------
__global__ __launch_bounds__(256) void halt_kernel(
    const float* __restrict__ st, const float* __restrict__ te,
    const float* __restrict__ pe_t, const float* __restrict__ wp,
    const float* __restrict__ bp, float* __restrict__ halting,
    float* __restrict__ remainders, float* __restrict__ n_updates,
    float* __restrict__ uw_c, const int* __restrict__ idxbuf,
    const int* __restrict__ cntp, int tzero)
{
  int cnt = *cntp;
  int i = blockIdx.x * 4 + (threadIdx.x >> 6);
  if (i >= cnt) return;
  int lane = threadIdx.x & 63;
  int pos = idxbuf[i];
  int s = pos & (Ss - 1);
  const float4* stv = (const float4*)(st + (size_t)pos * Hh);
  const float4* tev = (const float4*)(te + (size_t)s * Hh);
  const float4* pev = (const float4*)pe_t;
  const float4* wpv = (const float4*)wp;
  float sum = 0.f;
#pragma unroll
  for (int j = 0; j < 2; ++j) {
    int idx = lane + j * 64;
    float4 a = stv[idx], b = tev[idx], c = pev[idx], w = wpv[idx];
    sum += (a.x + b.x + c.x) * w.x + (a.y + b.y + c.y) * w.y +
           (a.z + b.z + c.z) * w.z + (a.w + b.w + c.w) * w.w;
  }
#pragma unroll
  for (int off = 32; off > 0; off >>= 1) sum += __shfl_xor(sum, off, 64);
  if (lane == 0) {
    float y = sum + bp[0];
    float p = 1.0f / (1.0f + expf(-y));
    const float THRESH = 1.0f - 0.1f;
    float h0  = tzero ? 0.f : halting[pos];
    float rem = tzero ? 0.f : remainders[pos];
    float nup = tzero ? 0.f : n_updates[pos];
    float still = (h0 < 1.0f) ? 1.f : 0.f;
    float cand  = h0 + p * still;
    float nh  = ((cand >  THRESH) ? 1.f : 0.f) * still;
    float st2 = ((cand <= THRESH) ? 1.f : 0.f) * still;
    h0  += p * st2;
    rem += nh * (1.0f - h0);
    h0  += nh * rem;
    nup += st2 + nh;
    float uwv = p * st2 + nh * rem;
    halting[pos]    = h0;
    remainders[pos] = rem;
    n_updates[pos]  = nup;
    uw_c[i]         = uwv;
  }
}

// ---- stage_x: x = st+te+pe (gathered) into single fp16 fragment plane -----
__global__ __launch_bounds__(256) void stagex_kernel(
    const float* __restrict__ st, const float* __restrict__ te,
    const float* __restrict__ pe_t, unsigned short* __restrict__ xf,
    const int* __restrict__ idxbuf, const int* __restrict__ cntp,
    int m_base, int mrows)
{
  const int K32 = Hh / 32;
  int cnt = *cntp;
  int rel = cnt - m_base;
  if (rel <= 0) return;
  if (rel > mrows) rel = mrows;
  int rows_pad = (rel + 127) & ~127;
  if (rows_pad > mrows) rows_pad = mrows;
  int id = blockIdx.x * 256 + threadIdx.x;
  int l = id & 63;
  int f = id >> 6;
  int mtile = f / K32, k0 = f - mtile * K32;
  if (mtile * 16 >= rows_pad) return;
  int m = m_base + mtile * 16 + (l & 15);
  int mc = (m < cnt) ? m : cnt - 1;
  int pos = idxbuf[mc];
  int kb = k0 * 32 + (l >> 4) * 8;
  const float* ap = st + (size_t)pos * Hh + kb;
  const float* tp = te + (size_t)(pos & (Ss - 1)) * Hh + kb;
  const float* pp = pe_t + kb;
  float4 xa = *(const float4*)ap, xb = *(const float4*)(ap + 4);
  float4 ta = *(const float4*)tp, tb = *(const float4*)(tp + 4);
  float4 pa = *(const float4*)pp, pb = *(const float4*)(pp + 4);
  float xs[8];
  xs[0] = xa.x + ta.x + pa.x; xs[1] = xa.y + ta.y + pa.y;
  xs[2] = xa.z + ta.z + pa.z; xs[3] = xa.w + ta.w + pa.w;
  xs[4] = xb.x + tb.x + pb.x; xs[5] = xb.y + tb.y + pb.y;
  xs[6] = xb.z + tb.z + pb.z; xs[7] = xb.w + tb.w + pb.w;
  split8_store1(xs, xf + ((size_t)f * 64 + l) * 8);
}

// ======================= GEMM kernels (ring-3, single barrier) =============
// block 128x128, 4 waves (2m x 2n), wave 64x64 = 4x4 frags of 16x16x32 fp16,
// A single-limb + B 2-limb: 2 MFMA per frag pair, dual accumulators.
// RING-3 LDS (3 x 24 KB = 72 KB -> 2 blocks/CU) with ONE barrier per
// k-step (was 2 with dbuf): at iter k we stage buf[(k+1)%3], last read at
// iter k-2 -- every wave at iter k has passed the mid-iteration barrier of
// iter k-1, which post-dates those reads, so no end-of-iteration barrier is
// needed. Cross-wave stage-write visibility: each wave's vmcnt(6) precedes
// the shared barrier, so barrier-crossing implies all writes to the current
// buffer landed. Per k-step: stage next (6 gloads/wave), vmcnt(6), barrier,
// 12 ds_read_b128, 32 MFMA. gemm1 adds one __syncthreads() before its
// epilogue (repack slice aliases buf0, read by other waves in final iter).

// ---- GEMM1: h = relu(x @ w1 + b1), stored as single fp16 A-frag plane -----
#define LSTR 66
__global__ __launch_bounds__(256, 2) void gemm1_kernel(
    const unsigned short* __restrict__ xf, const unsigned short* __restrict__ w1f,
    const float* __restrict__ b1, unsigned short* __restrict__ hf,
    const int* __restrict__ cntp, int m_base)
{
  __shared__ __align__(1024) char stage[3 * BUFSZ];
  const int K32 = Hh / 32, NTOT = DFF / 16;   // 16, 128
  int lin = blockIdx.x;
  int gsz = gridDim.x;
  int q = gsz >> 3, r = gsz & 7;
  int xcd = lin & 7, idx0 = lin >> 3;
  int swz = (xcd < r) ? (xcd * (q + 1) + idx0)
                      : (r * (q + 1) + (xcd - r) * q + idx0);
  int strip = swz >> 4;
  int nb    = swz & 15;
  int cnt = *cntp;
  int m0 = strip * 128;
  if (m_base + m0 >= cnt) return;
  int tid = threadIdx.x, lane = tid & 63, w = tid >> 6;
  int wm = w >> 1, wn = w & 1;
  int n0 = nb * 128;
  int mtb0 = m0 >> 4, ntb0 = n0 >> 4;
  char* sptr = stage;

  // 24 units: 0..7 = A mtile (1 limb), 8..23 = B (ntile, limb)
  auto stage_step = [&](int bsel, int kk) {
    unsigned so = (unsigned)bsel * (unsigned)BUFSZ;
#pragma unroll
    for (int j = 0; j < 6; ++j) {
      int u = w * 6 + j;
      if (u < 8) {
        const unsigned short* g =
            xf + ((size_t)(mtb0 + u) * K32 + kk) * 512 + (size_t)lane * 8;
        gload16(g, sptr + so + (unsigned)u * 1024u);
      } else {
        int v = u - 8;
        int ntile = v >> 1, limb = v & 1;
        const unsigned short* g =
            w1f + ((size_t)kk * NTOT + (ntb0 + ntile)) * 512
                + (size_t)limb * PS + (size_t)lane * 8;
        gload16(g, sptr + so + 8192u + (unsigned)v * 1024u);
      }
    }
  };

  floatx4 am[4][4], al[4][4];
#pragma unroll
  for (int i = 0; i < 4; ++i)
#pragma unroll
    for (int j = 0; j < 4; ++j) {
      am[i][j] = (floatx4){0.f, 0.f, 0.f, 0.f};
      al[i][j] = (floatx4){0.f, 0.f, 0.f, 0.f};
    }

  stage_step(0, 0);
  int cur = 0;
  for (int k0 = 0; k0 < K32; ++k0) {
    int nxt = (cur == 2) ? 0 : cur + 1;
    if (k0 + 1 < K32) {
      stage_step(nxt, k0 + 1);
      asm volatile("s_waitcnt vmcnt(6)" ::: "memory");   // stage(k0) landed
    } else {
      asm volatile("s_waitcnt vmcnt(0)" ::: "memory");
    }
    __builtin_amdgcn_s_barrier();          // all waves' stage-writes visible
    asm volatile("" ::: "memory");
    const char* sb = sptr + cur * BUFSZ + (size_t)lane * 16;
    half8 af[4], bf[2][4];
#pragma unroll
    for (int mt = 0; mt < 4; ++mt)
      af[mt] = *(const half8*)(sb + (wm * 4 + mt) * 1024);
#pragma unroll
    for (int nt = 0; nt < 4; ++nt) {
      bf[0][nt] = *(const half8*)(sb + 8192 + ((wn * 4 + nt) * 2 + 0) * 1024);
      bf[1][nt] = *(const half8*)(sb + 8192 + ((wn * 4 + nt) * 2 + 1) * 1024);
    }
    __builtin_amdgcn_s_setprio(1);
#pragma unroll
    for (int mt = 0; mt < 4; ++mt)
#pragma unroll
      for (int nt = 0; nt < 4; ++nt) {
        am[mt][nt] = __builtin_amdgcn_mfma_f32_16x16x32_f16(af[mt], bf[0][nt],
                                                            am[mt][nt], 0, 0, 0);
        al[mt][nt] = __builtin_amdgcn_mfma_f32_16x16x32_f16(af[mt], bf[1][nt],
                                                            al[mt][nt], 0, 0, 0);
      }
    __builtin_amdgcn_s_setprio(0);
    asm volatile("" ::: "memory");
    cur = nxt;
  }
  __syncthreads();   // final-iter readers done before epilogue reuses buf0
  // epilogue: relu + bias + limb combine; repack C-frag -> A-frag in 16-row
  // slices. Per-wave private LDS slice in buf0.
  {
    int r0 = (lane >> 4) * 4;
    int c0l = lane & 15;
    int mtb = mtb0 + wm * 4;
    int k2b = (n0 >> 5) + wn * 2;
    float* L = (float*)(void*)sptr + (size_t)w * (16 * LSTR);
    float bias[4];
#pragma unroll
    for (int nt = 0; nt < 4; ++nt) bias[nt] = b1[n0 + wn * 64 + nt * 16 + c0l];
#pragma unroll
    for (int mt = 0; mt < 4; ++mt) {
#pragma unroll
      for (int nt = 0; nt < 4; ++nt)
#pragma unroll
        for (int reg = 0; reg < 4; ++reg)
          L[(r0 + reg) * LSTR + nt * 16 + c0l] =
              fmaxf(am[mt][nt][reg] + al[mt][nt][reg] * RINV + bias[nt], 0.f);
#pragma unroll
      for (int k2 = 0; k2 < 2; ++k2) {
        const float* rp = L + (lane & 15) * LSTR + k2 * 32 + (lane >> 4) * 8;
        float xs[8];
        float4 xa = *(const float4*)rp, xb = *(const float4*)(rp + 4);
        xs[0]=xa.x; xs[1]=xa.y; xs[2]=xa.z; xs[3]=xa.w;
        xs[4]=xb.x; xs[5]=xb.y; xs[6]=xb.z; xs[7]=xb.w;
        size_t f2 = (size_t)(mtb + mt) * 64 + (k2b + k2);
        split8_store1(xs, hf + (f2 * 64 + lane) * 8);
      }
    }
  }
}

// ---- GEMM2f (FULL-K, fused bias + uw-blend scatter epilogue) --------------
__global__ __launch_bounds__(256, 2) void gemm2f_kernel(
    const unsigned short* __restrict__ hf, const unsigned short* __restrict__ w2f,
    const float* __restrict__ b2, const float* __restrict__ uw_c,
    float* __restrict__ st_out, float* __restrict__ prev,
    const int* __restrict__ idxbuf, const int* __restrict__ cntp,
    int m_base, int tzero)
{
  __shared__ __align__(1024) char stage[3 * BUFSZ];
  const int K32 = DFF / 32, NTOT = Hh / 16;   // 64, 32
  int lin = blockIdx.x;
  int gsz = gridDim.x;
  int q = gsz >> 3, r = gsz & 7;
  int xcd = lin & 7, idx0 = lin >> 3;
  int swz = (xcd < r) ? (xcd * (q + 1) + idx0)
                      : (r * (q + 1) + (xcd - r) * q + idx0);
  int strip = swz >> 2, nb = swz & 3;
  int cnt = *cntp;
  int m0 = strip * 128;
  if (m_base + m0 >= cnt) return;
  int n0 = nb * 128;
  int tid = threadIdx.x, lane = tid & 63, w = tid >> 6;
  int wm = w >> 1, wn = w & 1;
  int mtb0 = m0 >> 4, ntb0 = n0 >> 4;
  char* sptr = stage;

  auto stage_step = [&](int bsel, int kk) {
    unsigned so = (unsigned)bsel * (unsigned)BUFSZ;
#pragma unroll
    for (int j = 0; j < 6; ++j) {
      int u = w * 6 + j;
      if (u < 8) {
        const unsigned short* g =
            hf + ((size_t)(mtb0 + u) * K32 + kk) * 512 + (size_t)lane * 8;
        gload16(g, sptr + so + (unsigned)u * 1024u);
      } else {
        int v = u - 8;
        int ntile = v >> 1, limb = v & 1;
        const unsigned short* g =
            w2f + ((size_t)kk * NTOT + (ntb0 + ntile)) * 512
                + (size_t)limb * PS + (size_t)lane * 8;
        gload16(g, sptr + so + 8192u + (unsigned)v * 1024u);
      }
    }
  };

  floatx4 am[4][4], al[4][4];
#pragma unroll
  for (int i = 0; i < 4; ++i)
#pragma unroll
    for (int j = 0; j < 4; ++j) {
      am[i][j] = (floatx4){0.f, 0.f, 0.f, 0.f};
      al[i][j] = (floatx4){0.f, 0.f, 0.f, 0.f};
    }

  stage_step(0, 0);
  int cur = 0;
  for (int k0 = 0; k0 < K32; ++k0) {
    int nxt = (cur == 2) ? 0 : cur + 1;
    if (k0 + 1 < K32) {
      stage_step(nxt, k0 + 1);
      asm volatile("s_waitcnt vmcnt(6)" ::: "memory");
    } else {
      asm volatile("s_waitcnt vmcnt(0)" ::: "memory");
    }
    __builtin_amdgcn_s_barrier();
    asm volatile("" ::: "memory");
    const char* sb = sptr + cur * BUFSZ + (size_t)lane * 16;
    half8 af[4], bf[2][4];
#pragma unroll
    for (int mt = 0; mt < 4; ++mt)
      af[mt] = *(const half8*)(sb + (wm * 4 + mt) * 1024);
#pragma unroll
    for (int nt = 0; nt < 4; ++nt) {
      bf[0][nt] = *(const half8*)(sb + 8192 + ((wn * 4 + nt) * 2 + 0) * 1024);
      bf[1][nt] = *(const half8*)(sb + 8192 + ((wn * 4 + nt) * 2 + 1) * 1024);
    }
#pragma unroll
    for (int mt = 0; mt < 4; ++mt)
#pragma unroll
      for (int nt = 0; nt < 4; ++nt) {
        am[mt][nt] = __builtin_amdgcn_mfma_f32_16x16x32_f16(af[mt], bf[0][nt],
                                                            am[mt][nt], 0, 0, 0);
        al[mt][nt] = __builtin_amdgcn_mfma_f32_16x16x32_f16(af[mt], bf[1][nt],
                                                            al[mt][nt], 0, 0, 0);
      }
    asm volatile("" ::: "memory");
    cur = nxt;
  }
  // fused epilogue: sv = main + lo/2048 + b2; st_out = sv;
  // prev = sv*uw + prev*(1-uw)
  {
    int r0 = (lane >> 4) * 4;
    int c0l = lane & 15;
    int mtb = mtb0 + wm * 4;
    int njb = ntb0 + wn * 4;
    float bias[4];
#pragma unroll
    for (int nt = 0; nt < 4; ++nt) bias[nt] = b2[(njb + nt) * 16 + c0l];
#pragma unroll
    for (int mt = 0; mt < 4; ++mt) {
      int pos4[4]; float uw4[4]; bool ok4[4];
#pragma unroll
      for (int reg = 0; reg < 4; ++reg) {
        int m = m_base + (mtb + mt) * 16 + r0 + reg;
        ok4[reg] = (m < cnt);
        int mc = ok4[reg] ? m : 0;
        pos4[reg] = idxbuf[mc];
        uw4[reg]  = uw_c[mc];
      }
#pragma unroll
      for (int nt = 0; nt < 4; ++nt) {
        int col = (njb + nt) * 16 + c0l;
#pragma unroll
        for (int reg = 0; reg < 4; ++reg) {
          if (ok4[reg]) {
            float sv = am[mt][nt][reg] + al[mt][nt][reg] * RINV + bias[nt];
            size_t off = (size_t)pos4[reg] * Hh + col;
            float pv = tzero ? 0.f : prev[off];
            st_out[off] = sv;
            prev[off] = sv * uw4[reg] + pv * (1.f - uw4[reg]);
          }
        }
      }
    }
  }
}

extern "C" void kernel_launch(void* const* d_in, const int* in_sizes, int n_in,
                              void* d_out, int out_size, void* d_ws, size_t ws_size,
                              hipStream_t stream) {
  const float* state  = (const float*)d_in[0];
  const float* te     = (const float*)d_in[2];
  const float* pe     = (const float*)d_in[3];
  const float* wp     = (const float*)d_in[4];
  const float* bp     = (const float*)d_in[5];
  const float* w1     = (const float*)d_in[6];
  const float* b1     = (const float*)d_in[7];
  const float* w2     = (const float*)d_in[8];
  const float* b2     = (const float*)d_in[9];

  float* out        = (float*)d_out;
  float* prev       = out;                          // BS*H (fully written @t0)
  float* remainders = out + (size_t)BS * Hh;        // BS   (fully written @t0)
  float* n_updates  = remainders + BS;              // BS   (fully written @t0)

  float*          st      = (float*)d_ws;           // BS*H (fully written @t0)
  float*          halting = st + (size_t)BS * Hh;   // BS   (fully written @t0)
  float*          uw_c    = halting + BS;           // BS
  int*            idxbuf  = (int*)(uw_c + BS);      // BS
  int*            cntp    = idxbuf + BS;            // 64 (one counter per hop)
  unsigned short* w1f     = (unsigned short*)(cntp + 64);   // 2*PS (4 MB)
  unsigned short* w2f     = w1f + 2 * (size_t)PS;           // 2*PS (4 MB)
  unsigned short* hf      = w2f + 2 * (size_t)PS;

  size_t fixed = (size_t)((char*)hf - (char*)d_ws);
  size_t avail = (ws_size > fixed) ? (ws_size - fixed) : 0;
  // per row: hf = 2048*2 = 4096 B ; xf = 512*2 = 1024 B (single fp16 planes)
  int hrows = (int)((avail / 5120) & ~(size_t)127);
  if (hrows > BS) hrows = BS;
  if (hrows < 128) hrows = 128;
  unsigned short* xf = hf + (size_t)hrows * DFF;    // hf = hrows*DFF ushorts
  int nst = hrows / 128;

  // Only the hop counters need zeroing: all other state buffers are fully
  // written at hop 0 via the tzero paths.
  hipMemsetAsync(cntp, 0, 64 * sizeof(int), stream);

  prep_kernel<<<512, 256, 0, stream>>>(w1, w1f, Hh / 32, DFF / 16, DFF);
  prep_kernel<<<512, 256, 0, stream>>>(w2, w2f, DFF / 32, Hh / 16, Hh);

  for (int t = 0; t < HOPS; ++t) {
    const float* pe_t = pe + (size_t)t * Hh;
    int* cnt_t = cntp + t;
    int tz = (t == 0) ? 1 : 0;
    const float* st_src = tz ? state : st;   // hop 0 reads the input directly
    compact_kernel<<<BS / 1024, 1024, 0, stream>>>(halting, idxbuf, cnt_t, tz);
    halt_kernel<<<BS / 4, 256, 0, stream>>>(st_src, te, pe_t, wp, bp, halting,
                                            remainders, n_updates, uw_c,
                                            idxbuf, cnt_t, tz);
    for (int mb = 0; mb < BS; mb += hrows) {
      stagex_kernel<<<hrows / 4, 256, 0, stream>>>(st_src, te, pe_t, xf, idxbuf,
                                                   cnt_t, mb, hrows);
      gemm1_kernel<<<nst * 16, 256, 0, stream>>>(xf, w1f, b1, hf, cnt_t, mb);
      gemm2f_kernel<<<nst * 4, 256, 0, stream>>>(hf, w2f, b2, uw_c, st, prev,
                                                 idxbuf, cnt_t, mb, tz);
    }
  }
}

// Round 10
// 703.569 us; speedup vs baseline: 1.6236x; 1.0829x over previous
//
#include <hip/hip_runtime.h>
#include <math.h>

typedef short short8 __attribute__((ext_vector_type(8)));
typedef _Float16 half8 __attribute__((ext_vector_type(8)));
typedef float floatx4 __attribute__((ext_vector_type(4)));

#define Bb 64
#define Ss 512
#define Hh 512
#define DFF 2048
#define HOPS 6
#define BS (Bb*Ss)          // 32768 positions
#define PS 1048576          // weight plane stride (elems), both w1f and w2f
#define BUFSZ1 24576        // gemm1 stage buf: A 8KB (1 limb) + B 16KB (2 limbs)
#define BUFSZ2 16384        // gemm2 stage buf: A 8KB (1 limb) + B 8KB (1 limb)
#define RSCALE 2048.0f      // weight limb-2 scale (2^11 = fp16 ulp^-1)
#define RINV   (1.0f/2048.0f)

// ---------------- fp16 pack helpers ---------------------------------------
// A-side (x, h): SINGLE fp16 plane (error 2^-11|a|; R7-verified safe).
// W1: 2 fp16 limbs (limb2 scaled by 2048), dual accumulators in gemm1.
// W2: SINGLE fp16 limb (R10): adds an independent ~3.4e-4 output error term,
// same magnitude as the R7-accepted h-rounding term -> quadrature ~1.4x.
__device__ inline unsigned short f16u(float v) {
  _Float16 h = (_Float16)v;
  union { _Float16 h; unsigned short u; } c; c.h = h; return c.u;
}
__device__ inline void split8_store1(const float* xs, unsigned short* dst) {
  unsigned q[4];
#pragma unroll
  for (int j = 0; j < 4; ++j)
    q[j] = (unsigned)f16u(xs[2*j]) | ((unsigned)f16u(xs[2*j+1]) << 16);
  *(int4*)dst = make_int4(q[0], q[1], q[2], q[3]);
}

// ---------------- async global->LDS 16B helper -----------------------------
__device__ __forceinline__ void gload16(const void* g, void* l) {
  __builtin_amdgcn_global_load_lds(
      (const __attribute__((address_space(1))) void*)g,
      (__attribute__((address_space(3))) void*)l, 16, 0, 0);
}

// ---------------- weight pre-split into fragment-linear fp16 planes -------
// limb2=1: also write the scaled-residual plane (w1). limb2=0: main only (w2).
__global__ __launch_bounds__(256) void prep_kernel(
    const float* __restrict__ w, unsigned short* __restrict__ wf,
    int K32, int NTOT, int N, int limb2)
{
  int id = blockIdx.x * 256 + threadIdx.x;      // one per (k0,NT,lane)
  if (id >= K32 * NTOT * 64) return;
  int l  = id & 63;
  int NT = (id >> 6) % NTOT;
  int k0 = id / (64 * NTOT);
  int n  = NT * 16 + (l & 15);
  int kb = k0 * 32 + 8 * (l >> 4);
  float xs[8];
#pragma unroll
  for (int j = 0; j < 8; ++j) xs[j] = w[(size_t)(kb + j) * N + n];
  unsigned short* dst = wf + (size_t)id * 8;
  unsigned q1[4], q2[4];
#pragma unroll
  for (int j = 0; j < 4; ++j) {
    float lo = xs[2*j], hi = xs[2*j+1];
    _Float16 l1 = (_Float16)lo, h1 = (_Float16)hi;
    union { _Float16 h; unsigned short u; } cl, ch;
    cl.h = l1; ch.h = h1;
    q1[j] = (unsigned)cl.u | ((unsigned)ch.u << 16);
    float rl = (lo - (float)l1) * RSCALE, rh = (hi - (float)h1) * RSCALE;
    q2[j] = (unsigned)f16u(rl) | ((unsigned)f16u(rh) << 16);
  }
  *(int4*)(dst) = make_int4(q1[0], q1[1], q1[2], q1[3]);
  if (limb2)
    *(int4*)(dst + PS) = make_int4(q2[0], q2[1], q2[2], q2[3]);
}

// ---------------- parallel compaction (order-free, outputs invariant) ------
__global__ __launch_bounds__(1024) void compact_kernel(
    const float* __restrict__ halting, int* __restrict__ idx,
    int* __restrict__ cnt, int tzero)
{
  __shared__ int wsum[16];
  __shared__ int wbase[16];
  __shared__ int s_base;
  int tid = threadIdx.x;
  int lane = tid & 63, wid = tid >> 6;
  int pos = blockIdx.x * 1024 + tid;
  int flag = tzero ? 1 : ((halting[pos] < 1.0f) ? 1 : 0);
  unsigned long long m = __ballot(flag);
  int pre = __popcll(m & ((1ull << lane) - 1ull));
  if (lane == 0) wsum[wid] = __popcll(m);
  __syncthreads();
  if (tid == 0) {
    int a = 0;
#pragma unroll
    for (int i = 0; i < 16; ++i) { wbase[i] = a; a += wsum[i]; }
    s_base = (a > 0) ? atomicAdd(cnt, a) : 0;
  }
  __syncthreads();
  if (flag) idx[s_base + wbase[wid] + pre] = pos;
}

// ---------------- halting / p kernel (pure fp32) ---------------------------
__global__ __launch_bounds__(256) void halt_kernel(
    const float* __restrict__ st, const float* __restrict__ te,
    const float* __restrict__ pe_t, const float* __restrict__ wp,
    const float* __restrict__ bp, float* __restrict__ halting,
    float* __restrict__ remainders, float* __restrict__ n_updates,
    float* __restrict__ uw_c, const int* __restrict__ idxbuf,
    const int* __restrict__ cntp, int tzero)
{
  int cnt = *cntp;
  int i = blockIdx.x * 4 + (threadIdx.x >> 6);
  if (i >= cnt) return;
  int lane = threadIdx.x & 63;
  int pos = idxbuf[i];
  int s = pos & (Ss - 1);
  const float4* stv = (const float4*)(st + (size_t)pos * Hh);
  const float4* tev = (const float4*)(te + (size_t)s * Hh);
  const float4* pev = (const float4*)pe_t;
  const float4* wpv = (const float4*)wp;
  float sum = 0.f;
#pragma unroll
  for (int j = 0; j < 2; ++j) {
    int idx = lane + j * 64;
    float4 a = stv[idx], b = tev[idx], c = pev[idx], w = wpv[idx];
    sum += (a.x + b.x + c.x) * w.x + (a.y + b.y + c.y) * w.y +
           (a.z + b.z + c.z) * w.z + (a.w + b.w + c.w) * w.w;
  }
#pragma unroll
  for (int off = 32; off > 0; off >>= 1) sum += __shfl_xor(sum, off, 64);
  if (lane == 0) {
    float y = sum + bp[0];
    float p = 1.0f / (1.0f + expf(-y));
    const float THRESH = 1.0f - 0.1f;
    float h0  = tzero ? 0.f : halting[pos];
    float rem = tzero ? 0.f : remainders[pos];
    float nup = tzero ? 0.f : n_updates[pos];
    float still = (h0 < 1.0f) ? 1.f : 0.f;
    float cand  = h0 + p * still;
    float nh  = ((cand >  THRESH) ? 1.f : 0.f) * still;
    float st2 = ((cand <= THRESH) ? 1.f : 0.f) * still;
    h0  += p * st2;
    rem += nh * (1.0f - h0);
    h0  += nh * rem;
    nup += st2 + nh;
    float uwv = p * st2 + nh * rem;
    halting[pos]    = h0;
    remainders[pos] = rem;
    n_updates[pos]  = nup;
    uw_c[i]         = uwv;
  }
}

// ---- stage_x: x = st+te+pe (gathered) into single fp16 fragment plane -----
__global__ __launch_bounds__(256) void stagex_kernel(
    const float* __restrict__ st, const float* __restrict__ te,
    const float* __restrict__ pe_t, unsigned short* __restrict__ xf,
    const int* __restrict__ idxbuf, const int* __restrict__ cntp,
    int m_base, int mrows)
{
  const int K32 = Hh / 32;
  int cnt = *cntp;
  int rel = cnt - m_base;
  if (rel <= 0) return;
  if (rel > mrows) rel = mrows;
  int rows_pad = (rel + 127) & ~127;
  if (rows_pad > mrows) rows_pad = mrows;
  int id = blockIdx.x * 256 + threadIdx.x;
  int l = id & 63;
  int f = id >> 6;
  int mtile = f / K32, k0 = f - mtile * K32;
  if (mtile * 16 >= rows_pad) return;
  int m = m_base + mtile * 16 + (l & 15);
  int mc = (m < cnt) ? m : cnt - 1;
  int pos = idxbuf[mc];
  int kb = k0 * 32 + (l >> 4) * 8;
  const float* ap = st + (size_t)pos * Hh + kb;
  const float* tp = te + (size_t)(pos & (Ss - 1)) * Hh + kb;
  const float* pp = pe_t + kb;
  float4 xa = *(const float4*)ap, xb = *(const float4*)(ap + 4);
  float4 ta = *(const float4*)tp, tb = *(const float4*)(tp + 4);
  float4 pa = *(const float4*)pp, pb = *(const float4*)(pp + 4);
  float xs[8];
  xs[0] = xa.x + ta.x + pa.x; xs[1] = xa.y + ta.y + pa.y;
  xs[2] = xa.z + ta.z + pa.z; xs[3] = xa.w + ta.w + pa.w;
  xs[4] = xb.x + tb.x + pb.x; xs[5] = xb.y + tb.y + pb.y;
  xs[6] = xb.z + tb.z + pb.z; xs[7] = xb.w + tb.w + pb.w;
  split8_store1(xs, xf + ((size_t)f * 64 + l) * 8);
}

// ======================= GEMM kernels (ring-3, single barrier) =============
// block 128x128, 4 waves (2m x 2n), wave 64x64 = 4x4 frags of 16x16x32 fp16.
// RING-3 LDS, one barrier per k-step (R9 structure): stage buf[(k+1)%3]
// whose last reads were at iter k-2, protected by iter k-1's barrier.
// Per k-step: stage next, counted vmcnt, barrier, ds_read, MFMA.

// ---- GEMM1: h = relu(x @ w1 + b1); W1 dual-limb, dual accumulators --------
#define LSTR 66
__global__ __launch_bounds__(256, 2) void gemm1_kernel(
    const unsigned short* __restrict__ xf, const unsigned short* __restrict__ w1f,
    const float* __restrict__ b1, unsigned short* __restrict__ hf,
    const int* __restrict__ cntp, int m_base)
{
  __shared__ __align__(1024) char stage[3 * BUFSZ1];
  const int K32 = Hh / 32, NTOT = DFF / 16;   // 16, 128
  int lin = blockIdx.x;
  int gsz = gridDim.x;
  int q = gsz >> 3, r = gsz & 7;
  int xcd = lin & 7, idx0 = lin >> 3;
  int swz = (xcd < r) ? (xcd * (q + 1) + idx0)
                      : (r * (q + 1) + (xcd - r) * q + idx0);
  int strip = swz >> 4;
  int nb    = swz & 15;
  int cnt = *cntp;
  int m0 = strip * 128;
  if (m_base + m0 >= cnt) return;
  int tid = threadIdx.x, lane = tid & 63, w = tid >> 6;
  int wm = w >> 1, wn = w & 1;
  int n0 = nb * 128;
  int mtb0 = m0 >> 4, ntb0 = n0 >> 4;
  char* sptr = stage;

  // 24 units: 0..7 = A mtile (1 limb), 8..23 = B (ntile, limb)
  auto stage_step = [&](int bsel, int kk) {
    unsigned so = (unsigned)bsel * (unsigned)BUFSZ1;
#pragma unroll
    for (int j = 0; j < 6; ++j) {
      int u = w * 6 + j;
      if (u < 8) {
        const unsigned short* g =
            xf + ((size_t)(mtb0 + u) * K32 + kk) * 512 + (size_t)lane * 8;
        gload16(g, sptr + so + (unsigned)u * 1024u);
      } else {
        int v = u - 8;
        int ntile = v >> 1, limb = v & 1;
        const unsigned short* g =
            w1f + ((size_t)kk * NTOT + (ntb0 + ntile)) * 512
                + (size_t)limb * PS + (size_t)lane * 8;
        gload16(g, sptr + so + 8192u + (unsigned)v * 1024u);
      }
    }
  };

  floatx4 am[4][4], al[4][4];
#pragma unroll
  for (int i = 0; i < 4; ++i)
#pragma unroll
    for (int j = 0; j < 4; ++j) {
      am[i][j] = (floatx4){0.f, 0.f, 0.f, 0.f};
      al[i][j] = (floatx4){0.f, 0.f, 0.f, 0.f};
    }

  stage_step(0, 0);
  int cur = 0;
  for (int k0 = 0; k0 < K32; ++k0) {
    int nxt = (cur == 2) ? 0 : cur + 1;
    if (k0 + 1 < K32) {
      stage_step(nxt, k0 + 1);
      asm volatile("s_waitcnt vmcnt(6)" ::: "memory");   // stage(k0) landed
    } else {
      asm volatile("s_waitcnt vmcnt(0)" ::: "memory");
    }
    __builtin_amdgcn_s_barrier();          // all waves' stage-writes visible
    asm volatile("" ::: "memory");
    const char* sb = sptr + cur * BUFSZ1 + (size_t)lane * 16;
    half8 af[4], bf[2][4];
#pragma unroll
    for (int mt = 0; mt < 4; ++mt)
      af[mt] = *(const half8*)(sb + (wm * 4 + mt) * 1024);
#pragma unroll
    for (int nt = 0; nt < 4; ++nt) {
      bf[0][nt] = *(const half8*)(sb + 8192 + ((wn * 4 + nt) * 2 + 0) * 1024);
      bf[1][nt] = *(const half8*)(sb + 8192 + ((wn * 4 + nt) * 2 + 1) * 1024);
    }
    __builtin_amdgcn_s_setprio(1);
#pragma unroll
    for (int mt = 0; mt < 4; ++mt)
#pragma unroll
      for (int nt = 0; nt < 4; ++nt) {
        am[mt][nt] = __builtin_amdgcn_mfma_f32_16x16x32_f16(af[mt], bf[0][nt],
                                                            am[mt][nt], 0, 0, 0);
        al[mt][nt] = __builtin_amdgcn_mfma_f32_16x16x32_f16(af[mt], bf[1][nt],
                                                            al[mt][nt], 0, 0, 0);
      }
    __builtin_amdgcn_s_setprio(0);
    asm volatile("" ::: "memory");
    cur = nxt;
  }
  __syncthreads();   // final-iter readers done before epilogue reuses buf0
  // epilogue: relu + bias + limb combine; repack C-frag -> A-frag in 16-row
  // slices. Per-wave private LDS slice in buf0.
  {
    int r0 = (lane >> 4) * 4;
    int c0l = lane & 15;
    int mtb = mtb0 + wm * 4;
    int k2b = (n0 >> 5) + wn * 2;
    float* L = (float*)(void*)sptr + (size_t)w * (16 * LSTR);
    float bias[4];
#pragma unroll
    for (int nt = 0; nt < 4; ++nt) bias[nt] = b1[n0 + wn * 64 + nt * 16 + c0l];
#pragma unroll
    for (int mt = 0; mt < 4; ++mt) {
#pragma unroll
      for (int nt = 0; nt < 4; ++nt)
#pragma unroll
        for (int reg = 0; reg < 4; ++reg)
          L[(r0 + reg) * LSTR + nt * 16 + c0l] =
              fmaxf(am[mt][nt][reg] + al[mt][nt][reg] * RINV + bias[nt], 0.f);
#pragma unroll
      for (int k2 = 0; k2 < 2; ++k2) {
        const float* rp = L + (lane & 15) * LSTR + k2 * 32 + (lane >> 4) * 8;
        float xs[8];
        float4 xa = *(const float4*)rp, xb = *(const float4*)(rp + 4);
        xs[0]=xa.x; xs[1]=xa.y; xs[2]=xa.z; xs[3]=xa.w;
        xs[4]=xb.x; xs[5]=xb.y; xs[6]=xb.z; xs[7]=xb.w;
        size_t f2 = (size_t)(mtb + mt) * 64 + (k2b + k2);
        split8_store1(xs, hf + (f2 * 64 + lane) * 8);
      }
    }
  }
}

// ---- GEMM2f (FULL-K, W2 SINGLE-limb, fused bias + uw-blend scatter) -------
// R10: W2 low limb dropped -> 16 MFMA (was 32), 8 ds_read (was 12),
// 16 stage units (was 24, vmcnt 4), BUFSZ 16 KB (ring-3 = 48 KB).
__global__ __launch_bounds__(256, 2) void gemm2f_kernel(
    const unsigned short* __restrict__ hf, const unsigned short* __restrict__ w2f,
    const float* __restrict__ b2, const float* __restrict__ uw_c,
    float* __restrict__ st_out, float* __restrict__ prev,
    const int* __restrict__ idxbuf, const int* __restrict__ cntp,
    int m_base, int tzero)
{
  __shared__ __align__(1024) char stage[3 * BUFSZ2];
  const int K32 = DFF / 32, NTOT = Hh / 16;   // 64, 32
  int lin = blockIdx.x;
  int gsz = gridDim.x;
  int q = gsz >> 3, r = gsz & 7;
  int xcd = lin & 7, idx0 = lin >> 3;
  int swz = (xcd < r) ? (xcd * (q + 1) + idx0)
                      : (r * (q + 1) + (xcd - r) * q + idx0);
  int strip = swz >> 2, nb = swz & 3;
  int cnt = *cntp;
  int m0 = strip * 128;
  if (m_base + m0 >= cnt) return;
  int n0 = nb * 128;
  int tid = threadIdx.x, lane = tid & 63, w = tid >> 6;
  int wm = w >> 1, wn = w & 1;
  int mtb0 = m0 >> 4, ntb0 = n0 >> 4;
  char* sptr = stage;

  // 16 units: 0..7 = A mtile, 8..15 = B ntile (single limb)
  auto stage_step = [&](int bsel, int kk) {
    unsigned so = (unsigned)bsel * (unsigned)BUFSZ2;
#pragma unroll
    for (int j = 0; j < 4; ++j) {
      int u = w * 4 + j;
      if (u < 8) {
        const unsigned short* g =
            hf + ((size_t)(mtb0 + u) * K32 + kk) * 512 + (size_t)lane * 8;
        gload16(g, sptr + so + (unsigned)u * 1024u);
      } else {
        int v = u - 8;
        const unsigned short* g =
            w2f + ((size_t)kk * NTOT + (ntb0 + v)) * 512 + (size_t)lane * 8;
        gload16(g, sptr + so + 8192u + (unsigned)v * 1024u);
      }
    }
  };

  floatx4 am[4][4];
#pragma unroll
  for (int i = 0; i < 4; ++i)
#pragma unroll
    for (int j = 0; j < 4; ++j) am[i][j] = (floatx4){0.f, 0.f, 0.f, 0.f};

  stage_step(0, 0);
  int cur = 0;
  for (int k0 = 0; k0 < K32; ++k0) {
    int nxt = (cur == 2) ? 0 : cur + 1;
    if (k0 + 1 < K32) {
      stage_step(nxt, k0 + 1);
      asm volatile("s_waitcnt vmcnt(4)" ::: "memory");
    } else {
      asm volatile("s_waitcnt vmcnt(0)" ::: "memory");
    }
    __builtin_amdgcn_s_barrier();
    asm volatile("" ::: "memory");
    const char* sb = sptr + cur * BUFSZ2 + (size_t)lane * 16;
    half8 af[4], bf[4];
#pragma unroll
    for (int mt = 0; mt < 4; ++mt)
      af[mt] = *(const half8*)(sb + (wm * 4 + mt) * 1024);
#pragma unroll
    for (int nt = 0; nt < 4; ++nt)
      bf[nt] = *(const half8*)(sb + 8192 + (wn * 4 + nt) * 1024);
#pragma unroll
    for (int mt = 0; mt < 4; ++mt)
#pragma unroll
      for (int nt = 0; nt < 4; ++nt)
        am[mt][nt] = __builtin_amdgcn_mfma_f32_16x16x32_f16(af[mt], bf[nt],
                                                            am[mt][nt], 0, 0, 0);
    asm volatile("" ::: "memory");
    cur = nxt;
  }
  // fused epilogue: sv = am + b2; st_out = sv; prev = sv*uw + prev*(1-uw)
  {
    int r0 = (lane >> 4) * 4;
    int c0l = lane & 15;
    int mtb = mtb0 + wm * 4;
    int njb = ntb0 + wn * 4;
    float bias[4];
#pragma unroll
    for (int nt = 0; nt < 4; ++nt) bias[nt] = b2[(njb + nt) * 16 + c0l];
#pragma unroll
    for (int mt = 0; mt < 4; ++mt) {
      int pos4[4]; float uw4[4]; bool ok4[4];
#pragma unroll
      for (int reg = 0; reg < 4; ++reg) {
        int m = m_base + (mtb + mt) * 16 + r0 + reg;
        ok4[reg] = (m < cnt);
        int mc = ok4[reg] ? m : 0;
        pos4[reg] = idxbuf[mc];
        uw4[reg]  = uw_c[mc];
      }
#pragma unroll
      for (int nt = 0; nt < 4; ++nt) {
        int col = (njb + nt) * 16 + c0l;
#pragma unroll
        for (int reg = 0; reg < 4; ++reg) {
          if (ok4[reg]) {
            float sv = am[mt][nt][reg] + bias[nt];
            size_t off = (size_t)pos4[reg] * Hh + col;
            float pv = tzero ? 0.f : prev[off];
            st_out[off] = sv;
            prev[off] = sv * uw4[reg] + pv * (1.f - uw4[reg]);
          }
        }
      }
    }
  }
}

extern "C" void kernel_launch(void* const* d_in, const int* in_sizes, int n_in,
                              void* d_out, int out_size, void* d_ws, size_t ws_size,
                              hipStream_t stream) {
  const float* state  = (const float*)d_in[0];
  const float* te     = (const float*)d_in[2];
  const float* pe     = (const float*)d_in[3];
  const float* wp     = (const float*)d_in[4];
  const float* bp     = (const float*)d_in[5];
  const float* w1     = (const float*)d_in[6];
  const float* b1     = (const float*)d_in[7];
  const float* w2     = (const float*)d_in[8];
  const float* b2     = (const float*)d_in[9];

  float* out        = (float*)d_out;
  float* prev       = out;                          // BS*H (fully written @t0)
  float* remainders = out + (size_t)BS * Hh;        // BS   (fully written @t0)
  float* n_updates  = remainders + BS;              // BS   (fully written @t0)

  float*          st      = (float*)d_ws;           // BS*H (fully written @t0)
  float*          halting = st + (size_t)BS * Hh;   // BS   (fully written @t0)
  float*          uw_c    = halting + BS;           // BS
  int*            idxbuf  = (int*)(uw_c + BS);      // BS
  int*            cntp    = idxbuf + BS;            // 64 (one counter per hop)
  unsigned short* w1f     = (unsigned short*)(cntp + 64);   // 2*PS (4 MB)
  unsigned short* w2f     = w1f + 2 * (size_t)PS;           // main plane used
  unsigned short* hf      = w2f + 2 * (size_t)PS;

  size_t fixed = (size_t)((char*)hf - (char*)d_ws);
  size_t avail = (ws_size > fixed) ? (ws_size - fixed) : 0;
  // per row: hf = 2048*2 = 4096 B ; xf = 512*2 = 1024 B (single fp16 planes)
  int hrows = (int)((avail / 5120) & ~(size_t)127);
  if (hrows > BS) hrows = BS;
  if (hrows < 128) hrows = 128;
  unsigned short* xf = hf + (size_t)hrows * DFF;    // hf = hrows*DFF ushorts
  int nst = hrows / 128;

  // Only the hop counters need zeroing: all other state buffers are fully
  // written at hop 0 via the tzero paths.
  hipMemsetAsync(cntp, 0, 64 * sizeof(int), stream);

  prep_kernel<<<512, 256, 0, stream>>>(w1, w1f, Hh / 32, DFF / 16, DFF, 1);
  prep_kernel<<<512, 256, 0, stream>>>(w2, w2f, DFF / 32, Hh / 16, Hh, 0);

  for (int t = 0; t < HOPS; ++t) {
    const float* pe_t = pe + (size_t)t * Hh;
    int* cnt_t = cntp + t;
    int tz = (t == 0) ? 1 : 0;
    const float* st_src = tz ? state : st;   // hop 0 reads the input directly
    compact_kernel<<<BS / 1024, 1024, 0, stream>>>(halting, idxbuf, cnt_t, tz);
    halt_kernel<<<BS / 4, 256, 0, stream>>>(st_src, te, pe_t, wp, bp, halting,
                                            remainders, n_updates, uw_c,
                                            idxbuf, cnt_t, tz);
    for (int mb = 0; mb < BS; mb += hrows) {
      stagex_kernel<<<hrows / 4, 256, 0, stream>>>(st_src, te, pe_t, xf, idxbuf,
                                                   cnt_t, mb, hrows);
      gemm1_kernel<<<nst * 16, 256, 0, stream>>>(xf, w1f, b1, hf, cnt_t, mb);
      gemm2f_kernel<<<nst * 4, 256, 0, stream>>>(hf, w2f, b2, uw_c, st, prev,
                                                 idxbuf, cnt_t, mb, tz);
    }
  }
}

// Round 11
// 590.219 us; speedup vs baseline: 1.9354x; 1.1920x over previous
//
#include <hip/hip_runtime.h>
#include <math.h>

typedef short short8 __attribute__((ext_vector_type(8)));
typedef _Float16 half8 __attribute__((ext_vector_type(8)));
typedef float floatx4 __attribute__((ext_vector_type(4)));

#define Bb 64
#define Ss 512
#define Hh 512
#define DFF 2048
#define HOPS 6
#define BS (Bb*Ss)          // 32768 positions
#define PS 1048576          // weight plane stride (elems), both w1f and w2f
#define BUFSZ 16384         // stage buf: A 8KB + B 8KB (single fp16 limbs)
#define RSCALE 2048.0f
#define RINV   (1.0f/2048.0f)

// ---------------- fp16 pack helpers ---------------------------------------
// ALL operands single fp16 plane (R11). Error ledger (all independent,
// quadrature-combined at the output, vs observed floor absmax=0.0078):
//   h-rounding (R7):   ~3.4e-4   -- accepted, absmax 0.0039->0.0078
//   W2-rounding (R10): ~3.4e-4   -- accepted, absmax unchanged 0.0078
//   W1-rounding (R11): ~2.0e-4   -- smallest term; predicted absmax same
__device__ inline unsigned short f16u(float v) {
  _Float16 h = (_Float16)v;
  union { _Float16 h; unsigned short u; } c; c.h = h; return c.u;
}
__device__ inline void split8_store1(const float* xs, unsigned short* dst) {
  unsigned q[4];
#pragma unroll
  for (int j = 0; j < 4; ++j)
    q[j] = (unsigned)f16u(xs[2*j]) | ((unsigned)f16u(xs[2*j+1]) << 16);
  *(int4*)dst = make_int4(q[0], q[1], q[2], q[3]);
}

// ---------------- async global->LDS 16B helper -----------------------------
__device__ __forceinline__ void gload16(const void* g, void* l) {
  __builtin_amdgcn_global_load_lds(
      (const __attribute__((address_space(1))) void*)g,
      (__attribute__((address_space(3))) void*)l, 16, 0, 0);
}

// ---------------- weight pre-split into fragment-linear fp16 planes -------
__global__ __launch_bounds__(256) void prep_kernel(
    const float* __restrict__ w, unsigned short* __restrict__ wf,
    int K32, int NTOT, int N)
{
  int id = blockIdx.x * 256 + threadIdx.x;      // one per (k0,NT,lane)
  if (id >= K32 * NTOT * 64) return;
  int l  = id & 63;
  int NT = (id >> 6) % NTOT;
  int k0 = id / (64 * NTOT);
  int n  = NT * 16 + (l & 15);
  int kb = k0 * 32 + 8 * (l >> 4);
  float xs[8];
#pragma unroll
  for (int j = 0; j < 8; ++j) xs[j] = w[(size_t)(kb + j) * N + n];
  split8_store1(xs, wf + (size_t)id * 8);
}

// ---------------- parallel compaction (order-free, outputs invariant) ------
__global__ __launch_bounds__(1024) void compact_kernel(
    const float* __restrict__ halting, int* __restrict__ idx,
    int* __restrict__ cnt, int tzero)
{
  __shared__ int wsum[16];
  __shared__ int wbase[16];
  __shared__ int s_base;
  int tid = threadIdx.x;
  int lane = tid & 63, wid = tid >> 6;
  int pos = blockIdx.x * 1024 + tid;
  int flag = tzero ? 1 : ((halting[pos] < 1.0f) ? 1 : 0);
  unsigned long long m = __ballot(flag);
  int pre = __popcll(m & ((1ull << lane) - 1ull));
  if (lane == 0) wsum[wid] = __popcll(m);
  __syncthreads();
  if (tid == 0) {
    int a = 0;
#pragma unroll
    for (int i = 0; i < 16; ++i) { wbase[i] = a; a += wsum[i]; }
    s_base = (a > 0) ? atomicAdd(cnt, a) : 0;
  }
  __syncthreads();
  if (flag) idx[s_base + wbase[wid] + pre] = pos;
}

// ---------------- halting / p kernel (pure fp32) ---------------------------
__global__ __launch_bounds__(256) void halt_kernel(
    const float* __restrict__ st, const float* __restrict__ te,
    const float* __restrict__ pe_t, const float* __restrict__ wp,
    const float* __restrict__ bp, float* __restrict__ halting,
    float* __restrict__ remainders, float* __restrict__ n_updates,
    float* __restrict__ uw_c, const int* __restrict__ idxbuf,
    const int* __restrict__ cntp, int tzero)
{
  int cnt = *cntp;
  int i = blockIdx.x * 4 + (threadIdx.x >> 6);
  if (i >= cnt) return;
  int lane = threadIdx.x & 63;
  int pos = idxbuf[i];
  int s = pos & (Ss - 1);
  const float4* stv = (const float4*)(st + (size_t)pos * Hh);
  const float4* tev = (const float4*)(te + (size_t)s * Hh);
  const float4* pev = (const float4*)pe_t;
  const float4* wpv = (const float4*)wp;
  float sum = 0.f;
#pragma unroll
  for (int j = 0; j < 2; ++j) {
    int idx = lane + j * 64;
    float4 a = stv[idx], b = tev[idx], c = pev[idx], w = wpv[idx];
    sum += (a.x + b.x + c.x) * w.x + (a.y + b.y + c.y) * w.y +
           (a.z + b.z + c.z) * w.z + (a.w + b.w + c.w) * w.w;
  }
#pragma unroll
  for (int off = 32; off > 0; off >>= 1) sum += __shfl_xor(sum, off, 64);
  if (lane == 0) {
    float y = sum + bp[0];
    float p = 1.0f / (1.0f + expf(-y));
    const float THRESH = 1.0f - 0.1f;
    float h0  = tzero ? 0.f : halting[pos];
    float rem = tzero ? 0.f : remainders[pos];
    float nup = tzero ? 0.f : n_updates[pos];
    float still = (h0 < 1.0f) ? 1.f : 0.f;
    float cand  = h0 + p * still;
    float nh  = ((cand >  THRESH) ? 1.f : 0.f) * still;
    float st2 = ((cand <= THRESH) ? 1.f : 0.f) * still;
    h0  += p * st2;
    rem += nh * (1.0f - h0);
    h0  += nh * rem;
    nup += st2 + nh;
    float uwv = p * st2 + nh * rem;
    halting[pos]    = h0;
    remainders[pos] = rem;
    n_updates[pos]  = nup;
    uw_c[i]         = uwv;
  }
}

// ---- stage_x: x = st+te+pe (gathered) into single fp16 fragment plane -----
__global__ __launch_bounds__(256) void stagex_kernel(
    const float* __restrict__ st, const float* __restrict__ te,
    const float* __restrict__ pe_t, unsigned short* __restrict__ xf,
    const int* __restrict__ idxbuf, const int* __restrict__ cntp,
    int m_base, int mrows)
{
  const int K32 = Hh / 32;
  int cnt = *cntp;
  int rel = cnt - m_base;
  if (rel <= 0) return;
  if (rel > mrows) rel = mrows;
  int rows_pad = (rel + 127) & ~127;
  if (rows_pad > mrows) rows_pad = mrows;
  int id = blockIdx.x * 256 + threadIdx.x;
  int l = id & 63;
  int f = id >> 6;
  int mtile = f / K32, k0 = f - mtile * K32;
  if (mtile * 16 >= rows_pad) return;
  int m = m_base + mtile * 16 + (l & 15);
  int mc = (m < cnt) ? m : cnt - 1;
  int pos = idxbuf[mc];
  int kb = k0 * 32 + (l >> 4) * 8;
  const float* ap = st + (size_t)pos * Hh + kb;
  const float* tp = te + (size_t)(pos & (Ss - 1)) * Hh + kb;
  const float* pp = pe_t + kb;
  float4 xa = *(const float4*)ap, xb = *(const float4*)(ap + 4);
  float4 ta = *(const float4*)tp, tb = *(const float4*)(tp + 4);
  float4 pa = *(const float4*)pp, pb = *(const float4*)(pp + 4);
  float xs[8];
  xs[0] = xa.x + ta.x + pa.x; xs[1] = xa.y + ta.y + pa.y;
  xs[2] = xa.z + ta.z + pa.z; xs[3] = xa.w + ta.w + pa.w;
  xs[4] = xb.x + tb.x + pb.x; xs[5] = xb.y + tb.y + pb.y;
  xs[6] = xb.z + tb.z + pb.z; xs[7] = xb.w + tb.w + pb.w;
  split8_store1(xs, xf + ((size_t)f * 64 + l) * 8);
}

// ======================= GEMM kernels (ring-3, single barrier) =============
// block 128x128, 4 waves (2m x 2n), wave 64x64 = 4x4 frags of 16x16x32 fp16,
// ALL single-limb: 16 MFMA, 8 ds_read_b128, 16 stage units (4 gloads/wave,
// vmcnt(4)) per k-step. RING-3 LDS (3 x 16 KB = 48 KB), one barrier per
// k-step (R9-verified): stage buf[(k+1)%3] whose last reads were at iter
// k-2, protected by iter k-1's barrier.

// ---- GEMM1: h = relu(x @ w1 + b1), stored as single fp16 A-frag plane -----
#define LSTR 66
__global__ __launch_bounds__(256, 2) void gemm1_kernel(
    const unsigned short* __restrict__ xf, const unsigned short* __restrict__ w1f,
    const float* __restrict__ b1, unsigned short* __restrict__ hf,
    const int* __restrict__ cntp, int m_base)
{
  __shared__ __align__(1024) char stage[3 * BUFSZ];
  const int K32 = Hh / 32, NTOT = DFF / 16;   // 16, 128
  int lin = blockIdx.x;
  int gsz = gridDim.x;
  int q = gsz >> 3, r = gsz & 7;
  int xcd = lin & 7, idx0 = lin >> 3;
  int swz = (xcd < r) ? (xcd * (q + 1) + idx0)
                      : (r * (q + 1) + (xcd - r) * q + idx0);
  int strip = swz >> 4;
  int nb    = swz & 15;
  int cnt = *cntp;
  int m0 = strip * 128;
  if (m_base + m0 >= cnt) return;
  int tid = threadIdx.x, lane = tid & 63, w = tid >> 6;
  int wm = w >> 1, wn = w & 1;
  int n0 = nb * 128;
  int mtb0 = m0 >> 4, ntb0 = n0 >> 4;
  char* sptr = stage;

  // 16 units: 0..7 = A mtile, 8..15 = B ntile (single limb each)
  auto stage_step = [&](int bsel, int kk) {
    unsigned so = (unsigned)bsel * (unsigned)BUFSZ;
#pragma unroll
    for (int j = 0; j < 4; ++j) {
      int u = w * 4 + j;
      if (u < 8) {
        const unsigned short* g =
            xf + ((size_t)(mtb0 + u) * K32 + kk) * 512 + (size_t)lane * 8;
        gload16(g, sptr + so + (unsigned)u * 1024u);
      } else {
        int v = u - 8;
        const unsigned short* g =
            w1f + ((size_t)kk * NTOT + (ntb0 + v)) * 512 + (size_t)lane * 8;
        gload16(g, sptr + so + 8192u + (unsigned)v * 1024u);
      }
    }
  };

  floatx4 am[4][4];
#pragma unroll
  for (int i = 0; i < 4; ++i)
#pragma unroll
    for (int j = 0; j < 4; ++j) am[i][j] = (floatx4){0.f, 0.f, 0.f, 0.f};

  stage_step(0, 0);
  int cur = 0;
  for (int k0 = 0; k0 < K32; ++k0) {
    int nxt = (cur == 2) ? 0 : cur + 1;
    if (k0 + 1 < K32) {
      stage_step(nxt, k0 + 1);
      asm volatile("s_waitcnt vmcnt(4)" ::: "memory");   // stage(k0) landed
    } else {
      asm volatile("s_waitcnt vmcnt(0)" ::: "memory");
    }
    __builtin_amdgcn_s_barrier();          // all waves' stage-writes visible
    asm volatile("" ::: "memory");
    const char* sb = sptr + cur * BUFSZ + (size_t)lane * 16;
    half8 af[4], bf[4];
#pragma unroll
    for (int mt = 0; mt < 4; ++mt)
      af[mt] = *(const half8*)(sb + (wm * 4 + mt) * 1024);
#pragma unroll
    for (int nt = 0; nt < 4; ++nt)
      bf[nt] = *(const half8*)(sb + 8192 + (wn * 4 + nt) * 1024);
    __builtin_amdgcn_s_setprio(1);
#pragma unroll
    for (int mt = 0; mt < 4; ++mt)
#pragma unroll
      for (int nt = 0; nt < 4; ++nt)
        am[mt][nt] = __builtin_amdgcn_mfma_f32_16x16x32_f16(af[mt], bf[nt],
                                                            am[mt][nt], 0, 0, 0);
    __builtin_amdgcn_s_setprio(0);
    asm volatile("" ::: "memory");
    cur = nxt;
  }
  __syncthreads();   // final-iter readers done before epilogue reuses buf0
  // epilogue: relu + bias; repack C-frag -> A-frag in 16-row slices.
  // Per-wave private LDS slice in buf0.
  {
    int r0 = (lane >> 4) * 4;
    int c0l = lane & 15;
    int mtb = mtb0 + wm * 4;
    int k2b = (n0 >> 5) + wn * 2;
    float* L = (float*)(void*)sptr + (size_t)w * (16 * LSTR);
    float bias[4];
#pragma unroll
    for (int nt = 0; nt < 4; ++nt) bias[nt] = b1[n0 + wn * 64 + nt * 16 + c0l];
#pragma unroll
    for (int mt = 0; mt < 4; ++mt) {
#pragma unroll
      for (int nt = 0; nt < 4; ++nt)
#pragma unroll
        for (int reg = 0; reg < 4; ++reg)
          L[(r0 + reg) * LSTR + nt * 16 + c0l] =
              fmaxf(am[mt][nt][reg] + bias[nt], 0.f);
#pragma unroll
      for (int k2 = 0; k2 < 2; ++k2) {
        const float* rp = L + (lane & 15) * LSTR + k2 * 32 + (lane >> 4) * 8;
        float xs[8];
        float4 xa = *(const float4*)rp, xb = *(const float4*)(rp + 4);
        xs[0]=xa.x; xs[1]=xa.y; xs[2]=xa.z; xs[3]=xa.w;
        xs[4]=xb.x; xs[5]=xb.y; xs[6]=xb.z; xs[7]=xb.w;
        size_t f2 = (size_t)(mtb + mt) * 64 + (k2b + k2);
        split8_store1(xs, hf + (f2 * 64 + lane) * 8);
      }
    }
  }
}

// ---- GEMM2f (FULL-K, single-limb, fused bias + uw-blend scatter) ----------
__global__ __launch_bounds__(256, 2) void gemm2f_kernel(
    const unsigned short* __restrict__ hf, const unsigned short* __restrict__ w2f,
    const float* __restrict__ b2, const float* __restrict__ uw_c,
    float* __restrict__ st_out, float* __restrict__ prev,
    const int* __restrict__ idxbuf, const int* __restrict__ cntp,
    int m_base, int tzero)
{
  __shared__ __align__(1024) char stage[3 * BUFSZ];
  const int K32 = DFF / 32, NTOT = Hh / 16;   // 64, 32
  int lin = blockIdx.x;
  int gsz = gridDim.x;
  int q = gsz >> 3, r = gsz & 7;
  int xcd = lin & 7, idx0 = lin >> 3;
  int swz = (xcd < r) ? (xcd * (q + 1) + idx0)
                      : (r * (q + 1) + (xcd - r) * q + idx0);
  int strip = swz >> 2, nb = swz & 3;
  int cnt = *cntp;
  int m0 = strip * 128;
  if (m_base + m0 >= cnt) return;
  int n0 = nb * 128;
  int tid = threadIdx.x, lane = tid & 63, w = tid >> 6;
  int wm = w >> 1, wn = w & 1;
  int mtb0 = m0 >> 4, ntb0 = n0 >> 4;
  char* sptr = stage;

  auto stage_step = [&](int bsel, int kk) {
    unsigned so = (unsigned)bsel * (unsigned)BUFSZ;
#pragma unroll
    for (int j = 0; j < 4; ++j) {
      int u = w * 4 + j;
      if (u < 8) {
        const unsigned short* g =
            hf + ((size_t)(mtb0 + u) * K32 + kk) * 512 + (size_t)lane * 8;
        gload16(g, sptr + so + (unsigned)u * 1024u);
      } else {
        int v = u - 8;
        const unsigned short* g =
            w2f + ((size_t)kk * NTOT + (ntb0 + v)) * 512 + (size_t)lane * 8;
        gload16(g, sptr + so + 8192u + (unsigned)v * 1024u);
      }
    }
  };

  floatx4 am[4][4];
#pragma unroll
  for (int i = 0; i < 4; ++i)
#pragma unroll
    for (int j = 0; j < 4; ++j) am[i][j] = (floatx4){0.f, 0.f, 0.f, 0.f};

  stage_step(0, 0);
  int cur = 0;
  for (int k0 = 0; k0 < K32; ++k0) {
    int nxt = (cur == 2) ? 0 : cur + 1;
    if (k0 + 1 < K32) {
      stage_step(nxt, k0 + 1);
      asm volatile("s_waitcnt vmcnt(4)" ::: "memory");
    } else {
      asm volatile("s_waitcnt vmcnt(0)" ::: "memory");
    }
    __builtin_amdgcn_s_barrier();
    asm volatile("" ::: "memory");
    const char* sb = sptr + cur * BUFSZ + (size_t)lane * 16;
    half8 af[4], bf[4];
#pragma unroll
    for (int mt = 0; mt < 4; ++mt)
      af[mt] = *(const half8*)(sb + (wm * 4 + mt) * 1024);
#pragma unroll
    for (int nt = 0; nt < 4; ++nt)
      bf[nt] = *(const half8*)(sb + 8192 + (wn * 4 + nt) * 1024);
#pragma unroll
    for (int mt = 0; mt < 4; ++mt)
#pragma unroll
      for (int nt = 0; nt < 4; ++nt)
        am[mt][nt] = __builtin_amdgcn_mfma_f32_16x16x32_f16(af[mt], bf[nt],
                                                            am[mt][nt], 0, 0, 0);
    asm volatile("" ::: "memory");
    cur = nxt;
  }
  // fused epilogue: sv = am + b2; st_out = sv; prev = sv*uw + prev*(1-uw)
  {
    int r0 = (lane >> 4) * 4;
    int c0l = lane & 15;
    int mtb = mtb0 + wm * 4;
    int njb = ntb0 + wn * 4;
    float bias[4];
#pragma unroll
    for (int nt = 0; nt < 4; ++nt) bias[nt] = b2[(njb + nt) * 16 + c0l];
#pragma unroll
    for (int mt = 0; mt < 4; ++mt) {
      int pos4[4]; float uw4[4]; bool ok4[4];
#pragma unroll
      for (int reg = 0; reg < 4; ++reg) {
        int m = m_base + (mtb + mt) * 16 + r0 + reg;
        ok4[reg] = (m < cnt);
        int mc = ok4[reg] ? m : 0;
        pos4[reg] = idxbuf[mc];
        uw4[reg]  = uw_c[mc];
      }
#pragma unroll
      for (int nt = 0; nt < 4; ++nt) {
        int col = (njb + nt) * 16 + c0l;
#pragma unroll
        for (int reg = 0; reg < 4; ++reg) {
          if (ok4[reg]) {
            float sv = am[mt][nt][reg] + bias[nt];
            size_t off = (size_t)pos4[reg] * Hh + col;
            float pv = tzero ? 0.f : prev[off];
            st_out[off] = sv;
            prev[off] = sv * uw4[reg] + pv * (1.f - uw4[reg]);
          }
        }
      }
    }
  }
}

extern "C" void kernel_launch(void* const* d_in, const int* in_sizes, int n_in,
                              void* d_out, int out_size, void* d_ws, size_t ws_size,
                              hipStream_t stream) {
  const float* state  = (const float*)d_in[0];
  const float* te     = (const float*)d_in[2];
  const float* pe     = (const float*)d_in[3];
  const float* wp     = (const float*)d_in[4];
  const float* bp     = (const float*)d_in[5];
  const float* w1     = (const float*)d_in[6];
  const float* b1     = (const float*)d_in[7];
  const float* w2     = (const float*)d_in[8];
  const float* b2     = (const float*)d_in[9];

  float* out        = (float*)d_out;
  float* prev       = out;                          // BS*H (fully written @t0)
  float* remainders = out + (size_t)BS * Hh;        // BS   (fully written @t0)
  float* n_updates  = remainders + BS;              // BS   (fully written @t0)

  float*          st      = (float*)d_ws;           // BS*H (fully written @t0)
  float*          halting = st + (size_t)BS * Hh;   // BS   (fully written @t0)
  float*          uw_c    = halting + BS;           // BS
  int*            idxbuf  = (int*)(uw_c + BS);      // BS
  int*            cntp    = idxbuf + BS;            // 64 (one counter per hop)
  unsigned short* w1f     = (unsigned short*)(cntp + 64);   // PS (2 MB)
  unsigned short* w2f     = w1f + (size_t)PS;               // PS (2 MB)
  unsigned short* hf      = w2f + (size_t)PS;

  size_t fixed = (size_t)((char*)hf - (char*)d_ws);
  size_t avail = (ws_size > fixed) ? (ws_size - fixed) : 0;
  // per row: hf = 2048*2 = 4096 B ; xf = 512*2 = 1024 B (single fp16 planes)
  int hrows = (int)((avail / 5120) & ~(size_t)127);
  if (hrows > BS) hrows = BS;
  if (hrows < 128) hrows = 128;
  unsigned short* xf = hf + (size_t)hrows * DFF;    // hf = hrows*DFF ushorts
  int nst = hrows / 128;

  // Only the hop counters need zeroing: all other state buffers are fully
  // written at hop 0 via the tzero paths.
  hipMemsetAsync(cntp, 0, 64 * sizeof(int), stream);

  prep_kernel<<<512, 256, 0, stream>>>(w1, w1f, Hh / 32, DFF / 16, DFF);
  prep_kernel<<<512, 256, 0, stream>>>(w2, w2f, DFF / 32, Hh / 16, Hh);

  for (int t = 0; t < HOPS; ++t) {
    const float* pe_t = pe + (size_t)t * Hh;
    int* cnt_t = cntp + t;
    int tz = (t == 0) ? 1 : 0;
    const float* st_src = tz ? state : st;   // hop 0 reads the input directly
    compact_kernel<<<BS / 1024, 1024, 0, stream>>>(halting, idxbuf, cnt_t, tz);
    halt_kernel<<<BS / 4, 256, 0, stream>>>(st_src, te, pe_t, wp, bp, halting,
                                            remainders, n_updates, uw_c,
                                            idxbuf, cnt_t, tz);
    for (int mb = 0; mb < BS; mb += hrows) {
      stagex_kernel<<<hrows / 4, 256, 0, stream>>>(st_src, te, pe_t, xf, idxbuf,
                                                   cnt_t, mb, hrows);
      gemm1_kernel<<<nst * 16, 256, 0, stream>>>(xf, w1f, b1, hf, cnt_t, mb);
      gemm2f_kernel<<<nst * 4, 256, 0, stream>>>(hf, w2f, b2, uw_c, st, prev,
                                                 idxbuf, cnt_t, mb, tz);
    }
  }
}